// Round 1
// baseline (3189.157 us; speedup 1.0000x reference)
//
#include <hip/hip_runtime.h>
#include <math.h>

#define BN 32
#define NP 1024
#define KNN 30
#define NR 64
#define NFPS 55

// s = dinv*dinv with dinv = 1/sqrt(30) in f32, matching the reference's
// normalized laplacian (every kNN row-sum is exactly 30).
__device__ __forceinline__ float lap_s() {
    const float dv = 1.0f / sqrtf(30.0f);
    return dv * dv;
}

// ---------------------------------------------------------------------------
// k_init: zero the atomic reg accumulators and compute regs[3..6] directly.
// ---------------------------------------------------------------------------
__global__ __launch_bounds__(256) void k_init(const float* __restrict__ fc1_w,
                                              const float* __restrict__ fc1_b,
                                              const float* __restrict__ fc3_w,
                                              const float* __restrict__ fc3_b,
                                              float* __restrict__ regs) {
    __shared__ float r1[256], r2[256];
    int t = threadIdx.x;
    float s1 = 0.f;
    for (int i = t; i < 512; i += 256) { float v = fc1_w[(size_t)i * 256]; s1 += v * v; }
    float v2 = fc3_w[(size_t)t * 40];   // t < 256 covers all rows of fc3_w
    float s2 = v2 * v2;
    r1[t] = s1; r2[t] = s2;
    __syncthreads();
    for (int st = 128; st > 0; st >>= 1) {
        if (t < st) { r1[t] += r1[t + st]; r2[t] += r2[t + st]; }
        __syncthreads();
    }
    if (t == 0) {
        regs[0] = 0.f; regs[1] = 0.f; regs[2] = 0.f;
        regs[3] = r1[0];
        regs[4] = fc1_b[0] * fc1_b[0];
        regs[5] = r2[0];
        regs[6] = fc3_b[0] * fc3_b[0];
    }
}

// ---------------------------------------------------------------------------
// k_knn: per-row top-30 nearest neighbors (exact jax.lax.top_k tie order:
// (dist, idx) ascending; ascending-j scan + strict '<' displacement gives it).
// Also emits xs1 = L @ x fused (x tile already in LDS).
// ---------------------------------------------------------------------------
__global__ __launch_bounds__(64) void k_knn(const float* __restrict__ x,
                                            int* __restrict__ knn,
                                            float* __restrict__ xs1) {
    __shared__ float xls[NP * 7];
    __shared__ float sq[NP];
    int b = blockIdx.x;
    const float* xb = x + (size_t)b * NP * 7;
    for (int t = threadIdx.x; t < NP * 7; t += 64) xls[t] = xb[t];
    __syncthreads();
    for (int r = threadIdx.x; r < NP; r += 64) {
        float s = 0.f;
#pragma unroll
        for (int d = 0; d < 7; ++d) { float v = xls[r * 7 + d]; s += v * v; }
        sq[r] = s;
    }
    __syncthreads();
    int i = blockIdx.y * 64 + threadIdx.x;
    float xi[7];
#pragma unroll
    for (int d = 0; d < 7; ++d) xi[d] = xls[i * 7 + d];
    float sqi = sq[i];
    float bd[KNN]; int bi[KNN];
#pragma unroll
    for (int t = 0; t < KNN; ++t) { bd[t] = __builtin_inff(); bi[t] = 0; }
    for (int j = 0; j < NP; ++j) {
        float dot = 0.f;
#pragma unroll
        for (int d = 0; d < 7; ++d) dot += xi[d] * xls[j * 7 + d];
        float dist = fmaxf(sqi + sq[j] - 2.f * dot, 0.f);
        if (dist < bd[KNN - 1]) {
            // sorted insertion, fully unrolled (no dynamic register indexing)
#pragma unroll
            for (int t = KNN - 1; t >= 1; --t) {
                if (bd[t - 1] > dist)      { bd[t] = bd[t - 1]; bi[t] = bi[t - 1]; }
                else if (bd[t] > dist)     { bd[t] = dist;      bi[t] = j; }
            }
            if (bd[0] > dist) { bd[0] = dist; bi[0] = j; }
        }
    }
    int* kout = knn + ((size_t)b * NP + i) * KNN;
    float nsum[7] = {0.f, 0.f, 0.f, 0.f, 0.f, 0.f, 0.f};
#pragma unroll
    for (int t = 0; t < KNN; ++t) {
        int j = bi[t];
        kout[t] = j;
#pragma unroll
        for (int d = 0; d < 7; ++d) nsum[d] += xls[j * 7 + d];
    }
    const float s = lap_s();
    float* xo = xs1 + ((size_t)b * NP + i) * 7;
#pragma unroll
    for (int d = 0; d < 7; ++d) xo[d] = xi[d] - s * nsum[d];
}

// ---------------------------------------------------------------------------
// k_out: xs2 = 2 L xs1 - x, then out = relu([x|xs1|xs2] @ W1 + b1), (B,N,64).
// Two phases through LDS so the 64-wide store is coalesced.
// ---------------------------------------------------------------------------
__global__ __launch_bounds__(256) void k_out(const float* __restrict__ x,
                                             const float* __restrict__ xs1,
                                             const int* __restrict__ knn,
                                             const float* __restrict__ W1,
                                             const float* __restrict__ b1,
                                             float* __restrict__ out) {
    __shared__ float x1s[NP * 7];    // xs1 for ALL rows (neighbor gathers)
    __shared__ float x0s[256 * 7];   // x for this block's rows only
    __shared__ float fr[256 * 21];
    __shared__ float W1s[21 * 64];
    __shared__ float b1s[64];
    int b = blockIdx.x;
    int rbase = blockIdx.y * 256;
    int t = threadIdx.x;
    for (int q = t; q < NP * 7; q += 256) x1s[q] = xs1[(size_t)b * NP * 7 + q];
    for (int q = t; q < 256 * 7; q += 256) x0s[q] = x[(size_t)b * NP * 7 + (size_t)rbase * 7 + q];
    for (int q = t; q < 21 * 64; q += 256) W1s[q] = W1[q];
    if (t < 64) b1s[t] = b1[t];
    __syncthreads();
    {   // phase 1: per-row 21-feature vector
        int i = rbase + t;
        float f[21];
#pragma unroll
        for (int d = 0; d < 7; ++d) { f[d] = x0s[t * 7 + d]; f[7 + d] = x1s[i * 7 + d]; }
        float ns[7] = {0.f, 0.f, 0.f, 0.f, 0.f, 0.f, 0.f};
        const int* kn = knn + ((size_t)b * NP + i) * KNN;
        for (int q = 0; q < KNN; ++q) {
            int j = kn[q];
#pragma unroll
            for (int d = 0; d < 7; ++d) ns[d] += x1s[j * 7 + d];
        }
        const float s = lap_s();
#pragma unroll
        for (int d = 0; d < 7; ++d) f[14 + d] = 2.f * (f[7 + d] - s * ns[d]) - f[d];
#pragma unroll
        for (int d = 0; d < 21; ++d) fr[t * 21 + d] = f[d];
    }
    __syncthreads();
    // phase 2: (256 rows x 21) @ (21 x 64), coalesced store
    int o = t & 63, g = t >> 6;
    for (int m = 0; m < 64; ++m) {
        int r = g * 64 + m;
        float acc = b1s[o];
#pragma unroll
        for (int d = 0; d < 21; ++d) acc += fr[r * 21 + d] * W1s[d * 64 + o];
        out[((size_t)b * NP + rbase + r) * 64 + o] = fmaxf(acc, 0.f);
    }
}

// ---------------------------------------------------------------------------
// k_z1: Z1 = L @ out via kNN gathers (B,N,64).
// ---------------------------------------------------------------------------
__global__ __launch_bounds__(256) void k_z1(const float* __restrict__ out,
                                            const int* __restrict__ knn,
                                            float* __restrict__ Z1) {
    int b = blockIdx.x;
    int i = blockIdx.y * 4 + (threadIdx.x >> 6);
    int f = threadIdx.x & 63;
    const int* kn = knn + ((size_t)b * NP + i) * KNN;
    const float* ob = out + (size_t)b * NP * 64;
    float sum = 0.f;
    for (int q = 0; q < KNN; ++q) sum += ob[(size_t)kn[q] * 64 + f];
    Z1[((size_t)b * NP + i) * 64 + f] = ob[(size_t)i * 64 + f] - lap_s() * sum;
}

// ---------------------------------------------------------------------------
// k_t1: reg1 += sum((out^T Z1)^2) per batch. f-half per block, LDS chunks.
// ---------------------------------------------------------------------------
__global__ __launch_bounds__(256) void k_t1(const float* __restrict__ out,
                                            const float* __restrict__ Z1,
                                            float* __restrict__ regs) {
    __shared__ float os[64 * 64];
    __shared__ float zs[64 * 64];
    __shared__ float red[256];
    int b = blockIdx.x;
    int f0 = blockIdx.y * 32;
    int t = threadIdx.x;
    int fl = t >> 3;          // 0..31
    int gb = (t & 7) * 8;     // 0..56
    float acc[8];
#pragma unroll
    for (int q = 0; q < 8; ++q) acc[q] = 0.f;
    for (int c = 0; c < 16; ++c) {
        const float* ob = out + ((size_t)b * NP + c * 64) * 64;
        const float* zb = Z1 + ((size_t)b * NP + c * 64) * 64;
        for (int q = t; q < 64 * 64; q += 256) { os[q] = ob[q]; zs[q] = zb[q]; }
        __syncthreads();
        for (int n = 0; n < 64; ++n) {
            float a = os[n * 64 + f0 + fl];
#pragma unroll
            for (int q = 0; q < 8; ++q) acc[q] += a * zs[n * 64 + gb + q];
        }
        __syncthreads();
    }
    float loc = 0.f;
#pragma unroll
    for (int q = 0; q < 8; ++q) loc += acc[q] * acc[q];
    red[t] = loc; __syncthreads();
    for (int st = 128; st > 0; st >>= 1) { if (t < st) red[t] += red[t + st]; __syncthreads(); }
    if (t == 0) atomicAdd(&regs[0], red[0]);
}

// ---------------------------------------------------------------------------
// k_vreeb: V_reeb[b,r,f] = max_{s<16} out[b, sccs[b,r,s], f]
// ---------------------------------------------------------------------------
__global__ __launch_bounds__(256) void k_vreeb(const float* __restrict__ out,
                                               const int* __restrict__ sccs,
                                               float* __restrict__ V) {
    int b = blockIdx.x;
    int r = blockIdx.y * 4 + (threadIdx.x >> 6);
    int f = threadIdx.x & 63;
    const int* sc = sccs + ((size_t)b * NR + r) * 16;
    const float* ob = out + (size_t)b * NP * 64;
    float m = -__builtin_inff();
    for (int q = 0; q < 16; ++q) m = fmaxf(m, ob[(size_t)sc[q] * 64 + f]);
    V[((size_t)b * NR + r) * 64 + f] = m;
}

// ---------------------------------------------------------------------------
// k_vfps: V_fps[b,p,f] = max_{s<1024} out[b, sccs_fps[b,p,s], f]
// ---------------------------------------------------------------------------
__global__ __launch_bounds__(256) void k_vfps(const float* __restrict__ out,
                                              const int* __restrict__ sccs_fps,
                                              float* __restrict__ V) {
    __shared__ int idxs[1024];
    __shared__ float red[256];
    int b = blockIdx.x, p = blockIdx.y;
    int t = threadIdx.x;
    const int* sp = sccs_fps + ((size_t)b * NFPS + p) * 1024;
    for (int q = t; q < 1024; q += 256) idxs[q] = sp[q];
    __syncthreads();
    int f = t & 63, sc = t >> 6;
    const float* ob = out + (size_t)b * NP * 64;
    float m = -__builtin_inff();
    for (int s = sc; s < 1024; s += 4) m = fmaxf(m, ob[(size_t)idxs[s] * 64 + f]);
    red[t] = m; __syncthreads();
    if (sc == 0) {
        m = fmaxf(fmaxf(red[f], red[64 + f]), fmaxf(red[128 + f], red[192 + f]));
        V[((size_t)b * NFPS + p) * 64 + f] = m;
    }
}

// ---------------------------------------------------------------------------
// k_lfps: L_fps = I - D^{-1/2} dist D^{-1/2} on the pairwise-distance matrix
// of V_fps (55x55 per batch).
// ---------------------------------------------------------------------------
__global__ __launch_bounds__(256) void k_lfps(const float* __restrict__ V,
                                              float* __restrict__ Lf) {
    __shared__ float Vs[NFPS * 64];
    __shared__ float sq[NFPS];
    __shared__ float dist[NFPS * NFPS];
    __shared__ float dinv[NFPS];
    int b = blockIdx.x, t = threadIdx.x;
    for (int q = t; q < NFPS * 64; q += 256) Vs[q] = V[(size_t)b * NFPS * 64 + q];
    __syncthreads();
    if (t < NFPS) {
        float s = 0.f;
        for (int f = 0; f < 64; ++f) { float v = Vs[t * 64 + f]; s += v * v; }
        sq[t] = s;
    }
    __syncthreads();
    for (int q = t; q < NFPS * NFPS; q += 256) {
        int i = q / NFPS, j = q % NFPS;
        float dot = 0.f;
        for (int f = 0; f < 64; ++f) dot += Vs[i * 64 + f] * Vs[j * 64 + f];
        dist[q] = fmaxf(sq[i] + sq[j] - 2.f * dot, 0.f);
    }
    __syncthreads();
    if (t < NFPS) {
        float s = 0.f;
        for (int j = 0; j < NFPS; ++j) s += dist[t * NFPS + j];
        dinv[t] = (s > 0.f) ? 1.0f / sqrtf(fmaxf(s, 1e-12f)) : 0.f;
    }
    __syncthreads();
    for (int q = t; q < NFPS * NFPS; q += 256) {
        int i = q / NFPS, j = q % NFPS;
        Lf[(size_t)b * NFPS * NFPS + q] = ((i == j) ? 1.f : 0.f) - dist[q] * dinv[i] * dinv[j];
    }
}

// ---------------------------------------------------------------------------
// k_cheb6<N>: K=6 Chebyshev conv (dense L in LDS, ping-pong buffers, register
// accumulators) + relu + Z = L @ out. One block per batch.
// LDS: N*N + 2*N*64 floats  (N=64 -> 48KB; N=55 -> ~39.6KB)
// ---------------------------------------------------------------------------
template<int N>
__global__ __launch_bounds__(1024) void k_cheb6(const float* __restrict__ L,
                                                const float* __restrict__ V,
                                                const float* __restrict__ W,
                                                const float* __restrict__ bias,
                                                float* __restrict__ out,
                                                float* __restrict__ Z) {
    __shared__ float Ls[N * N];
    __shared__ float bA[N * 64];
    __shared__ float bB[N * 64];
    constexpr int NOUT = N * 256;
    int b = blockIdx.x;
    int t = threadIdx.x;
    for (int q = t; q < N * N; q += 1024) Ls[q] = L[(size_t)b * N * N + q];
    for (int q = t; q < N * 64; q += 1024) bA[q] = V[(size_t)b * N * 64 + q];
    float a[16];
#pragma unroll
    for (int i = 0; i < 16; ++i) a[i] = 0.f;
    for (int i = 0, q = t; q < NOUT; ++i, q += 1024) a[i] = bias[q & 255];
    __syncthreads();

    auto accum = [&](const float* xb, int k) {
        const float* Wk = W + (size_t)k * 64 * 256;
        for (int i = 0, q = t; q < NOUT; ++i, q += 1024) {
            int r = q >> 8, o = q & 255;
            float s = a[i];
#pragma unroll
            for (int m = 0; m < 64; ++m) s += xb[r * 64 + m] * Wk[m * 256 + o];
            a[i] = s;
        }
    };
    auto chebmm = [&](const float* src, float* dst, bool first) {
        for (int q = t; q < N * 64; q += 1024) {
            int r = q >> 6, c = q & 63;
            float s = 0.f;
            for (int m = 0; m < N; ++m) s += Ls[r * N + m] * src[m * 64 + c];
            dst[q] = first ? s : (2.f * s - dst[q]);   // dst[q] only touched by owner
        }
    };

    accum(bA, 0);              __syncthreads();
    chebmm(bA, bB, true);      __syncthreads();
    accum(bB, 1);              __syncthreads();
    chebmm(bB, bA, false);     __syncthreads();   // bA = 2 L bB - bA  (xs2)
    accum(bA, 2);              __syncthreads();
    chebmm(bA, bB, false);     __syncthreads();   // xs3
    accum(bB, 3);              __syncthreads();
    chebmm(bB, bA, false);     __syncthreads();   // xs4
    accum(bA, 4);              __syncthreads();
    chebmm(bA, bB, false);     __syncthreads();   // xs5
    accum(bB, 5);

    float* ob = out + (size_t)b * NOUT;
    for (int i = 0, q = t; q < NOUT; ++i, q += 1024) ob[q] = fmaxf(a[i], 0.f);
    __threadfence_block();
    __syncthreads();
    // Z = L @ relu(out): read out back (same CU, L1/L2-hot)
    float* zb = Z + (size_t)b * NOUT;
    for (int q = t; q < NOUT; q += 1024) {
        int r = q >> 8, o = q & 255;
        float s = 0.f;
        for (int m = 0; m < N; ++m) s += Ls[r * N + m] * ob[m * 256 + o];
        zb[q] = s;
    }
}

// ---------------------------------------------------------------------------
// k_treg<N>: reg += sum((out^T Z)^2), out/Z are (B,N,256).
// Grid (B, 8 f-tiles x 2 g-halves). LDS ~41KB.
// ---------------------------------------------------------------------------
template<int N>
__global__ __launch_bounds__(256) void k_treg(const float* __restrict__ out,
                                              const float* __restrict__ Z,
                                              float* __restrict__ reg) {
    __shared__ float zs[N * 128];
    __shared__ float os[N * 32];
    __shared__ float red[256];
    int b = blockIdx.x;
    int f0 = (blockIdx.y >> 1) * 32;
    int g0 = (blockIdx.y & 1) * 128;
    int t = threadIdx.x;
    for (int q = t; q < N * 128; q += 256) {
        int r = q >> 7, gl = q & 127;
        zs[q] = Z[(size_t)b * N * 256 + r * 256 + g0 + gl];
    }
    for (int q = t; q < N * 32; q += 256) {
        int r = q >> 5, f = q & 31;
        os[q] = out[(size_t)b * N * 256 + r * 256 + f0 + f];
    }
    __syncthreads();
    int fl = t >> 3;           // 0..31
    int gb = (t & 7) * 16;     // 0..112
    float accv[16];
#pragma unroll
    for (int q = 0; q < 16; ++q) accv[q] = 0.f;
    for (int n = 0; n < N; ++n) {
        float a = os[n * 32 + fl];
        const float* zr = zs + n * 128 + gb;
#pragma unroll
        for (int q = 0; q < 16; ++q) accv[q] += a * zr[q];
    }
    float loc = 0.f;
#pragma unroll
    for (int q = 0; q < 16; ++q) loc += accv[q] * accv[q];
    red[t] = loc; __syncthreads();
    for (int st = 128; st > 0; st >>= 1) { if (t < st) red[t] += red[t + st]; __syncthreads(); }
    if (t == 0) atomicAdd(reg, red[0]);
}

// ---------------------------------------------------------------------------
// k_tail: feature max-pool + 2-layer MLP -> logits
// ---------------------------------------------------------------------------
__global__ __launch_bounds__(256) void k_tail(const float* __restrict__ outR,
                                              const float* __restrict__ outP,
                                              const float* __restrict__ fc1_w,
                                              const float* __restrict__ fc1_b,
                                              const float* __restrict__ fc3_w,
                                              const float* __restrict__ fc3_b,
                                              float* __restrict__ logits) {
    __shared__ float feat[512];
    __shared__ float h[256];
    int b = blockIdx.x, t = threadIdx.x;
    float m = -__builtin_inff();
    for (int r = 0; r < NR; ++r) m = fmaxf(m, outR[((size_t)b * NR + r) * 256 + t]);
    feat[t] = m;
    m = -__builtin_inff();
    for (int p = 0; p < NFPS; ++p) m = fmaxf(m, outP[((size_t)b * NFPS + p) * 256 + t]);
    feat[256 + t] = m;
    __syncthreads();
    float a = fc1_b[t];
    for (int i = 0; i < 512; ++i) a += feat[i] * fc1_w[(size_t)i * 256 + t];
    h[t] = fmaxf(a, 0.f);
    __syncthreads();
    if (t < 40) {
        float a2 = fc3_b[t];
        for (int i = 0; i < 256; ++i) a2 += h[i] * fc3_w[(size_t)i * 40 + t];
        logits[(size_t)b * 40 + t] = a2;
    }
}

// ---------------------------------------------------------------------------
extern "C" void kernel_launch(void* const* d_in, const int* in_sizes, int n_in,
                              void* d_out, int out_size, void* d_ws, size_t ws_size,
                              hipStream_t stream) {
    const float* x      = (const float*)d_in[0];
    // d_in[1] (x2) unused by the reference
    const float* L_reeb = (const float*)d_in[2];
    const float* W1     = (const float*)d_in[3];
    const float* b1     = (const float*)d_in[4];
    const float* W_reeb = (const float*)d_in[5];
    const float* b_reeb = (const float*)d_in[6];
    const float* W_fps  = (const float*)d_in[7];
    const float* b_fps  = (const float*)d_in[8];
    const float* fc1_w  = (const float*)d_in[9];
    const float* fc1_b  = (const float*)d_in[10];
    const float* fc3_w  = (const float*)d_in[11];
    const float* fc3_b  = (const float*)d_in[12];
    const int*   sccs   = (const int*)d_in[13];
    const int*   sccs_f = (const int*)d_in[14];
    // k / batch_size / num_points are compile-time constants here (30/32/1024)

    float* outv = (float*)d_out;          // 32*40 logits
    float* regs = outv + 1280;            // 7 regs

    // workspace partition (256B-aligned)
    char* w = (char*)d_ws;
    size_t off = 0;
    auto alloc = [&](size_t bytes) { void* p = w + off; off = (off + bytes + 255) & ~(size_t)255; return p; };
    int*   knn   = (int*)  alloc((size_t)BN * NP * KNN * 4);
    float* xs1   = (float*)alloc((size_t)BN * NP * 7 * 4);
    float* outF  = (float*)alloc((size_t)BN * NP * 64 * 4);
    float* Z1    = (float*)alloc((size_t)BN * NP * 64 * 4);
    float* Vreeb = (float*)alloc((size_t)BN * NR * 64 * 4);
    float* outRb = (float*)alloc((size_t)BN * NR * 256 * 4);
    float* Z2    = (float*)alloc((size_t)BN * NR * 256 * 4);
    float* Vfps  = (float*)alloc((size_t)BN * NFPS * 64 * 4);
    float* Lfps  = (float*)alloc((size_t)BN * NFPS * NFPS * 4);
    float* outP  = (float*)alloc((size_t)BN * NFPS * 256 * 4);
    float* Z3    = (float*)alloc((size_t)BN * NFPS * 256 * 4);

    k_init<<<1, 256, 0, stream>>>(fc1_w, fc1_b, fc3_w, fc3_b, regs);
    k_knn<<<dim3(BN, NP / 64), 64, 0, stream>>>(x, knn, xs1);
    k_out<<<dim3(BN, NP / 256), 256, 0, stream>>>(x, xs1, knn, W1, b1, outF);
    k_z1<<<dim3(BN, NP / 4), 256, 0, stream>>>(outF, knn, Z1);
    k_t1<<<dim3(BN, 2), 256, 0, stream>>>(outF, Z1, regs);
    k_vreeb<<<dim3(BN, NR / 4), 256, 0, stream>>>(outF, sccs, Vreeb);
    k_cheb6<NR><<<BN, 1024, 0, stream>>>(L_reeb, Vreeb, W_reeb, b_reeb, outRb, Z2);
    k_treg<NR><<<dim3(BN, 16), 256, 0, stream>>>(outRb, Z2, regs + 1);
    k_vfps<<<dim3(BN, NFPS), 256, 0, stream>>>(outF, sccs_f, Vfps);
    k_lfps<<<BN, 256, 0, stream>>>(Vfps, Lfps);
    k_cheb6<NFPS><<<BN, 1024, 0, stream>>>(Lfps, Vfps, W_fps, b_fps, outP, Z3);
    k_treg<NFPS><<<dim3(BN, 16), 256, 0, stream>>>(outP, Z3, regs + 2);
    k_tail<<<BN, 256, 0, stream>>>(outRb, outP, fc1_w, fc1_b, fc3_w, fc3_b, outv);
}

// Round 2
// 1532.205 us; speedup vs baseline: 2.0814x; 2.0814x over previous
//
#include <hip/hip_runtime.h>
#include <math.h>

#define BN 32
#define NP 1024
#define KNN 30
#define NR 64
#define NFPS 55

// s = dinv*dinv with dinv = 1/sqrt(30) in f32, matching the reference's
// normalized laplacian (every kNN row-sum is exactly 30).
__device__ __forceinline__ float lap_s() {
    const float dv = 1.0f / sqrtf(30.0f);
    return dv * dv;
}

// ---------------------------------------------------------------------------
// k_init: zero the atomic reg accumulators and compute regs[3..6] directly.
// ---------------------------------------------------------------------------
__global__ __launch_bounds__(256) void k_init(const float* __restrict__ fc1_w,
                                              const float* __restrict__ fc1_b,
                                              const float* __restrict__ fc3_w,
                                              const float* __restrict__ fc3_b,
                                              float* __restrict__ regs) {
    __shared__ float r1[256], r2[256];
    int t = threadIdx.x;
    float s1 = 0.f;
    for (int i = t; i < 512; i += 256) { float v = fc1_w[(size_t)i * 256]; s1 += v * v; }
    float v2 = fc3_w[(size_t)t * 40];   // t < 256 covers all rows of fc3_w
    float s2 = v2 * v2;
    r1[t] = s1; r2[t] = s2;
    __syncthreads();
    for (int st = 128; st > 0; st >>= 1) {
        if (t < st) { r1[t] += r1[t + st]; r2[t] += r2[t + st]; }
        __syncthreads();
    }
    if (t == 0) {
        regs[0] = 0.f; regs[1] = 0.f; regs[2] = 0.f;
        regs[3] = r1[0];
        regs[4] = fc1_b[0] * fc1_b[0];
        regs[5] = r2[0];
        regs[6] = fc3_b[0] * fc3_b[0];
    }
}

// ---------------------------------------------------------------------------
// k_knn: per-row top-30 nearest neighbors (exact jax.lax.top_k tie order:
// (dist, idx) ascending; ascending-j scan + strict '<' displacement gives it).
// Also emits xs1 = L @ x fused (x tile already in LDS).
// ---------------------------------------------------------------------------
__global__ __launch_bounds__(64) void k_knn(const float* __restrict__ x,
                                            int* __restrict__ knn,
                                            float* __restrict__ xs1) {
    __shared__ float xls[NP * 7];
    __shared__ float sq[NP];
    int b = blockIdx.x;
    const float* xb = x + (size_t)b * NP * 7;
    for (int t = threadIdx.x; t < NP * 7; t += 64) xls[t] = xb[t];
    __syncthreads();
    for (int r = threadIdx.x; r < NP; r += 64) {
        float s = 0.f;
#pragma unroll
        for (int d = 0; d < 7; ++d) { float v = xls[r * 7 + d]; s += v * v; }
        sq[r] = s;
    }
    __syncthreads();
    int i = blockIdx.y * 64 + threadIdx.x;
    float xi[7];
#pragma unroll
    for (int d = 0; d < 7; ++d) xi[d] = xls[i * 7 + d];
    float sqi = sq[i];
    float bd[KNN]; int bi[KNN];
#pragma unroll
    for (int t = 0; t < KNN; ++t) { bd[t] = __builtin_inff(); bi[t] = 0; }
    for (int j = 0; j < NP; ++j) {
        float dot = 0.f;
#pragma unroll
        for (int d = 0; d < 7; ++d) dot += xi[d] * xls[j * 7 + d];
        float dist = fmaxf(sqi + sq[j] - 2.f * dot, 0.f);
        if (dist < bd[KNN - 1]) {
            // sorted insertion, fully unrolled (no dynamic register indexing)
#pragma unroll
            for (int t = KNN - 1; t >= 1; --t) {
                if (bd[t - 1] > dist)      { bd[t] = bd[t - 1]; bi[t] = bi[t - 1]; }
                else if (bd[t] > dist)     { bd[t] = dist;      bi[t] = j; }
            }
            if (bd[0] > dist) { bd[0] = dist; bi[0] = j; }
        }
    }
    int* kout = knn + ((size_t)b * NP + i) * KNN;
    float nsum[7] = {0.f, 0.f, 0.f, 0.f, 0.f, 0.f, 0.f};
#pragma unroll
    for (int t = 0; t < KNN; ++t) {
        int j = bi[t];
        kout[t] = j;
#pragma unroll
        for (int d = 0; d < 7; ++d) nsum[d] += xls[j * 7 + d];
    }
    const float s = lap_s();
    float* xo = xs1 + ((size_t)b * NP + i) * 7;
#pragma unroll
    for (int d = 0; d < 7; ++d) xo[d] = xi[d] - s * nsum[d];
}

// ---------------------------------------------------------------------------
// k_out: xs2 = 2 L xs1 - x, then out = relu([x|xs1|xs2] @ W1 + b1), (B,N,64).
// Two phases through LDS so the 64-wide store is coalesced.
// ---------------------------------------------------------------------------
__global__ __launch_bounds__(256) void k_out(const float* __restrict__ x,
                                             const float* __restrict__ xs1,
                                             const int* __restrict__ knn,
                                             const float* __restrict__ W1,
                                             const float* __restrict__ b1,
                                             float* __restrict__ out) {
    __shared__ float x1s[NP * 7];    // xs1 for ALL rows (neighbor gathers)
    __shared__ float x0s[256 * 7];   // x for this block's rows only
    __shared__ float fr[256 * 21];
    __shared__ float W1s[21 * 64];
    __shared__ float b1s[64];
    int b = blockIdx.x;
    int rbase = blockIdx.y * 256;
    int t = threadIdx.x;
    for (int q = t; q < NP * 7; q += 256) x1s[q] = xs1[(size_t)b * NP * 7 + q];
    for (int q = t; q < 256 * 7; q += 256) x0s[q] = x[(size_t)b * NP * 7 + (size_t)rbase * 7 + q];
    for (int q = t; q < 21 * 64; q += 256) W1s[q] = W1[q];
    if (t < 64) b1s[t] = b1[t];
    __syncthreads();
    {   // phase 1: per-row 21-feature vector
        int i = rbase + t;
        float f[21];
#pragma unroll
        for (int d = 0; d < 7; ++d) { f[d] = x0s[t * 7 + d]; f[7 + d] = x1s[i * 7 + d]; }
        float ns[7] = {0.f, 0.f, 0.f, 0.f, 0.f, 0.f, 0.f};
        const int* kn = knn + ((size_t)b * NP + i) * KNN;
        for (int q = 0; q < KNN; ++q) {
            int j = kn[q];
#pragma unroll
            for (int d = 0; d < 7; ++d) ns[d] += x1s[j * 7 + d];
        }
        const float s = lap_s();
#pragma unroll
        for (int d = 0; d < 7; ++d) f[14 + d] = 2.f * (f[7 + d] - s * ns[d]) - f[d];
#pragma unroll
        for (int d = 0; d < 21; ++d) fr[t * 21 + d] = f[d];
    }
    __syncthreads();
    // phase 2: (256 rows x 21) @ (21 x 64), coalesced store
    int o = t & 63, g = t >> 6;
    for (int m = 0; m < 64; ++m) {
        int r = g * 64 + m;
        float acc = b1s[o];
#pragma unroll
        for (int d = 0; d < 21; ++d) acc += fr[r * 21 + d] * W1s[d * 64 + o];
        out[((size_t)b * NP + rbase + r) * 64 + o] = fmaxf(acc, 0.f);
    }
}

// ---------------------------------------------------------------------------
// k_z1: Z1 = L @ out via kNN gathers (B,N,64).
// ---------------------------------------------------------------------------
__global__ __launch_bounds__(256) void k_z1(const float* __restrict__ out,
                                            const int* __restrict__ knn,
                                            float* __restrict__ Z1) {
    int b = blockIdx.x;
    int i = blockIdx.y * 4 + (threadIdx.x >> 6);
    int f = threadIdx.x & 63;
    const int* kn = knn + ((size_t)b * NP + i) * KNN;
    const float* ob = out + (size_t)b * NP * 64;
    float sum = 0.f;
    for (int q = 0; q < KNN; ++q) sum += ob[(size_t)kn[q] * 64 + f];
    Z1[((size_t)b * NP + i) * 64 + f] = ob[(size_t)i * 64 + f] - lap_s() * sum;
}

// ---------------------------------------------------------------------------
// k_t1: reg1 += sum((out^T Z1)^2) per batch. f-half per block, LDS chunks.
// ---------------------------------------------------------------------------
__global__ __launch_bounds__(256) void k_t1(const float* __restrict__ out,
                                            const float* __restrict__ Z1,
                                            float* __restrict__ regs) {
    __shared__ float os[64 * 64];
    __shared__ float zs[64 * 64];
    __shared__ float red[256];
    int b = blockIdx.x;
    int f0 = blockIdx.y * 32;
    int t = threadIdx.x;
    int fl = t >> 3;          // 0..31
    int gb = (t & 7) * 8;     // 0..56
    float acc[8];
#pragma unroll
    for (int q = 0; q < 8; ++q) acc[q] = 0.f;
    for (int c = 0; c < 16; ++c) {
        const float* ob = out + ((size_t)b * NP + c * 64) * 64;
        const float* zb = Z1 + ((size_t)b * NP + c * 64) * 64;
        for (int q = t; q < 64 * 64; q += 256) { os[q] = ob[q]; zs[q] = zb[q]; }
        __syncthreads();
        for (int n = 0; n < 64; ++n) {
            float a = os[n * 64 + f0 + fl];
#pragma unroll
            for (int q = 0; q < 8; ++q) acc[q] += a * zs[n * 64 + gb + q];
        }
        __syncthreads();
    }
    float loc = 0.f;
#pragma unroll
    for (int q = 0; q < 8; ++q) loc += acc[q] * acc[q];
    red[t] = loc; __syncthreads();
    for (int st = 128; st > 0; st >>= 1) { if (t < st) red[t] += red[t + st]; __syncthreads(); }
    if (t == 0) atomicAdd(&regs[0], red[0]);
}

// ---------------------------------------------------------------------------
// k_vreeb: V_reeb[b,r,f] = max_{s<16} out[b, sccs[b,r,s], f]
// ---------------------------------------------------------------------------
__global__ __launch_bounds__(256) void k_vreeb(const float* __restrict__ out,
                                               const int* __restrict__ sccs,
                                               float* __restrict__ V) {
    int b = blockIdx.x;
    int r = blockIdx.y * 4 + (threadIdx.x >> 6);
    int f = threadIdx.x & 63;
    const int* sc = sccs + ((size_t)b * NR + r) * 16;
    const float* ob = out + (size_t)b * NP * 64;
    float m = -__builtin_inff();
    for (int q = 0; q < 16; ++q) m = fmaxf(m, ob[(size_t)sc[q] * 64 + f]);
    V[((size_t)b * NR + r) * 64 + f] = m;
}

// ---------------------------------------------------------------------------
// k_vfps: V_fps[b,p,f] = max_{s<1024} out[b, sccs_fps[b,p,s], f]
// ---------------------------------------------------------------------------
__global__ __launch_bounds__(256) void k_vfps(const float* __restrict__ out,
                                              const int* __restrict__ sccs_fps,
                                              float* __restrict__ V) {
    __shared__ int idxs[1024];
    __shared__ float red[256];
    int b = blockIdx.x, p = blockIdx.y;
    int t = threadIdx.x;
    const int* sp = sccs_fps + ((size_t)b * NFPS + p) * 1024;
    for (int q = t; q < 1024; q += 256) idxs[q] = sp[q];
    __syncthreads();
    int f = t & 63, sc = t >> 6;
    const float* ob = out + (size_t)b * NP * 64;
    float m = -__builtin_inff();
    for (int s = sc; s < 1024; s += 4) m = fmaxf(m, ob[(size_t)idxs[s] * 64 + f]);
    red[t] = m; __syncthreads();
    if (sc == 0) {
        m = fmaxf(fmaxf(red[f], red[64 + f]), fmaxf(red[128 + f], red[192 + f]));
        V[((size_t)b * NFPS + p) * 64 + f] = m;
    }
}

// ---------------------------------------------------------------------------
// k_lfps: L_fps = I - D^{-1/2} dist D^{-1/2} on the pairwise-distance matrix
// of V_fps (55x55 per batch).
// ---------------------------------------------------------------------------
__global__ __launch_bounds__(256) void k_lfps(const float* __restrict__ V,
                                              float* __restrict__ Lf) {
    __shared__ float Vs[NFPS * 64];
    __shared__ float sq[NFPS];
    __shared__ float dist[NFPS * NFPS];
    __shared__ float dinv[NFPS];
    int b = blockIdx.x, t = threadIdx.x;
    for (int q = t; q < NFPS * 64; q += 256) Vs[q] = V[(size_t)b * NFPS * 64 + q];
    __syncthreads();
    if (t < NFPS) {
        float s = 0.f;
        for (int f = 0; f < 64; ++f) { float v = Vs[t * 64 + f]; s += v * v; }
        sq[t] = s;
    }
    __syncthreads();
    for (int q = t; q < NFPS * NFPS; q += 256) {
        int i = q / NFPS, j = q % NFPS;
        float dot = 0.f;
        for (int f = 0; f < 64; ++f) dot += Vs[i * 64 + f] * Vs[j * 64 + f];
        dist[q] = fmaxf(sq[i] + sq[j] - 2.f * dot, 0.f);
    }
    __syncthreads();
    if (t < NFPS) {
        float s = 0.f;
        for (int j = 0; j < NFPS; ++j) s += dist[t * NFPS + j];
        dinv[t] = (s > 0.f) ? 1.0f / sqrtf(fmaxf(s, 1e-12f)) : 0.f;
    }
    __syncthreads();
    for (int q = t; q < NFPS * NFPS; q += 256) {
        int i = q / NFPS, j = q % NFPS;
        Lf[(size_t)b * NFPS * NFPS + q] = ((i == j) ? 1.f : 0.f) - dist[q] * dinv[i] * dinv[j];
    }
}

// ---------------------------------------------------------------------------
// k_cheb6<N>: K=6 Chebyshev conv + relu + Z = L @ out.
// Grid (B, 4): each block owns a 64-wide output-column slice.
// Accumulators in VGPRs via compile-time-unrolled NITER loop (the R0 version
// had a runtime-bound loop -> dynamic indexing -> scratch spill -> 1.16 GB of
// HBM traffic per dispatch. Never again.)
// LDS: Ls[N*N] + bA/bB[N*64] + Ws[64*64]  (N=64 -> 64KB; N=55 -> ~56KB)
// ---------------------------------------------------------------------------
template<int N>
__global__ __launch_bounds__(256) void k_cheb6(const float* __restrict__ L,
                                               const float* __restrict__ V,
                                               const float* __restrict__ W,
                                               const float* __restrict__ bias,
                                               float* __restrict__ out,
                                               float* __restrict__ Z) {
    __shared__ float Ls[N * N];
    __shared__ float bA[N * 64];
    __shared__ float bB[N * 64];
    __shared__ float Ws[64 * 64];
    constexpr int NW = N * 64;                 // outputs per block (col slice)
    constexpr int NITER = (NW + 255) / 256;    // 16 (N=64) / 14 (N=55)
    int b = blockIdx.x;
    int o0 = blockIdx.y * 64;
    int t = threadIdx.x;

    for (int q = t; q < N * N; q += 256) Ls[q] = L[(size_t)b * N * N + q];
    for (int q = t; q < N * 64; q += 256) bA[q] = V[(size_t)b * N * 64 + q];
    // stage W slice for k=0
    {
        const float* Wk = W + o0;
        for (int q = t; q < 64 * 64; q += 256) Ws[q] = Wk[(q >> 6) * 256 + (q & 63)];
    }
    float a[NITER];
#pragma unroll
    for (int i = 0; i < NITER; ++i) {
        int q = t + i * 256;
        a[i] = (q < NW) ? bias[o0 + (q & 63)] : 0.f;
    }
    __syncthreads();

    auto accum = [&](const float* xb) {
#pragma unroll
        for (int i = 0; i < NITER; ++i) {
            int q = t + i * 256;
            if (q < NW) {
                int r = q >> 6, o = q & 63;
                float s = a[i];
#pragma unroll 8
                for (int m = 0; m < 64; ++m) s += xb[r * 64 + m] * Ws[m * 64 + o];
                a[i] = s;
            }
        }
    };
    // chebmm + stage next W slice (both write LDS regions not read by peers
    // until after the following barrier)
    auto chebmm = [&](const float* src, float* dst, bool first, int knext) {
        for (int q = t; q < N * 64; q += 256) {
            int r = q >> 6, c = q & 63;
            float s = 0.f;
            for (int m = 0; m < N; ++m) s += Ls[r * N + m] * src[m * 64 + c];
            dst[q] = first ? s : (2.f * s - dst[q]);   // dst[q] owner-only
        }
    };
    auto loadW = [&](int k) {
        const float* Wk = W + (size_t)k * 64 * 256 + o0;
        for (int q = t; q < 64 * 64; q += 256) Ws[q] = Wk[(q >> 6) * 256 + (q & 63)];
    };

    accum(bA);                 __syncthreads();   // uses Ws(k=0)
    chebmm(bA, bB, true, 1);   loadW(1);  __syncthreads();
    accum(bB);                 __syncthreads();
    chebmm(bB, bA, false, 2);  loadW(2);  __syncthreads();   // bA = xs2
    accum(bA);                 __syncthreads();
    chebmm(bA, bB, false, 3);  loadW(3);  __syncthreads();   // bB = xs3
    accum(bB);                 __syncthreads();
    chebmm(bB, bA, false, 4);  loadW(4);  __syncthreads();   // bA = xs4
    accum(bA);                 __syncthreads();
    chebmm(bA, bB, false, 5);  loadW(5);  __syncthreads();   // bB = xs5
    accum(bB);                 __syncthreads();

    // write relu(out) into bA (free now) for the Z pass + store to global
    float* ob = out + (size_t)b * N * 256 + o0;
#pragma unroll
    for (int i = 0; i < NITER; ++i) {
        int q = t + i * 256;
        if (q < NW) {
            int r = q >> 6, o = q & 63;
            float v = fmaxf(a[i], 0.f);
            bA[q] = v;
            ob[r * 256 + o] = v;
        }
    }
    __syncthreads();
    // Z[b, r, o0+o] = sum_m Ls[r,m] * relu_out[m, o]
    float* zb = Z + (size_t)b * N * 256 + o0;
    for (int q = t; q < N * 64; q += 256) {
        int r = q >> 6, o = q & 63;
        float s = 0.f;
        for (int m = 0; m < N; ++m) s += Ls[r * N + m] * bA[m * 64 + o];
        zb[r * 256 + o] = s;
    }
}

// ---------------------------------------------------------------------------
// k_treg<N>: reg += sum((out^T Z)^2), out/Z are (B,N,256).
// Grid (B, 8 f-tiles x 2 g-halves). LDS ~41KB.
// ---------------------------------------------------------------------------
template<int N>
__global__ __launch_bounds__(256) void k_treg(const float* __restrict__ out,
                                              const float* __restrict__ Z,
                                              float* __restrict__ reg) {
    __shared__ float zs[N * 128];
    __shared__ float os[N * 32];
    __shared__ float red[256];
    int b = blockIdx.x;
    int f0 = (blockIdx.y >> 1) * 32;
    int g0 = (blockIdx.y & 1) * 128;
    int t = threadIdx.x;
    for (int q = t; q < N * 128; q += 256) {
        int r = q >> 7, gl = q & 127;
        zs[q] = Z[(size_t)b * N * 256 + r * 256 + g0 + gl];
    }
    for (int q = t; q < N * 32; q += 256) {
        int r = q >> 5, f = q & 31;
        os[q] = out[(size_t)b * N * 256 + r * 256 + f0 + f];
    }
    __syncthreads();
    int fl = t >> 3;           // 0..31
    int gb = (t & 7) * 16;     // 0..112
    float accv[16];
#pragma unroll
    for (int q = 0; q < 16; ++q) accv[q] = 0.f;
    for (int n = 0; n < N; ++n) {
        float a = os[n * 32 + fl];
        const float* zr = zs + n * 128 + gb;
#pragma unroll
        for (int q = 0; q < 16; ++q) accv[q] += a * zr[q];
    }
    float loc = 0.f;
#pragma unroll
    for (int q = 0; q < 16; ++q) loc += accv[q] * accv[q];
    red[t] = loc; __syncthreads();
    for (int st = 128; st > 0; st >>= 1) { if (t < st) red[t] += red[t + st]; __syncthreads(); }
    if (t == 0) atomicAdd(reg, red[0]);
}

// ---------------------------------------------------------------------------
// k_tail: feature max-pool + 2-layer MLP -> logits
// ---------------------------------------------------------------------------
__global__ __launch_bounds__(256) void k_tail(const float* __restrict__ outR,
                                              const float* __restrict__ outP,
                                              const float* __restrict__ fc1_w,
                                              const float* __restrict__ fc1_b,
                                              const float* __restrict__ fc3_w,
                                              const float* __restrict__ fc3_b,
                                              float* __restrict__ logits) {
    __shared__ float feat[512];
    __shared__ float h[256];
    int b = blockIdx.x, t = threadIdx.x;
    float m = -__builtin_inff();
    for (int r = 0; r < NR; ++r) m = fmaxf(m, outR[((size_t)b * NR + r) * 256 + t]);
    feat[t] = m;
    m = -__builtin_inff();
    for (int p = 0; p < NFPS; ++p) m = fmaxf(m, outP[((size_t)b * NFPS + p) * 256 + t]);
    feat[256 + t] = m;
    __syncthreads();
    float a = fc1_b[t];
    for (int i = 0; i < 512; ++i) a += feat[i] * fc1_w[(size_t)i * 256 + t];
    h[t] = fmaxf(a, 0.f);
    __syncthreads();
    if (t < 40) {
        float a2 = fc3_b[t];
        for (int i = 0; i < 256; ++i) a2 += h[i] * fc3_w[(size_t)i * 40 + t];
        logits[(size_t)b * 40 + t] = a2;
    }
}

// ---------------------------------------------------------------------------
extern "C" void kernel_launch(void* const* d_in, const int* in_sizes, int n_in,
                              void* d_out, int out_size, void* d_ws, size_t ws_size,
                              hipStream_t stream) {
    const float* x      = (const float*)d_in[0];
    // d_in[1] (x2) unused by the reference
    const float* L_reeb = (const float*)d_in[2];
    const float* W1     = (const float*)d_in[3];
    const float* b1     = (const float*)d_in[4];
    const float* W_reeb = (const float*)d_in[5];
    const float* b_reeb = (const float*)d_in[6];
    const float* W_fps  = (const float*)d_in[7];
    const float* b_fps  = (const float*)d_in[8];
    const float* fc1_w  = (const float*)d_in[9];
    const float* fc1_b  = (const float*)d_in[10];
    const float* fc3_w  = (const float*)d_in[11];
    const float* fc3_b  = (const float*)d_in[12];
    const int*   sccs   = (const int*)d_in[13];
    const int*   sccs_f = (const int*)d_in[14];

    float* outv = (float*)d_out;          // 32*40 logits
    float* regs = outv + 1280;            // 7 regs

    char* w = (char*)d_ws;
    size_t off = 0;
    auto alloc = [&](size_t bytes) { void* p = w + off; off = (off + bytes + 255) & ~(size_t)255; return p; };
    int*   knn   = (int*)  alloc((size_t)BN * NP * KNN * 4);
    float* xs1   = (float*)alloc((size_t)BN * NP * 7 * 4);
    float* outF  = (float*)alloc((size_t)BN * NP * 64 * 4);
    float* Z1    = (float*)alloc((size_t)BN * NP * 64 * 4);
    float* Vreeb = (float*)alloc((size_t)BN * NR * 64 * 4);
    float* outRb = (float*)alloc((size_t)BN * NR * 256 * 4);
    float* Z2    = (float*)alloc((size_t)BN * NR * 256 * 4);
    float* Vfps  = (float*)alloc((size_t)BN * NFPS * 64 * 4);
    float* Lfps  = (float*)alloc((size_t)BN * NFPS * NFPS * 4);
    float* outP  = (float*)alloc((size_t)BN * NFPS * 256 * 4);
    float* Z3    = (float*)alloc((size_t)BN * NFPS * 256 * 4);

    k_init<<<1, 256, 0, stream>>>(fc1_w, fc1_b, fc3_w, fc3_b, regs);
    k_knn<<<dim3(BN, NP / 64), 64, 0, stream>>>(x, knn, xs1);
    k_out<<<dim3(BN, NP / 256), 256, 0, stream>>>(x, xs1, knn, W1, b1, outF);
    k_z1<<<dim3(BN, NP / 4), 256, 0, stream>>>(outF, knn, Z1);
    k_t1<<<dim3(BN, 2), 256, 0, stream>>>(outF, Z1, regs);
    k_vreeb<<<dim3(BN, NR / 4), 256, 0, stream>>>(outF, sccs, Vreeb);
    k_cheb6<NR><<<dim3(BN, 4), 256, 0, stream>>>(L_reeb, Vreeb, W_reeb, b_reeb, outRb, Z2);
    k_treg<NR><<<dim3(BN, 16), 256, 0, stream>>>(outRb, Z2, regs + 1);
    k_vfps<<<dim3(BN, NFPS), 256, 0, stream>>>(outF, sccs_f, Vfps);
    k_lfps<<<BN, 256, 0, stream>>>(Vfps, Lfps);
    k_cheb6<NFPS><<<dim3(BN, 4), 256, 0, stream>>>(Lfps, Vfps, W_fps, b_fps, outP, Z3);
    k_treg<NFPS><<<dim3(BN, 16), 256, 0, stream>>>(outP, Z3, regs + 2);
    k_tail<<<BN, 256, 0, stream>>>(outRb, outP, fc1_w, fc1_b, fc3_w, fc3_b, outv);
}

// Round 3
// 959.451 us; speedup vs baseline: 3.3239x; 1.5970x over previous
//
#include <hip/hip_runtime.h>
#include <math.h>

#define BN 32
#define NP 1024
#define KNN 30
#define NR 64
#define NFPS 55

// s = dinv*dinv with dinv = 1/sqrt(30) in f32, matching the reference's
// normalized laplacian (every kNN row-sum is exactly 30).
__device__ __forceinline__ float lap_s() {
    const float dv = 1.0f / sqrtf(30.0f);
    return dv * dv;
}

// ---------------------------------------------------------------------------
// k_init: zero the atomic reg accumulators and compute regs[3..6] directly.
// ---------------------------------------------------------------------------
__global__ __launch_bounds__(256) void k_init(const float* __restrict__ fc1_w,
                                              const float* __restrict__ fc1_b,
                                              const float* __restrict__ fc3_w,
                                              const float* __restrict__ fc3_b,
                                              float* __restrict__ regs) {
    __shared__ float r1[256], r2[256];
    int t = threadIdx.x;
    float s1 = 0.f;
    for (int i = t; i < 512; i += 256) { float v = fc1_w[(size_t)i * 256]; s1 += v * v; }
    float v2 = fc3_w[(size_t)t * 40];   // t < 256 covers all rows of fc3_w
    float s2 = v2 * v2;
    r1[t] = s1; r2[t] = s2;
    __syncthreads();
    for (int st = 128; st > 0; st >>= 1) {
        if (t < st) { r1[t] += r1[t + st]; r2[t] += r2[t + st]; }
        __syncthreads();
    }
    if (t == 0) {
        regs[0] = 0.f; regs[1] = 0.f; regs[2] = 0.f;
        regs[3] = r1[0];
        regs[4] = fc1_b[0] * fc1_b[0];
        regs[5] = r2[0];
        regs[6] = fc3_b[0] * fc3_b[0];
    }
}

// ---------------------------------------------------------------------------
// k_knn: 4 waves per block, each scans a 256-wide j-range keeping its local
// top-30 (dist,idx) with exact jax.lax.top_k tie order (strict-< insertion,
// ascending j within a range, ranges ascending by wave). Then a per-row
// 4-way lexicographic merge produces the global top-30, and a final phase
// computes xs1 = L @ x from the selected neighbors (global x, L1/L2-hot).
// LDS phase1: x padded to 8 floats/row with sq in slot 7 (2x ds_read_b128/j).
// LDS phase2 (union, after barrier): cd[64][121]f32 + ci[64][121]u16 + fin.
// ---------------------------------------------------------------------------
__global__ __launch_bounds__(256) void k_knn(const float* __restrict__ x,
                                             int* __restrict__ knn,
                                             float* __restrict__ xs1) {
    __shared__ float smem[12576];   // 49.1 KB, unioned phases
    int b = blockIdx.x;
    int t = threadIdx.x;
    const float* xb = x + (size_t)b * NP * 7;

    // ---- phase 1 load: xls[r*8 + d] (d<7 = x, d==7 = sq placeholder) ----
    float* xls = smem;              // [1024*8]
    for (int q = t; q < NP * 8; q += 256) {
        int r = q >> 3, d = q & 7;
        xls[q] = (d < 7) ? xb[r * 7 + d] : 0.f;
    }
    __syncthreads();
    for (int r = t; r < NP; r += 256) {
        float s = 0.f;
#pragma unroll
        for (int d = 0; d < 7; ++d) { float v = xls[r * 8 + d]; s += v * v; }
        xls[r * 8 + 7] = s;
    }
    __syncthreads();

    // ---- phase 1 scan: wave wv covers j in [wv*256, wv*256+256) ----
    int ln = t & 63, wv = t >> 6;
    int row = blockIdx.y * 64 + ln;
    float4 xiA = *(const float4*)&xls[row * 8];
    float4 xiB = *(const float4*)&xls[row * 8 + 4];
    float sqi = xiB.w;              // slot 7 = sq[row]
    float bd[KNN]; int bi[KNN];
#pragma unroll
    for (int q = 0; q < KNN; ++q) { bd[q] = __builtin_inff(); bi[q] = 0; }
    int jbase = wv * 256;
    for (int jj = 0; jj < 256; ++jj) {
        int j = jbase + jj;
        float4 ra = *(const float4*)&xls[j * 8];
        float4 rb = *(const float4*)&xls[j * 8 + 4];
        float dot = xiA.x * ra.x + xiA.y * ra.y + xiA.z * ra.z + xiA.w * ra.w
                  + xiB.x * rb.x + xiB.y * rb.y + xiB.z * rb.z;
        float dist = fmaxf(sqi + rb.w - 2.f * dot, 0.f);
        if (dist < bd[KNN - 1]) {
#pragma unroll
            for (int q = KNN - 1; q >= 1; --q) {
                if (bd[q - 1] > dist)      { bd[q] = bd[q - 1]; bi[q] = bi[q - 1]; }
                else if (bd[q] > dist)     { bd[q] = dist;      bi[q] = j; }
            }
            if (bd[0] > dist) { bd[0] = dist; bi[0] = j; }
        }
    }
    __syncthreads();   // all xls/sq reads done; smem reusable

    // ---- phase 2: write candidate lists ----
    float* cd = smem;                                   // [64*121] f32
    unsigned short* ci = (unsigned short*)(smem + 7744); // [64*121] u16
    unsigned short* fin = (unsigned short*)(smem + 11616); // [64*30] u16
    {
        int base = ln * 121 + wv * 30;
#pragma unroll
        for (int q = 0; q < KNN; ++q) { cd[base + q] = bd[q]; ci[base + q] = (unsigned short)bi[q]; }
    }
    __syncthreads();

    // ---- phase 3: per-row 4-way merge (threads 0..63) ----
    if (t < 64) {
        int p0 = 0, p1 = 0, p2 = 0, p3 = 0;
        int base = t * 121;
        int* kout = knn + ((size_t)b * NP + blockIdx.y * 64 + t) * KNN;
        for (int s = 0; s < KNN; ++s) {
            float best = cd[base + p0]; int bw = 0;
            float d1 = cd[base + 30 + p1]; if (d1 < best) { best = d1; bw = 1; }
            float d2 = cd[base + 60 + p2]; if (d2 < best) { best = d2; bw = 2; }
            float d3 = cd[base + 90 + p3]; if (d3 < best) { best = d3; bw = 3; }
            int off = (bw == 0) ? p0 : (bw == 1) ? 30 + p1 : (bw == 2) ? 60 + p2 : 90 + p3;
            int idx = ci[base + off];
            kout[s] = idx;
            fin[t * 30 + s] = (unsigned short)idx;
            p0 += (bw == 0); p1 += (bw == 1); p2 += (bw == 2); p3 += (bw == 3);
        }
    }
    __syncthreads();

    // ---- phase 4: xs1 = x - s * sum_{j in knn} x[j]  (global x, L1-hot) ----
    const float s = lap_s();
    for (int u = t; u < 64 * 7; u += 256) {
        int rl = u / 7, d = u % 7;
        int grow = blockIdx.y * 64 + rl;
        const unsigned short* fr = fin + rl * 30;
        float sum = 0.f;
        for (int q = 0; q < KNN; ++q) sum += xb[(size_t)fr[q] * 7 + d];
        xs1[((size_t)b * NP + grow) * 7 + d] = xb[(size_t)grow * 7 + d] - s * sum;
    }
}

// ---------------------------------------------------------------------------
// k_out: xs2 = 2 L xs1 - x, then out = relu([x|xs1|xs2] @ W1 + b1), (B,N,64).
// Two phases through LDS so the 64-wide store is coalesced.
// ---------------------------------------------------------------------------
__global__ __launch_bounds__(256) void k_out(const float* __restrict__ x,
                                             const float* __restrict__ xs1,
                                             const int* __restrict__ knn,
                                             const float* __restrict__ W1,
                                             const float* __restrict__ b1,
                                             float* __restrict__ out) {
    __shared__ float x1s[NP * 7];    // xs1 for ALL rows (neighbor gathers)
    __shared__ float x0s[256 * 7];   // x for this block's rows only
    __shared__ float fr[256 * 21];
    __shared__ float W1s[21 * 64];
    __shared__ float b1s[64];
    int b = blockIdx.x;
    int rbase = blockIdx.y * 256;
    int t = threadIdx.x;
    for (int q = t; q < NP * 7; q += 256) x1s[q] = xs1[(size_t)b * NP * 7 + q];
    for (int q = t; q < 256 * 7; q += 256) x0s[q] = x[(size_t)b * NP * 7 + (size_t)rbase * 7 + q];
    for (int q = t; q < 21 * 64; q += 256) W1s[q] = W1[q];
    if (t < 64) b1s[t] = b1[t];
    __syncthreads();
    {   // phase 1: per-row 21-feature vector
        int i = rbase + t;
        float f[21];
#pragma unroll
        for (int d = 0; d < 7; ++d) { f[d] = x0s[t * 7 + d]; f[7 + d] = x1s[i * 7 + d]; }
        float ns[7] = {0.f, 0.f, 0.f, 0.f, 0.f, 0.f, 0.f};
        const int* kn = knn + ((size_t)b * NP + i) * KNN;
        for (int q = 0; q < KNN; ++q) {
            int j = kn[q];
#pragma unroll
            for (int d = 0; d < 7; ++d) ns[d] += x1s[j * 7 + d];
        }
        const float s = lap_s();
#pragma unroll
        for (int d = 0; d < 7; ++d) f[14 + d] = 2.f * (f[7 + d] - s * ns[d]) - f[d];
#pragma unroll
        for (int d = 0; d < 21; ++d) fr[t * 21 + d] = f[d];
    }
    __syncthreads();
    // phase 2: (256 rows x 21) @ (21 x 64), coalesced store
    int o = t & 63, g = t >> 6;
    for (int m = 0; m < 64; ++m) {
        int r = g * 64 + m;
        float acc = b1s[o];
#pragma unroll
        for (int d = 0; d < 21; ++d) acc += fr[r * 21 + d] * W1s[d * 64 + o];
        out[((size_t)b * NP + rbase + r) * 64 + o] = fmaxf(acc, 0.f);
    }
}

// ---------------------------------------------------------------------------
// k_z1: Z1 = L @ out via kNN gathers (B,N,64).
// ---------------------------------------------------------------------------
__global__ __launch_bounds__(256) void k_z1(const float* __restrict__ out,
                                            const int* __restrict__ knn,
                                            float* __restrict__ Z1) {
    int b = blockIdx.x;
    int i = blockIdx.y * 4 + (threadIdx.x >> 6);
    int f = threadIdx.x & 63;
    const int* kn = knn + ((size_t)b * NP + i) * KNN;
    const float* ob = out + (size_t)b * NP * 64;
    float sum = 0.f;
    for (int q = 0; q < KNN; ++q) sum += ob[(size_t)kn[q] * 64 + f];
    Z1[((size_t)b * NP + i) * 64 + f] = ob[(size_t)i * 64 + f] - lap_s() * sum;
}

// ---------------------------------------------------------------------------
// k_t1: reg1 += sum((out^T Z1)^2) per batch. f-half per block, LDS chunks.
// ---------------------------------------------------------------------------
__global__ __launch_bounds__(256) void k_t1(const float* __restrict__ out,
                                            const float* __restrict__ Z1,
                                            float* __restrict__ regs) {
    __shared__ float os[64 * 64];
    __shared__ float zs[64 * 64];
    __shared__ float red[256];
    int b = blockIdx.x;
    int f0 = blockIdx.y * 32;
    int t = threadIdx.x;
    int fl = t >> 3;          // 0..31
    int gb = (t & 7) * 8;     // 0..56
    float acc[8];
#pragma unroll
    for (int q = 0; q < 8; ++q) acc[q] = 0.f;
    for (int c = 0; c < 16; ++c) {
        const float* ob = out + ((size_t)b * NP + c * 64) * 64;
        const float* zb = Z1 + ((size_t)b * NP + c * 64) * 64;
        for (int q = t; q < 64 * 64; q += 256) { os[q] = ob[q]; zs[q] = zb[q]; }
        __syncthreads();
        for (int n = 0; n < 64; ++n) {
            float a = os[n * 64 + f0 + fl];
#pragma unroll
            for (int q = 0; q < 8; ++q) acc[q] += a * zs[n * 64 + gb + q];
        }
        __syncthreads();
    }
    float loc = 0.f;
#pragma unroll
    for (int q = 0; q < 8; ++q) loc += acc[q] * acc[q];
    red[t] = loc; __syncthreads();
    for (int st = 128; st > 0; st >>= 1) { if (t < st) red[t] += red[t + st]; __syncthreads(); }
    if (t == 0) atomicAdd(&regs[0], red[0]);
}

// ---------------------------------------------------------------------------
// k_vreeb: V_reeb[b,r,f] = max_{s<16} out[b, sccs[b,r,s], f]
// ---------------------------------------------------------------------------
__global__ __launch_bounds__(256) void k_vreeb(const float* __restrict__ out,
                                               const int* __restrict__ sccs,
                                               float* __restrict__ V) {
    int b = blockIdx.x;
    int r = blockIdx.y * 4 + (threadIdx.x >> 6);
    int f = threadIdx.x & 63;
    const int* sc = sccs + ((size_t)b * NR + r) * 16;
    const float* ob = out + (size_t)b * NP * 64;
    float m = -__builtin_inff();
    for (int q = 0; q < 16; ++q) m = fmaxf(m, ob[(size_t)sc[q] * 64 + f]);
    V[((size_t)b * NR + r) * 64 + f] = m;
}

// ---------------------------------------------------------------------------
// k_vfps: V_fps[b,p,f] = max_{s<1024} out[b, sccs_fps[b,p,s], f]
// ---------------------------------------------------------------------------
__global__ __launch_bounds__(256) void k_vfps(const float* __restrict__ out,
                                              const int* __restrict__ sccs_fps,
                                              float* __restrict__ V) {
    __shared__ int idxs[1024];
    __shared__ float red[256];
    int b = blockIdx.x, p = blockIdx.y;
    int t = threadIdx.x;
    const int* sp = sccs_fps + ((size_t)b * NFPS + p) * 1024;
    for (int q = t; q < 1024; q += 256) idxs[q] = sp[q];
    __syncthreads();
    int f = t & 63, sc = t >> 6;
    const float* ob = out + (size_t)b * NP * 64;
    float m = -__builtin_inff();
    for (int s = sc; s < 1024; s += 4) m = fmaxf(m, ob[(size_t)idxs[s] * 64 + f]);
    red[t] = m; __syncthreads();
    if (sc == 0) {
        m = fmaxf(fmaxf(red[f], red[64 + f]), fmaxf(red[128 + f], red[192 + f]));
        V[((size_t)b * NFPS + p) * 64 + f] = m;
    }
}

// ---------------------------------------------------------------------------
// k_lfps: L_fps = I - D^{-1/2} dist D^{-1/2} on the pairwise-distance matrix
// of V_fps (55x55 per batch).
// ---------------------------------------------------------------------------
__global__ __launch_bounds__(256) void k_lfps(const float* __restrict__ V,
                                              float* __restrict__ Lf) {
    __shared__ float Vs[NFPS * 64];
    __shared__ float sq[NFPS];
    __shared__ float dist[NFPS * NFPS];
    __shared__ float dinv[NFPS];
    int b = blockIdx.x, t = threadIdx.x;
    for (int q = t; q < NFPS * 64; q += 256) Vs[q] = V[(size_t)b * NFPS * 64 + q];
    __syncthreads();
    if (t < NFPS) {
        float s = 0.f;
        for (int f = 0; f < 64; ++f) { float v = Vs[t * 64 + f]; s += v * v; }
        sq[t] = s;
    }
    __syncthreads();
    for (int q = t; q < NFPS * NFPS; q += 256) {
        int i = q / NFPS, j = q % NFPS;
        float dot = 0.f;
        for (int f = 0; f < 64; ++f) dot += Vs[i * 64 + f] * Vs[j * 64 + f];
        dist[q] = fmaxf(sq[i] + sq[j] - 2.f * dot, 0.f);
    }
    __syncthreads();
    if (t < NFPS) {
        float s = 0.f;
        for (int j = 0; j < NFPS; ++j) s += dist[t * NFPS + j];
        dinv[t] = (s > 0.f) ? 1.0f / sqrtf(fmaxf(s, 1e-12f)) : 0.f;
    }
    __syncthreads();
    for (int q = t; q < NFPS * NFPS; q += 256) {
        int i = q / NFPS, j = q % NFPS;
        Lf[(size_t)b * NFPS * NFPS + q] = ((i == j) ? 1.f : 0.f) - dist[q] * dinv[i] * dinv[j];
    }
}

// ---------------------------------------------------------------------------
// k_cheb6<N>: K=6 Chebyshev conv + relu + Z = L @ out.
// Grid (B, 4): each block owns a 64-wide output-column slice.
// Accumulators in VGPRs via compile-time-unrolled NITER loop.
// ---------------------------------------------------------------------------
template<int N>
__global__ __launch_bounds__(256) void k_cheb6(const float* __restrict__ L,
                                               const float* __restrict__ V,
                                               const float* __restrict__ W,
                                               const float* __restrict__ bias,
                                               float* __restrict__ out,
                                               float* __restrict__ Z) {
    __shared__ float Ls[N * N];
    __shared__ float bA[N * 64];
    __shared__ float bB[N * 64];
    __shared__ float Ws[64 * 64];
    constexpr int NW = N * 64;                 // outputs per block (col slice)
    constexpr int NITER = (NW + 255) / 256;    // 16 (N=64) / 14 (N=55)
    int b = blockIdx.x;
    int o0 = blockIdx.y * 64;
    int t = threadIdx.x;

    for (int q = t; q < N * N; q += 256) Ls[q] = L[(size_t)b * N * N + q];
    for (int q = t; q < N * 64; q += 256) bA[q] = V[(size_t)b * N * 64 + q];
    {
        const float* Wk = W + o0;
        for (int q = t; q < 64 * 64; q += 256) Ws[q] = Wk[(q >> 6) * 256 + (q & 63)];
    }
    float a[NITER];
#pragma unroll
    for (int i = 0; i < NITER; ++i) {
        int q = t + i * 256;
        a[i] = (q < NW) ? bias[o0 + (q & 63)] : 0.f;
    }
    __syncthreads();

    auto accum = [&](const float* xb) {
#pragma unroll
        for (int i = 0; i < NITER; ++i) {
            int q = t + i * 256;
            if (q < NW) {
                int r = q >> 6, o = q & 63;
                float s = a[i];
#pragma unroll 8
                for (int m = 0; m < 64; ++m) s += xb[r * 64 + m] * Ws[m * 64 + o];
                a[i] = s;
            }
        }
    };
    auto chebmm = [&](const float* src, float* dst, bool first) {
        for (int q = t; q < N * 64; q += 256) {
            int r = q >> 6, c = q & 63;
            float s = 0.f;
            for (int m = 0; m < N; ++m) s += Ls[r * N + m] * src[m * 64 + c];
            dst[q] = first ? s : (2.f * s - dst[q]);   // dst[q] owner-only
        }
    };
    auto loadW = [&](int k) {
        const float* Wk = W + (size_t)k * 64 * 256 + o0;
        for (int q = t; q < 64 * 64; q += 256) Ws[q] = Wk[(q >> 6) * 256 + (q & 63)];
    };

    accum(bA);                 __syncthreads();   // uses Ws(k=0)
    chebmm(bA, bB, true);      loadW(1);  __syncthreads();
    accum(bB);                 __syncthreads();
    chebmm(bB, bA, false);     loadW(2);  __syncthreads();   // bA = xs2
    accum(bA);                 __syncthreads();
    chebmm(bA, bB, false);     loadW(3);  __syncthreads();   // bB = xs3
    accum(bB);                 __syncthreads();
    chebmm(bB, bA, false);     loadW(4);  __syncthreads();   // bA = xs4
    accum(bA);                 __syncthreads();
    chebmm(bA, bB, false);     loadW(5);  __syncthreads();   // bB = xs5
    accum(bB);                 __syncthreads();

    float* ob = out + (size_t)b * N * 256 + o0;
#pragma unroll
    for (int i = 0; i < NITER; ++i) {
        int q = t + i * 256;
        if (q < NW) {
            int r = q >> 6, o = q & 63;
            float v = fmaxf(a[i], 0.f);
            bA[q] = v;
            ob[r * 256 + o] = v;
        }
    }
    __syncthreads();
    float* zb = Z + (size_t)b * N * 256 + o0;
    for (int q = t; q < N * 64; q += 256) {
        int r = q >> 6, o = q & 63;
        float s = 0.f;
        for (int m = 0; m < N; ++m) s += Ls[r * N + m] * bA[m * 64 + o];
        zb[r * 256 + o] = s;
    }
}

// ---------------------------------------------------------------------------
// k_treg<N>: reg += sum((out^T Z)^2), out/Z are (B,N,256).
// Grid (B, 8 f-tiles x 2 g-halves). LDS ~41KB.
// ---------------------------------------------------------------------------
template<int N>
__global__ __launch_bounds__(256) void k_treg(const float* __restrict__ out,
                                              const float* __restrict__ Z,
                                              float* __restrict__ reg) {
    __shared__ float zs[N * 128];
    __shared__ float os[N * 32];
    __shared__ float red[256];
    int b = blockIdx.x;
    int f0 = (blockIdx.y >> 1) * 32;
    int g0 = (blockIdx.y & 1) * 128;
    int t = threadIdx.x;
    for (int q = t; q < N * 128; q += 256) {
        int r = q >> 7, gl = q & 127;
        zs[q] = Z[(size_t)b * N * 256 + r * 256 + g0 + gl];
    }
    for (int q = t; q < N * 32; q += 256) {
        int r = q >> 5, f = q & 31;
        os[q] = out[(size_t)b * N * 256 + r * 256 + f0 + f];
    }
    __syncthreads();
    int fl = t >> 3;           // 0..31
    int gb = (t & 7) * 16;     // 0..112
    float accv[16];
#pragma unroll
    for (int q = 0; q < 16; ++q) accv[q] = 0.f;
    for (int n = 0; n < N; ++n) {
        float a = os[n * 32 + fl];
        const float* zr = zs + n * 128 + gb;
#pragma unroll
        for (int q = 0; q < 16; ++q) accv[q] += a * zr[q];
    }
    float loc = 0.f;
#pragma unroll
    for (int q = 0; q < 16; ++q) loc += accv[q] * accv[q];
    red[t] = loc; __syncthreads();
    for (int st = 128; st > 0; st >>= 1) { if (t < st) red[t] += red[t + st]; __syncthreads(); }
    if (t == 0) atomicAdd(reg, red[0]);
}

// ---------------------------------------------------------------------------
// k_tail: feature max-pool + 2-layer MLP -> logits
// ---------------------------------------------------------------------------
__global__ __launch_bounds__(256) void k_tail(const float* __restrict__ outR,
                                              const float* __restrict__ outP,
                                              const float* __restrict__ fc1_w,
                                              const float* __restrict__ fc1_b,
                                              const float* __restrict__ fc3_w,
                                              const float* __restrict__ fc3_b,
                                              float* __restrict__ logits) {
    __shared__ float feat[512];
    __shared__ float h[256];
    int b = blockIdx.x, t = threadIdx.x;
    float m = -__builtin_inff();
    for (int r = 0; r < NR; ++r) m = fmaxf(m, outR[((size_t)b * NR + r) * 256 + t]);
    feat[t] = m;
    m = -__builtin_inff();
    for (int p = 0; p < NFPS; ++p) m = fmaxf(m, outP[((size_t)b * NFPS + p) * 256 + t]);
    feat[256 + t] = m;
    __syncthreads();
    float a = fc1_b[t];
    for (int i = 0; i < 512; ++i) a += feat[i] * fc1_w[(size_t)i * 256 + t];
    h[t] = fmaxf(a, 0.f);
    __syncthreads();
    if (t < 40) {
        float a2 = fc3_b[t];
        for (int i = 0; i < 256; ++i) a2 += h[i] * fc3_w[(size_t)i * 40 + t];
        logits[(size_t)b * 40 + t] = a2;
    }
}

// ---------------------------------------------------------------------------
extern "C" void kernel_launch(void* const* d_in, const int* in_sizes, int n_in,
                              void* d_out, int out_size, void* d_ws, size_t ws_size,
                              hipStream_t stream) {
    const float* x      = (const float*)d_in[0];
    // d_in[1] (x2) unused by the reference
    const float* L_reeb = (const float*)d_in[2];
    const float* W1     = (const float*)d_in[3];
    const float* b1     = (const float*)d_in[4];
    const float* W_reeb = (const float*)d_in[5];
    const float* b_reeb = (const float*)d_in[6];
    const float* W_fps  = (const float*)d_in[7];
    const float* b_fps  = (const float*)d_in[8];
    const float* fc1_w  = (const float*)d_in[9];
    const float* fc1_b  = (const float*)d_in[10];
    const float* fc3_w  = (const float*)d_in[11];
    const float* fc3_b  = (const float*)d_in[12];
    const int*   sccs   = (const int*)d_in[13];
    const int*   sccs_f = (const int*)d_in[14];

    float* outv = (float*)d_out;          // 32*40 logits
    float* regs = outv + 1280;            // 7 regs

    char* w = (char*)d_ws;
    size_t off = 0;
    auto alloc = [&](size_t bytes) { void* p = w + off; off = (off + bytes + 255) & ~(size_t)255; return p; };
    int*   knn   = (int*)  alloc((size_t)BN * NP * KNN * 4);
    float* xs1   = (float*)alloc((size_t)BN * NP * 7 * 4);
    float* outF  = (float*)alloc((size_t)BN * NP * 64 * 4);
    float* Z1    = (float*)alloc((size_t)BN * NP * 64 * 4);
    float* Vreeb = (float*)alloc((size_t)BN * NR * 64 * 4);
    float* outRb = (float*)alloc((size_t)BN * NR * 256 * 4);
    float* Z2    = (float*)alloc((size_t)BN * NR * 256 * 4);
    float* Vfps  = (float*)alloc((size_t)BN * NFPS * 64 * 4);
    float* Lfps  = (float*)alloc((size_t)BN * NFPS * NFPS * 4);
    float* outP  = (float*)alloc((size_t)BN * NFPS * 256 * 4);
    float* Z3    = (float*)alloc((size_t)BN * NFPS * 256 * 4);

    k_init<<<1, 256, 0, stream>>>(fc1_w, fc1_b, fc3_w, fc3_b, regs);
    k_knn<<<dim3(BN, NP / 64), 256, 0, stream>>>(x, knn, xs1);
    k_out<<<dim3(BN, NP / 256), 256, 0, stream>>>(x, xs1, knn, W1, b1, outF);
    k_z1<<<dim3(BN, NP / 4), 256, 0, stream>>>(outF, knn, Z1);
    k_t1<<<dim3(BN, 2), 256, 0, stream>>>(outF, Z1, regs);
    k_vreeb<<<dim3(BN, NR / 4), 256, 0, stream>>>(outF, sccs, Vreeb);
    k_cheb6<NR><<<dim3(BN, 4), 256, 0, stream>>>(L_reeb, Vreeb, W_reeb, b_reeb, outRb, Z2);
    k_treg<NR><<<dim3(BN, 16), 256, 0, stream>>>(outRb, Z2, regs + 1);
    k_vfps<<<dim3(BN, NFPS), 256, 0, stream>>>(outF, sccs_f, Vfps);
    k_lfps<<<BN, 256, 0, stream>>>(Vfps, Lfps);
    k_cheb6<NFPS><<<dim3(BN, 4), 256, 0, stream>>>(Lfps, Vfps, W_fps, b_fps, outP, Z3);
    k_treg<NFPS><<<dim3(BN, 16), 256, 0, stream>>>(outP, Z3, regs + 2);
    k_tail<<<BN, 256, 0, stream>>>(outRb, outP, fc1_w, fc1_b, fc3_w, fc3_b, outv);
}

// Round 4
// 738.777 us; speedup vs baseline: 4.3168x; 1.2987x over previous
//
#include <hip/hip_runtime.h>
#include <math.h>

#define BN 32
#define NP 1024
#define KNN 30
#define NR 64
#define NFPS 55

// s = dinv*dinv with dinv = 1/sqrt(30) in f32, matching the reference's
// normalized laplacian (every kNN row-sum is exactly 30).
__device__ __forceinline__ float lap_s() {
    const float dv = 1.0f / sqrtf(30.0f);
    return dv * dv;
}

// ---------------------------------------------------------------------------
// k_init: zero the atomic reg accumulators and compute regs[3..6] directly.
// ---------------------------------------------------------------------------
__global__ __launch_bounds__(256) void k_init(const float* __restrict__ fc1_w,
                                              const float* __restrict__ fc1_b,
                                              const float* __restrict__ fc3_w,
                                              const float* __restrict__ fc3_b,
                                              float* __restrict__ regs) {
    __shared__ float r1[256], r2[256];
    int t = threadIdx.x;
    float s1 = 0.f;
    for (int i = t; i < 512; i += 256) { float v = fc1_w[(size_t)i * 256]; s1 += v * v; }
    float v2 = fc3_w[(size_t)t * 40];   // t < 256 covers all rows of fc3_w
    float s2 = v2 * v2;
    r1[t] = s1; r2[t] = s2;
    __syncthreads();
    for (int st = 128; st > 0; st >>= 1) {
        if (t < st) { r1[t] += r1[t + st]; r2[t] += r2[t + st]; }
        __syncthreads();
    }
    if (t == 0) {
        regs[0] = 0.f; regs[1] = 0.f; regs[2] = 0.f;
        regs[3] = r1[0];
        regs[4] = fc1_b[0] * fc1_b[0];
        regs[5] = r2[0];
        regs[6] = fc3_b[0] * fc3_b[0];
    }
}

// ---------------------------------------------------------------------------
// k_knn: branchless top-30 via med3 value-list + threshold rescan.
// One thread = one row; phase 1 keeps the 30 smallest DISTANCE VALUES with
// one v_med3_f32 per list slot per j (bd[q] = med3(bd[q-1], dist, bd[q]) is
// exactly sorted-insert-truncate when bd is ascending). Phase 2 rescans,
// emitting j with dist < T plus the first (30-c) ties dist==T in ascending j
// -- exactly the jax.lax.top_k (dist,idx)-lexicographic SET (downstream is
// permutation-invariant: neighbor sums only). xs1 = x - s*sum_nbr(x) fused.
// ---------------------------------------------------------------------------
__global__ __launch_bounds__(256) void k_knn(const float* __restrict__ x,
                                             int* __restrict__ knn,
                                             float* __restrict__ xs1) {
    __shared__ float xls[NP * 8];   // 32 KB: 7 features + sq in slot 7
    int b = blockIdx.x;
    int t = threadIdx.x;
    const float* xb = x + (size_t)b * NP * 7;
    for (int q = t; q < NP * 8; q += 256) {
        int r = q >> 3, d = q & 7;
        xls[q] = (d < 7) ? xb[r * 7 + d] : 0.f;
    }
    __syncthreads();
    for (int r = t; r < NP; r += 256) {
        float s = 0.f;
#pragma unroll
        for (int d = 0; d < 7; ++d) { float v = xls[r * 8 + d]; s += v * v; }
        xls[r * 8 + 7] = s;
    }
    __syncthreads();

    int row = blockIdx.y * 256 + t;
    float4 xiA = *(const float4*)&xls[row * 8];
    float4 xiB = *(const float4*)&xls[row * 8 + 4];
    float sqi = xiB.w;

    float bd[KNN];
#pragma unroll
    for (int q = 0; q < KNN; ++q) bd[q] = __builtin_inff();

    // ---- phase 1: branchless value top-30 (prefetch j+1) ----
    float4 ra = *(const float4*)&xls[0];
    float4 rb = *(const float4*)&xls[4];
    for (int j = 0; j < NP; ++j) {
        float4 ca = ra, cb = rb;
        if (j + 1 < NP) {
            ra = *(const float4*)&xls[(j + 1) * 8];
            rb = *(const float4*)&xls[(j + 1) * 8 + 4];
        }
        float dot = xiA.x * ca.x;
        dot = fmaf(xiA.y, ca.y, dot);
        dot = fmaf(xiA.z, ca.z, dot);
        dot = fmaf(xiA.w, ca.w, dot);
        dot = fmaf(xiB.x, cb.x, dot);
        dot = fmaf(xiB.y, cb.y, dot);
        dot = fmaf(xiB.z, cb.z, dot);
        float dist = fmaxf(sqi + cb.w - 2.f * dot, 0.f);
#pragma unroll
        for (int q = KNN - 1; q >= 1; --q)
            bd[q] = __builtin_amdgcn_fmed3f(bd[q - 1], dist, bd[q]);
        bd[0] = fminf(bd[0], dist);
    }

    float T = bd[KNN - 1];
    int c_exp = 0;
#pragma unroll
    for (int q = 0; q < KNN - 1; ++q) c_exp += (bd[q] < T) ? 1 : 0;
    int n_need = KNN - c_exp;    // ties to take (usually 1)

    // ---- phase 2: rescan, emit set + fused neighbor-sum ----
    int* kout = knn + ((size_t)b * NP + row) * KNN;
    float ns[7] = {0.f, 0.f, 0.f, 0.f, 0.f, 0.f, 0.f};
    int cs = 0, ct = 0;
    ra = *(const float4*)&xls[0];
    rb = *(const float4*)&xls[4];
    for (int j = 0; j < NP; ++j) {
        float4 ca = ra, cb = rb;
        if (j + 1 < NP) {
            ra = *(const float4*)&xls[(j + 1) * 8];
            rb = *(const float4*)&xls[(j + 1) * 8 + 4];
        }
        float dot = xiA.x * ca.x;
        dot = fmaf(xiA.y, ca.y, dot);
        dot = fmaf(xiA.z, ca.z, dot);
        dot = fmaf(xiA.w, ca.w, dot);
        dot = fmaf(xiB.x, cb.x, dot);
        dot = fmaf(xiB.y, cb.y, dot);
        dot = fmaf(xiB.z, cb.z, dot);
        float dist = fmaxf(sqi + cb.w - 2.f * dot, 0.f);
        bool lt = dist < T;
        bool eq = (dist == T) && (ct < n_need);
        if (lt || eq) {
            int pos = lt ? cs : (c_exp + ct);
            cs += lt ? 1 : 0;
            ct += eq ? 1 : 0;
            kout[pos] = j;
            ns[0] += ca.x; ns[1] += ca.y; ns[2] += ca.z; ns[3] += ca.w;
            ns[4] += cb.x; ns[5] += cb.y; ns[6] += cb.z;
        }
    }
    const float s = lap_s();
    float* xo = xs1 + ((size_t)b * NP + row) * 7;
#pragma unroll
    for (int d = 0; d < 7; ++d) xo[d] = xls[row * 8 + d] - s * ns[d];
}

// ---------------------------------------------------------------------------
// k_out: xs2 = 2 L xs1 - x, then out = relu([x|xs1|xs2] @ W1 + b1), (B,N,64).
// Two phases through LDS so the 64-wide store is coalesced.
// ---------------------------------------------------------------------------
__global__ __launch_bounds__(256) void k_out(const float* __restrict__ x,
                                             const float* __restrict__ xs1,
                                             const int* __restrict__ knn,
                                             const float* __restrict__ W1,
                                             const float* __restrict__ b1,
                                             float* __restrict__ out) {
    __shared__ float x1s[NP * 7];    // xs1 for ALL rows (neighbor gathers)
    __shared__ float x0s[256 * 7];   // x for this block's rows only
    __shared__ float fr[256 * 21];
    __shared__ float W1s[21 * 64];
    __shared__ float b1s[64];
    int b = blockIdx.x;
    int rbase = blockIdx.y * 256;
    int t = threadIdx.x;
    for (int q = t; q < NP * 7; q += 256) x1s[q] = xs1[(size_t)b * NP * 7 + q];
    for (int q = t; q < 256 * 7; q += 256) x0s[q] = x[(size_t)b * NP * 7 + (size_t)rbase * 7 + q];
    for (int q = t; q < 21 * 64; q += 256) W1s[q] = W1[q];
    if (t < 64) b1s[t] = b1[t];
    __syncthreads();
    {   // phase 1: per-row 21-feature vector
        int i = rbase + t;
        float f[21];
#pragma unroll
        for (int d = 0; d < 7; ++d) { f[d] = x0s[t * 7 + d]; f[7 + d] = x1s[i * 7 + d]; }
        float ns[7] = {0.f, 0.f, 0.f, 0.f, 0.f, 0.f, 0.f};
        const int* kn = knn + ((size_t)b * NP + i) * KNN;
        for (int q = 0; q < KNN; ++q) {
            int j = kn[q];
#pragma unroll
            for (int d = 0; d < 7; ++d) ns[d] += x1s[j * 7 + d];
        }
        const float s = lap_s();
#pragma unroll
        for (int d = 0; d < 7; ++d) f[14 + d] = 2.f * (f[7 + d] - s * ns[d]) - f[d];
#pragma unroll
        for (int d = 0; d < 21; ++d) fr[t * 21 + d] = f[d];
    }
    __syncthreads();
    // phase 2: (256 rows x 21) @ (21 x 64), coalesced store
    int o = t & 63, g = t >> 6;
    for (int m = 0; m < 64; ++m) {
        int r = g * 64 + m;
        float acc = b1s[o];
#pragma unroll
        for (int d = 0; d < 21; ++d) acc += fr[r * 21 + d] * W1s[d * 64 + o];
        out[((size_t)b * NP + rbase + r) * 64 + o] = fmaxf(acc, 0.f);
    }
}

// ---------------------------------------------------------------------------
// k_z1: Z1 = L @ out via kNN gathers (B,N,64).
// ---------------------------------------------------------------------------
__global__ __launch_bounds__(256) void k_z1(const float* __restrict__ out,
                                            const int* __restrict__ knn,
                                            float* __restrict__ Z1) {
    int b = blockIdx.x;
    int i = blockIdx.y * 4 + (threadIdx.x >> 6);
    int f = threadIdx.x & 63;
    const int* kn = knn + ((size_t)b * NP + i) * KNN;
    const float* ob = out + (size_t)b * NP * 64;
    float sum = 0.f;
    for (int q = 0; q < KNN; ++q) sum += ob[(size_t)kn[q] * 64 + f];
    Z1[((size_t)b * NP + i) * 64 + f] = ob[(size_t)i * 64 + f] - lap_s() * sum;
}

// ---------------------------------------------------------------------------
// k_t1: reg1 += sum((out^T Z1)^2) per batch. f-half per block, LDS chunks.
// ---------------------------------------------------------------------------
__global__ __launch_bounds__(256) void k_t1(const float* __restrict__ out,
                                            const float* __restrict__ Z1,
                                            float* __restrict__ regs) {
    __shared__ float os[64 * 64];
    __shared__ float zs[64 * 64];
    __shared__ float red[256];
    int b = blockIdx.x;
    int f0 = blockIdx.y * 32;
    int t = threadIdx.x;
    int fl = t >> 3;          // 0..31
    int gb = (t & 7) * 8;     // 0..56
    float acc[8];
#pragma unroll
    for (int q = 0; q < 8; ++q) acc[q] = 0.f;
    for (int c = 0; c < 16; ++c) {
        const float* ob = out + ((size_t)b * NP + c * 64) * 64;
        const float* zb = Z1 + ((size_t)b * NP + c * 64) * 64;
        for (int q = t; q < 64 * 64; q += 256) { os[q] = ob[q]; zs[q] = zb[q]; }
        __syncthreads();
        for (int n = 0; n < 64; ++n) {
            float a = os[n * 64 + f0 + fl];
#pragma unroll
            for (int q = 0; q < 8; ++q) acc[q] += a * zs[n * 64 + gb + q];
        }
        __syncthreads();
    }
    float loc = 0.f;
#pragma unroll
    for (int q = 0; q < 8; ++q) loc += acc[q] * acc[q];
    red[t] = loc; __syncthreads();
    for (int st = 128; st > 0; st >>= 1) { if (t < st) red[t] += red[t + st]; __syncthreads(); }
    if (t == 0) atomicAdd(&regs[0], red[0]);
}

// ---------------------------------------------------------------------------
// k_vreeb: V_reeb[b,r,f] = max_{s<16} out[b, sccs[b,r,s], f]
// ---------------------------------------------------------------------------
__global__ __launch_bounds__(256) void k_vreeb(const float* __restrict__ out,
                                               const int* __restrict__ sccs,
                                               float* __restrict__ V) {
    int b = blockIdx.x;
    int r = blockIdx.y * 4 + (threadIdx.x >> 6);
    int f = threadIdx.x & 63;
    const int* sc = sccs + ((size_t)b * NR + r) * 16;
    const float* ob = out + (size_t)b * NP * 64;
    float m = -__builtin_inff();
    for (int q = 0; q < 16; ++q) m = fmaxf(m, ob[(size_t)sc[q] * 64 + f]);
    V[((size_t)b * NR + r) * 64 + f] = m;
}

// ---------------------------------------------------------------------------
// k_vfps: V_fps[b,p,f] = max_{s<1024} out[b, sccs_fps[b,p,s], f]
// ---------------------------------------------------------------------------
__global__ __launch_bounds__(256) void k_vfps(const float* __restrict__ out,
                                              const int* __restrict__ sccs_fps,
                                              float* __restrict__ V) {
    __shared__ int idxs[1024];
    __shared__ float red[256];
    int b = blockIdx.x, p = blockIdx.y;
    int t = threadIdx.x;
    const int* sp = sccs_fps + ((size_t)b * NFPS + p) * 1024;
    for (int q = t; q < 1024; q += 256) idxs[q] = sp[q];
    __syncthreads();
    int f = t & 63, sc = t >> 6;
    const float* ob = out + (size_t)b * NP * 64;
    float m = -__builtin_inff();
    for (int s = sc; s < 1024; s += 4) m = fmaxf(m, ob[(size_t)idxs[s] * 64 + f]);
    red[t] = m; __syncthreads();
    if (sc == 0) {
        m = fmaxf(fmaxf(red[f], red[64 + f]), fmaxf(red[128 + f], red[192 + f]));
        V[((size_t)b * NFPS + p) * 64 + f] = m;
    }
}

// ---------------------------------------------------------------------------
// k_lfps: L_fps = I - D^{-1/2} dist D^{-1/2} on the pairwise-distance matrix
// of V_fps (55x55 per batch).
// ---------------------------------------------------------------------------
__global__ __launch_bounds__(256) void k_lfps(const float* __restrict__ V,
                                              float* __restrict__ Lf) {
    __shared__ float Vs[NFPS * 64];
    __shared__ float sq[NFPS];
    __shared__ float dist[NFPS * NFPS];
    __shared__ float dinv[NFPS];
    int b = blockIdx.x, t = threadIdx.x;
    for (int q = t; q < NFPS * 64; q += 256) Vs[q] = V[(size_t)b * NFPS * 64 + q];
    __syncthreads();
    if (t < NFPS) {
        float s = 0.f;
        for (int f = 0; f < 64; ++f) { float v = Vs[t * 64 + f]; s += v * v; }
        sq[t] = s;
    }
    __syncthreads();
    for (int q = t; q < NFPS * NFPS; q += 256) {
        int i = q / NFPS, j = q % NFPS;
        float dot = 0.f;
        for (int f = 0; f < 64; ++f) dot += Vs[i * 64 + f] * Vs[j * 64 + f];
        dist[q] = fmaxf(sq[i] + sq[j] - 2.f * dot, 0.f);
    }
    __syncthreads();
    if (t < NFPS) {
        float s = 0.f;
        for (int j = 0; j < NFPS; ++j) s += dist[t * NFPS + j];
        dinv[t] = (s > 0.f) ? 1.0f / sqrtf(fmaxf(s, 1e-12f)) : 0.f;
    }
    __syncthreads();
    for (int q = t; q < NFPS * NFPS; q += 256) {
        int i = q / NFPS, j = q % NFPS;
        Lf[(size_t)b * NFPS * NFPS + q] = ((i == j) ? 1.f : 0.f) - dist[q] * dinv[i] * dinv[j];
    }
}

// ---------------------------------------------------------------------------
// k_cheb6<N>: K=6 Chebyshev conv + relu + Z = L @ out.
// Grid (B, 4): each block owns a 64-wide output-column slice.
// Accumulators in VGPRs via compile-time-unrolled NITER loop.
// ---------------------------------------------------------------------------
template<int N>
__global__ __launch_bounds__(256) void k_cheb6(const float* __restrict__ L,
                                               const float* __restrict__ V,
                                               const float* __restrict__ W,
                                               const float* __restrict__ bias,
                                               float* __restrict__ out,
                                               float* __restrict__ Z) {
    __shared__ float Ls[N * N];
    __shared__ float bA[N * 64];
    __shared__ float bB[N * 64];
    __shared__ float Ws[64 * 64];
    constexpr int NW = N * 64;                 // outputs per block (col slice)
    constexpr int NITER = (NW + 255) / 256;    // 16 (N=64) / 14 (N=55)
    int b = blockIdx.x;
    int o0 = blockIdx.y * 64;
    int t = threadIdx.x;

    for (int q = t; q < N * N; q += 256) Ls[q] = L[(size_t)b * N * N + q];
    for (int q = t; q < N * 64; q += 256) bA[q] = V[(size_t)b * N * 64 + q];
    {
        const float* Wk = W + o0;
        for (int q = t; q < 64 * 64; q += 256) Ws[q] = Wk[(q >> 6) * 256 + (q & 63)];
    }
    float a[NITER];
#pragma unroll
    for (int i = 0; i < NITER; ++i) {
        int q = t + i * 256;
        a[i] = (q < NW) ? bias[o0 + (q & 63)] : 0.f;
    }
    __syncthreads();

    auto accum = [&](const float* xb) {
#pragma unroll
        for (int i = 0; i < NITER; ++i) {
            int q = t + i * 256;
            if (q < NW) {
                int r = q >> 6, o = q & 63;
                float s = a[i];
#pragma unroll 8
                for (int m = 0; m < 64; ++m) s += xb[r * 64 + m] * Ws[m * 64 + o];
                a[i] = s;
            }
        }
    };
    auto chebmm = [&](const float* src, float* dst, bool first) {
        for (int q = t; q < N * 64; q += 256) {
            int r = q >> 6, c = q & 63;
            float s = 0.f;
            for (int m = 0; m < N; ++m) s += Ls[r * N + m] * src[m * 64 + c];
            dst[q] = first ? s : (2.f * s - dst[q]);   // dst[q] owner-only
        }
    };
    auto loadW = [&](int k) {
        const float* Wk = W + (size_t)k * 64 * 256 + o0;
        for (int q = t; q < 64 * 64; q += 256) Ws[q] = Wk[(q >> 6) * 256 + (q & 63)];
    };

    accum(bA);                 __syncthreads();   // uses Ws(k=0)
    chebmm(bA, bB, true);      loadW(1);  __syncthreads();
    accum(bB);                 __syncthreads();
    chebmm(bB, bA, false);     loadW(2);  __syncthreads();   // bA = xs2
    accum(bA);                 __syncthreads();
    chebmm(bA, bB, false);     loadW(3);  __syncthreads();   // bB = xs3
    accum(bB);                 __syncthreads();
    chebmm(bB, bA, false);     loadW(4);  __syncthreads();   // bA = xs4
    accum(bA);                 __syncthreads();
    chebmm(bA, bB, false);     loadW(5);  __syncthreads();   // bB = xs5
    accum(bB);                 __syncthreads();

    float* ob = out + (size_t)b * N * 256 + o0;
#pragma unroll
    for (int i = 0; i < NITER; ++i) {
        int q = t + i * 256;
        if (q < NW) {
            int r = q >> 6, o = q & 63;
            float v = fmaxf(a[i], 0.f);
            bA[q] = v;
            ob[r * 256 + o] = v;
        }
    }
    __syncthreads();
    float* zb = Z + (size_t)b * N * 256 + o0;
    for (int q = t; q < N * 64; q += 256) {
        int r = q >> 6, o = q & 63;
        float s = 0.f;
        for (int m = 0; m < N; ++m) s += Ls[r * N + m] * bA[m * 64 + o];
        zb[r * 256 + o] = s;
    }
}

// ---------------------------------------------------------------------------
// k_treg<N>: reg += sum((out^T Z)^2), out/Z are (B,N,256).
// Grid (B, 8 f-tiles x 2 g-halves). LDS ~41KB.
// ---------------------------------------------------------------------------
template<int N>
__global__ __launch_bounds__(256) void k_treg(const float* __restrict__ out,
                                              const float* __restrict__ Z,
                                              float* __restrict__ reg) {
    __shared__ float zs[N * 128];
    __shared__ float os[N * 32];
    __shared__ float red[256];
    int b = blockIdx.x;
    int f0 = (blockIdx.y >> 1) * 32;
    int g0 = (blockIdx.y & 1) * 128;
    int t = threadIdx.x;
    for (int q = t; q < N * 128; q += 256) {
        int r = q >> 7, gl = q & 127;
        zs[q] = Z[(size_t)b * N * 256 + r * 256 + g0 + gl];
    }
    for (int q = t; q < N * 32; q += 256) {
        int r = q >> 5, f = q & 31;
        os[q] = out[(size_t)b * N * 256 + r * 256 + f0 + f];
    }
    __syncthreads();
    int fl = t >> 3;           // 0..31
    int gb = (t & 7) * 16;     // 0..112
    float accv[16];
#pragma unroll
    for (int q = 0; q < 16; ++q) accv[q] = 0.f;
    for (int n = 0; n < N; ++n) {
        float a = os[n * 32 + fl];
        const float* zr = zs + n * 128 + gb;
#pragma unroll
        for (int q = 0; q < 16; ++q) accv[q] += a * zr[q];
    }
    float loc = 0.f;
#pragma unroll
    for (int q = 0; q < 16; ++q) loc += accv[q] * accv[q];
    red[t] = loc; __syncthreads();
    for (int st = 128; st > 0; st >>= 1) { if (t < st) red[t] += red[t + st]; __syncthreads(); }
    if (t == 0) atomicAdd(reg, red[0]);
}

// ---------------------------------------------------------------------------
// k_tail: feature max-pool + 2-layer MLP -> logits
// ---------------------------------------------------------------------------
__global__ __launch_bounds__(256) void k_tail(const float* __restrict__ outR,
                                              const float* __restrict__ outP,
                                              const float* __restrict__ fc1_w,
                                              const float* __restrict__ fc1_b,
                                              const float* __restrict__ fc3_w,
                                              const float* __restrict__ fc3_b,
                                              float* __restrict__ logits) {
    __shared__ float feat[512];
    __shared__ float h[256];
    int b = blockIdx.x, t = threadIdx.x;
    float m = -__builtin_inff();
    for (int r = 0; r < NR; ++r) m = fmaxf(m, outR[((size_t)b * NR + r) * 256 + t]);
    feat[t] = m;
    m = -__builtin_inff();
    for (int p = 0; p < NFPS; ++p) m = fmaxf(m, outP[((size_t)b * NFPS + p) * 256 + t]);
    feat[256 + t] = m;
    __syncthreads();
    float a = fc1_b[t];
    for (int i = 0; i < 512; ++i) a += feat[i] * fc1_w[(size_t)i * 256 + t];
    h[t] = fmaxf(a, 0.f);
    __syncthreads();
    if (t < 40) {
        float a2 = fc3_b[t];
        for (int i = 0; i < 256; ++i) a2 += h[i] * fc3_w[(size_t)i * 40 + t];
        logits[(size_t)b * 40 + t] = a2;
    }
}

// ---------------------------------------------------------------------------
extern "C" void kernel_launch(void* const* d_in, const int* in_sizes, int n_in,
                              void* d_out, int out_size, void* d_ws, size_t ws_size,
                              hipStream_t stream) {
    const float* x      = (const float*)d_in[0];
    // d_in[1] (x2) unused by the reference
    const float* L_reeb = (const float*)d_in[2];
    const float* W1     = (const float*)d_in[3];
    const float* b1     = (const float*)d_in[4];
    const float* W_reeb = (const float*)d_in[5];
    const float* b_reeb = (const float*)d_in[6];
    const float* W_fps  = (const float*)d_in[7];
    const float* b_fps  = (const float*)d_in[8];
    const float* fc1_w  = (const float*)d_in[9];
    const float* fc1_b  = (const float*)d_in[10];
    const float* fc3_w  = (const float*)d_in[11];
    const float* fc3_b  = (const float*)d_in[12];
    const int*   sccs   = (const int*)d_in[13];
    const int*   sccs_f = (const int*)d_in[14];

    float* outv = (float*)d_out;          // 32*40 logits
    float* regs = outv + 1280;            // 7 regs

    char* w = (char*)d_ws;
    size_t off = 0;
    auto alloc = [&](size_t bytes) { void* p = w + off; off = (off + bytes + 255) & ~(size_t)255; return p; };
    int*   knn   = (int*)  alloc((size_t)BN * NP * KNN * 4);
    float* xs1   = (float*)alloc((size_t)BN * NP * 7 * 4);
    float* outF  = (float*)alloc((size_t)BN * NP * 64 * 4);
    float* Z1    = (float*)alloc((size_t)BN * NP * 64 * 4);
    float* Vreeb = (float*)alloc((size_t)BN * NR * 64 * 4);
    float* outRb = (float*)alloc((size_t)BN * NR * 256 * 4);
    float* Z2    = (float*)alloc((size_t)BN * NR * 256 * 4);
    float* Vfps  = (float*)alloc((size_t)BN * NFPS * 64 * 4);
    float* Lfps  = (float*)alloc((size_t)BN * NFPS * NFPS * 4);
    float* outP  = (float*)alloc((size_t)BN * NFPS * 256 * 4);
    float* Z3    = (float*)alloc((size_t)BN * NFPS * 256 * 4);

    k_init<<<1, 256, 0, stream>>>(fc1_w, fc1_b, fc3_w, fc3_b, regs);
    k_knn<<<dim3(BN, NP / 256), 256, 0, stream>>>(x, knn, xs1);
    k_out<<<dim3(BN, NP / 256), 256, 0, stream>>>(x, xs1, knn, W1, b1, outF);
    k_z1<<<dim3(BN, NP / 4), 256, 0, stream>>>(outF, knn, Z1);
    k_t1<<<dim3(BN, 2), 256, 0, stream>>>(outF, Z1, regs);
    k_vreeb<<<dim3(BN, NR / 4), 256, 0, stream>>>(outF, sccs, Vreeb);
    k_cheb6<NR><<<dim3(BN, 4), 256, 0, stream>>>(L_reeb, Vreeb, W_reeb, b_reeb, outRb, Z2);
    k_treg<NR><<<dim3(BN, 16), 256, 0, stream>>>(outRb, Z2, regs + 1);
    k_vfps<<<dim3(BN, NFPS), 256, 0, stream>>>(outF, sccs_f, Vfps);
    k_lfps<<<BN, 256, 0, stream>>>(Vfps, Lfps);
    k_cheb6<NFPS><<<dim3(BN, 4), 256, 0, stream>>>(Lfps, Vfps, W_fps, b_fps, outP, Z3);
    k_treg<NFPS><<<dim3(BN, 16), 256, 0, stream>>>(outP, Z3, regs + 2);
    k_tail<<<BN, 256, 0, stream>>>(outRb, outP, fc1_w, fc1_b, fc3_w, fc3_b, outv);
}

// Round 7
// 623.073 us; speedup vs baseline: 5.1184x; 1.1857x over previous
//
#include <hip/hip_runtime.h>
#include <math.h>

#define BN 32
#define NP 1024
#define KNN 30
#define NR 64
#define NFPS 55

// s = dinv*dinv with dinv = 1/sqrt(30) in f32, matching the reference's
// normalized laplacian (every kNN row-sum is exactly 30).
__device__ __forceinline__ float lap_s() {
    const float dv = 1.0f / sqrtf(30.0f);
    return dv * dv;
}

// Distance with ALL operations IEEE-pinned (contract off): guarantees the
// phase-A value and the phase-C recompute are bit-identical.
__device__ __forceinline__ float dist7(const float4& xiA, const float4& xiB,
                                       float sqi, const float4& ca, const float4& cb) {
#pragma clang fp contract(off)
    float dot = xiA.x * ca.x;
    dot = fmaf(xiA.y, ca.y, dot);
    dot = fmaf(xiA.z, ca.z, dot);
    dot = fmaf(xiA.w, ca.w, dot);
    dot = fmaf(xiB.x, cb.x, dot);
    dot = fmaf(xiB.y, cb.y, dot);
    dot = fmaf(xiB.z, cb.z, dot);
    float r = sqi + cb.w;
    r = r - 2.f * dot;
    return fmaxf(r, 0.f);
}

// ---------------------------------------------------------------------------
// k_init: zero the atomic reg accumulators and compute regs[3..6] directly.
// ---------------------------------------------------------------------------
__global__ __launch_bounds__(256) void k_init(const float* __restrict__ fc1_w,
                                              const float* __restrict__ fc1_b,
                                              const float* __restrict__ fc3_w,
                                              const float* __restrict__ fc3_b,
                                              float* __restrict__ regs) {
    __shared__ float r1[256], r2[256];
    int t = threadIdx.x;
    float s1 = 0.f;
    for (int i = t; i < 512; i += 256) { float v = fc1_w[(size_t)i * 256]; s1 += v * v; }
    float v2 = fc3_w[(size_t)t * 40];   // t < 256 covers all rows of fc3_w
    float s2 = v2 * v2;
    r1[t] = s1; r2[t] = s2;
    __syncthreads();
    for (int st = 128; st > 0; st >>= 1) {
        if (t < st) { r1[t] += r1[t + st]; r2[t] += r2[t + st]; }
        __syncthreads();
    }
    if (t == 0) {
        regs[0] = 0.f; regs[1] = 0.f; regs[2] = 0.f;
        regs[3] = r1[0];
        regs[4] = fc1_b[0] * fc1_b[0];
        regs[5] = r2[0];
        regs[6] = fc3_b[0] * fc3_b[0];
    }
}

// ---------------------------------------------------------------------------
// k_knn: 4 waves/row-group split over j, med3 value-only top-30 per wave,
// per-row 4-way VALUE merge (tie -> lowest wave = jax (dist,idx) order),
// per-wave threshold rescan emits its taken_w indices (set semantics:
// downstream only consumes neighbor SUMS). xs1 fused via per-wave partials.
// R6 bug was here: the final xs1 reduction used `if (t < 448)` in a
// 256-thread block -- dims 4..6 never written (kept 0xAA poison). Now a
// proper strided loop.
// ---------------------------------------------------------------------------
__global__ __launch_bounds__(256) void k_knn(const float* __restrict__ x,
                                             int* __restrict__ knn,
                                             float* __restrict__ xs1) {
    __shared__ float xls[NP * 8];          // 32768 B: 7 feats + sq in slot 7
    __shared__ float vals[4 * KNN * 64];   // 30720 B (ns-partial overlay later)
    __shared__ float Tm[4 * 64];           // per-(wave,row) threshold
    __shared__ int   Pk[4 * 64];           // base | (need<<8) | (tk<<16)
    int b = blockIdx.x;
    int t = threadIdx.x;
    int ln = t & 63, wv = t >> 6;
    const float* xb = x + (size_t)b * NP * 7;

    for (int q = t; q < NP * 8; q += 256) {
        int r = q >> 3, d = q & 7;
        xls[q] = (d < 7) ? xb[r * 7 + d] : 0.f;
    }
    __syncthreads();
    for (int r = t; r < NP; r += 256) {
        float s = 0.f;
#pragma unroll
        for (int d = 0; d < 7; ++d) { float v = xls[r * 8 + d]; s += v * v; }
        xls[r * 8 + 7] = s;
    }
    __syncthreads();

    int grow = blockIdx.y * 64 + ln;
    float4 xiA = *(const float4*)&xls[grow * 8];
    float4 xiB = *(const float4*)&xls[grow * 8 + 4];
    float sqi = xiB.w;

    // ---- phase A: wave-local branchless value top-30 over 256 j ----
    float bd[KNN];
#pragma unroll
    for (int q = 0; q < KNN; ++q) bd[q] = __builtin_inff();
    int jbase = wv * 256;
    float4 ra = *(const float4*)&xls[jbase * 8];
    float4 rb = *(const float4*)&xls[jbase * 8 + 4];
    for (int jj = 0; jj < 256; ++jj) {
        float4 ca = ra, cb = rb;
        if (jj + 1 < 256) {
            ra = *(const float4*)&xls[(jbase + jj + 1) * 8];
            rb = *(const float4*)&xls[(jbase + jj + 1) * 8 + 4];
        }
        float dist = dist7(xiA, xiB, sqi, ca, cb);
#pragma unroll
        for (int q = KNN - 1; q >= 1; --q)
            bd[q] = __builtin_amdgcn_fmed3f(bd[q - 1], dist, bd[q]);
        bd[0] = fminf(bd[0], dist);
    }
#pragma unroll
    for (int q = 0; q < KNN; ++q) vals[wv * (KNN * 64) + q * 64 + ln] = bd[q];
    __syncthreads();

    // ---- merge: one thread per row, 4-way value merge, tie -> lowest wave ----
    if (t < 64) {
        const float inf = __builtin_inff();
        float h0 = vals[0 * 1920 + t];
        float h1 = vals[1 * 1920 + t];
        float h2 = vals[2 * 1920 + t];
        float h3 = vals[3 * 1920 + t];
        int p0 = 0, p1 = 0, p2 = 0, p3 = 0;
        for (int s = 0; s < KNN; ++s) {
            float best = h0; int bw = 0;
            if (h1 < best) { best = h1; bw = 1; }
            if (h2 < best) { best = h2; bw = 2; }
            if (h3 < best) { best = h3; bw = 3; }
            if (bw == 0)      { ++p0; h0 = (p0 < KNN) ? vals[0 * 1920 + p0 * 64 + t] : inf; }
            else if (bw == 1) { ++p1; h1 = (p1 < KNN) ? vals[1 * 1920 + p1 * 64 + t] : inf; }
            else if (bw == 2) { ++p2; h2 = (p2 < KNN) ? vals[2 * 1920 + p2 * 64 + t] : inf; }
            else              { ++p3; h3 = (p3 < KNN) ? vals[3 * 1920 + p3 * 64 + t] : inf; }
        }
        int bacc = 0;
        int tks[4] = {p0, p1, p2, p3};
#pragma unroll
        for (int w = 0; w < 4; ++w) {
            int tk = tks[w];
            float T; int need;
            if (tk == 0) { T = -__builtin_inff(); need = 0; }
            else {
                T = vals[w * 1920 + (tk - 1) * 64 + t];
                need = 1;
                for (int q = tk - 2; q >= 0; --q) {
                    if (vals[w * 1920 + q * 64 + t] == T) ++need; else break;
                }
            }
            Tm[w * 64 + t] = T;
            Pk[w * 64 + t] = bacc | (need << 8) | (tk << 16);
            bacc += tk;
        }
    }
    __syncthreads();

    // ---- phase C: per-wave threshold rescan, emit + ns partials ----
    float Tw = Tm[wv * 64 + ln];
    int pk = Pk[wv * 64 + ln];
    int base = pk & 255, need = (pk >> 8) & 255, tk = pk >> 16;
    int* kout = knn + ((size_t)b * NP + grow) * KNN;
    float n0 = 0.f, n1 = 0.f, n2 = 0.f, n3 = 0.f, n4 = 0.f, n5 = 0.f, n6 = 0.f;
    int cs = 0, ct = 0;
    ra = *(const float4*)&xls[jbase * 8];
    rb = *(const float4*)&xls[jbase * 8 + 4];
    for (int jj = 0; jj < 256; ++jj) {
        float4 ca = ra, cb = rb;
        if (jj + 1 < 256) {
            ra = *(const float4*)&xls[(jbase + jj + 1) * 8];
            rb = *(const float4*)&xls[(jbase + jj + 1) * 8 + 4];
        }
        float dist = dist7(xiA, xiB, sqi, ca, cb);
        bool lt = dist < Tw;
        bool eq = (dist == Tw) && (ct < need);
        if ((lt || eq) && (cs + ct < tk)) {
            kout[base + cs + ct] = jbase + jj;
            cs += lt ? 1 : 0;
            ct += eq ? 1 : 0;
            n0 += ca.x; n1 += ca.y; n2 += ca.z; n3 += ca.w;
            n4 += cb.x; n5 += cb.y; n6 += cb.z;
        }
    }
    // safety net: fill any unwritten slots with self-index (bounded memory).
    for (int q = cs + ct; q < tk; ++q) kout[base + q] = grow;
    // ns partials overlay the (now-dead) vals region
    float* nsb = vals;
    nsb[wv * 448 + 0 * 64 + ln] = n0;
    nsb[wv * 448 + 1 * 64 + ln] = n1;
    nsb[wv * 448 + 2 * 64 + ln] = n2;
    nsb[wv * 448 + 3 * 64 + ln] = n3;
    nsb[wv * 448 + 4 * 64 + ln] = n4;
    nsb[wv * 448 + 5 * 64 + ln] = n5;
    nsb[wv * 448 + 6 * 64 + ln] = n6;
    __syncthreads();
    for (int u = t; u < 448; u += 256) {       // FIX: strided, covers all 448
        int d = u >> 6, rl = u & 63;
        float tot = nsb[d * 64 + rl] + nsb[448 + d * 64 + rl]
                  + nsb[896 + d * 64 + rl] + nsb[1344 + d * 64 + rl];
        int gr = blockIdx.y * 64 + rl;
        xs1[((size_t)b * NP + gr) * 7 + d] = xls[gr * 8 + d] - lap_s() * tot;
    }
}

// ---------------------------------------------------------------------------
// k_out: xs2 = 2 L xs1 - x, then out = relu([x|xs1|xs2] @ W1 + b1), (B,N,64).
// Two phases through LDS so the 64-wide store is coalesced.
// ---------------------------------------------------------------------------
__global__ __launch_bounds__(256) void k_out(const float* __restrict__ x,
                                             const float* __restrict__ xs1,
                                             const int* __restrict__ knn,
                                             const float* __restrict__ W1,
                                             const float* __restrict__ b1,
                                             float* __restrict__ out) {
    __shared__ float x1s[NP * 7];    // xs1 for ALL rows (neighbor gathers)
    __shared__ float x0s[256 * 7];   // x for this block's rows only
    __shared__ float fr[256 * 21];
    __shared__ float W1s[21 * 64];
    __shared__ float b1s[64];
    int b = blockIdx.x;
    int rbase = blockIdx.y * 256;
    int t = threadIdx.x;
    for (int q = t; q < NP * 7; q += 256) x1s[q] = xs1[(size_t)b * NP * 7 + q];
    for (int q = t; q < 256 * 7; q += 256) x0s[q] = x[(size_t)b * NP * 7 + (size_t)rbase * 7 + q];
    for (int q = t; q < 21 * 64; q += 256) W1s[q] = W1[q];
    if (t < 64) b1s[t] = b1[t];
    __syncthreads();
    {   // phase 1: per-row 21-feature vector
        int i = rbase + t;
        float f[21];
#pragma unroll
        for (int d = 0; d < 7; ++d) { f[d] = x0s[t * 7 + d]; f[7 + d] = x1s[i * 7 + d]; }
        float ns[7] = {0.f, 0.f, 0.f, 0.f, 0.f, 0.f, 0.f};
        const int* kn = knn + ((size_t)b * NP + i) * KNN;
        for (int q = 0; q < KNN; ++q) {
            int j = kn[q];
#pragma unroll
            for (int d = 0; d < 7; ++d) ns[d] += x1s[j * 7 + d];
        }
        const float s = lap_s();
#pragma unroll
        for (int d = 0; d < 7; ++d) f[14 + d] = 2.f * (f[7 + d] - s * ns[d]) - f[d];
#pragma unroll
        for (int d = 0; d < 21; ++d) fr[t * 21 + d] = f[d];
    }
    __syncthreads();
    // phase 2: (256 rows x 21) @ (21 x 64), coalesced store
    int o = t & 63, g = t >> 6;
    for (int m = 0; m < 64; ++m) {
        int r = g * 64 + m;
        float acc = b1s[o];
#pragma unroll
        for (int d = 0; d < 21; ++d) acc += fr[r * 21 + d] * W1s[d * 64 + o];
        out[((size_t)b * NP + rbase + r) * 64 + o] = fmaxf(acc, 0.f);
    }
}

// ---------------------------------------------------------------------------
// k_z1: Z1 = L @ out via kNN gathers (B,N,64).
// ---------------------------------------------------------------------------
__global__ __launch_bounds__(256) void k_z1(const float* __restrict__ out,
                                            const int* __restrict__ knn,
                                            float* __restrict__ Z1) {
    int b = blockIdx.x;
    int i = blockIdx.y * 4 + (threadIdx.x >> 6);
    int f = threadIdx.x & 63;
    const int* kn = knn + ((size_t)b * NP + i) * KNN;
    const float* ob = out + (size_t)b * NP * 64;
    float sum = 0.f;
    for (int q = 0; q < KNN; ++q) sum += ob[(size_t)kn[q] * 64 + f];
    Z1[((size_t)b * NP + i) * 64 + f] = ob[(size_t)i * 64 + f] - lap_s() * sum;
}

// ---------------------------------------------------------------------------
// k_t1: reg1 += sum((out^T Z1)^2) per batch. f-half per block, LDS chunks.
// ---------------------------------------------------------------------------
__global__ __launch_bounds__(256) void k_t1(const float* __restrict__ out,
                                            const float* __restrict__ Z1,
                                            float* __restrict__ regs) {
    __shared__ float os[64 * 64];
    __shared__ float zs[64 * 64];
    __shared__ float red[256];
    int b = blockIdx.x;
    int f0 = blockIdx.y * 32;
    int t = threadIdx.x;
    int fl = t >> 3;          // 0..31
    int gb = (t & 7) * 8;     // 0..56
    float acc[8];
#pragma unroll
    for (int q = 0; q < 8; ++q) acc[q] = 0.f;
    for (int c = 0; c < 16; ++c) {
        const float* ob = out + ((size_t)b * NP + c * 64) * 64;
        const float* zb = Z1 + ((size_t)b * NP + c * 64) * 64;
        for (int q = t; q < 64 * 64; q += 256) { os[q] = ob[q]; zs[q] = zb[q]; }
        __syncthreads();
        for (int n = 0; n < 64; ++n) {
            float a = os[n * 64 + f0 + fl];
#pragma unroll
            for (int q = 0; q < 8; ++q) acc[q] += a * zs[n * 64 + gb + q];
        }
        __syncthreads();
    }
    float loc = 0.f;
#pragma unroll
    for (int q = 0; q < 8; ++q) loc += acc[q] * acc[q];
    red[t] = loc; __syncthreads();
    for (int st = 128; st > 0; st >>= 1) { if (t < st) red[t] += red[t + st]; __syncthreads(); }
    if (t == 0) atomicAdd(&regs[0], red[0]);
}

// ---------------------------------------------------------------------------
// k_vreeb: V_reeb[b,r,f] = max_{s<16} out[b, sccs[b,r,s], f]
// ---------------------------------------------------------------------------
__global__ __launch_bounds__(256) void k_vreeb(const float* __restrict__ out,
                                               const int* __restrict__ sccs,
                                               float* __restrict__ V) {
    int b = blockIdx.x;
    int r = blockIdx.y * 4 + (threadIdx.x >> 6);
    int f = threadIdx.x & 63;
    const int* sc = sccs + ((size_t)b * NR + r) * 16;
    const float* ob = out + (size_t)b * NP * 64;
    float m = -__builtin_inff();
    for (int q = 0; q < 16; ++q) m = fmaxf(m, ob[(size_t)sc[q] * 64 + f]);
    V[((size_t)b * NR + r) * 64 + f] = m;
}

// ---------------------------------------------------------------------------
// k_vfps: V_fps[b,p,f] = max_{s<1024} out[b, sccs_fps[b,p,s], f]
// ---------------------------------------------------------------------------
__global__ __launch_bounds__(256) void k_vfps(const float* __restrict__ out,
                                              const int* __restrict__ sccs_fps,
                                              float* __restrict__ V) {
    __shared__ int idxs[1024];
    __shared__ float red[256];
    int b = blockIdx.x, p = blockIdx.y;
    int t = threadIdx.x;
    const int* sp = sccs_fps + ((size_t)b * NFPS + p) * 1024;
    for (int q = t; q < 1024; q += 256) idxs[q] = sp[q];
    __syncthreads();
    int f = t & 63, sc = t >> 6;
    const float* ob = out + (size_t)b * NP * 64;
    float m = -__builtin_inff();
    for (int s = sc; s < 1024; s += 4) m = fmaxf(m, ob[(size_t)idxs[s] * 64 + f]);
    red[t] = m; __syncthreads();
    if (sc == 0) {
        m = fmaxf(fmaxf(red[f], red[64 + f]), fmaxf(red[128 + f], red[192 + f]));
        V[((size_t)b * NFPS + p) * 64 + f] = m;
    }
}

// ---------------------------------------------------------------------------
// k_lfps: L_fps = I - D^{-1/2} dist D^{-1/2} on the pairwise-distance matrix
// of V_fps (55x55 per batch).
// ---------------------------------------------------------------------------
__global__ __launch_bounds__(256) void k_lfps(const float* __restrict__ V,
                                              float* __restrict__ Lf) {
    __shared__ float Vs[NFPS * 64];
    __shared__ float sq[NFPS];
    __shared__ float dist[NFPS * NFPS];
    __shared__ float dinv[NFPS];
    int b = blockIdx.x, t = threadIdx.x;
    for (int q = t; q < NFPS * 64; q += 256) Vs[q] = V[(size_t)b * NFPS * 64 + q];
    __syncthreads();
    if (t < NFPS) {
        float s = 0.f;
        for (int f = 0; f < 64; ++f) { float v = Vs[t * 64 + f]; s += v * v; }
        sq[t] = s;
    }
    __syncthreads();
    for (int q = t; q < NFPS * NFPS; q += 256) {
        int i = q / NFPS, j = q % NFPS;
        float dot = 0.f;
        for (int f = 0; f < 64; ++f) dot += Vs[i * 64 + f] * Vs[j * 64 + f];
        dist[q] = fmaxf(sq[i] + sq[j] - 2.f * dot, 0.f);
    }
    __syncthreads();
    if (t < NFPS) {
        float s = 0.f;
        for (int j = 0; j < NFPS; ++j) s += dist[t * NFPS + j];
        dinv[t] = (s > 0.f) ? 1.0f / sqrtf(fmaxf(s, 1e-12f)) : 0.f;
    }
    __syncthreads();
    for (int q = t; q < NFPS * NFPS; q += 256) {
        int i = q / NFPS, j = q % NFPS;
        Lf[(size_t)b * NFPS * NFPS + q] = ((i == j) ? 1.f : 0.f) - dist[q] * dinv[i] * dinv[j];
    }
}

// ---------------------------------------------------------------------------
// k_cheb6<N>: K=6 Chebyshev conv + relu + Z = L @ out.
// Grid (B, 4): each block owns a 64-wide output-column slice.
// Accumulators in VGPRs via compile-time-unrolled NITER loop.
// ---------------------------------------------------------------------------
template<int N>
__global__ __launch_bounds__(256) void k_cheb6(const float* __restrict__ L,
                                               const float* __restrict__ V,
                                               const float* __restrict__ W,
                                               const float* __restrict__ bias,
                                               float* __restrict__ out,
                                               float* __restrict__ Z) {
    __shared__ float Ls[N * N];
    __shared__ float bA[N * 64];
    __shared__ float bB[N * 64];
    __shared__ float Ws[64 * 64];
    constexpr int NW = N * 64;                 // outputs per block (col slice)
    constexpr int NITER = (NW + 255) / 256;    // 16 (N=64) / 14 (N=55)
    int b = blockIdx.x;
    int o0 = blockIdx.y * 64;
    int t = threadIdx.x;

    for (int q = t; q < N * N; q += 256) Ls[q] = L[(size_t)b * N * N + q];
    for (int q = t; q < N * 64; q += 256) bA[q] = V[(size_t)b * N * 64 + q];
    {
        const float* Wk = W + o0;
        for (int q = t; q < 64 * 64; q += 256) Ws[q] = Wk[(q >> 6) * 256 + (q & 63)];
    }
    float a[NITER];
#pragma unroll
    for (int i = 0; i < NITER; ++i) {
        int q = t + i * 256;
        a[i] = (q < NW) ? bias[o0 + (q & 63)] : 0.f;
    }
    __syncthreads();

    auto accum = [&](const float* xb) {
#pragma unroll
        for (int i = 0; i < NITER; ++i) {
            int q = t + i * 256;
            if (q < NW) {
                int r = q >> 6, o = q & 63;
                float s = a[i];
#pragma unroll 8
                for (int m = 0; m < 64; ++m) s += xb[r * 64 + m] * Ws[m * 64 + o];
                a[i] = s;
            }
        }
    };
    auto chebmm = [&](const float* src, float* dst, bool first) {
        for (int q = t; q < N * 64; q += 256) {
            int r = q >> 6, c = q & 63;
            float s = 0.f;
            for (int m = 0; m < N; ++m) s += Ls[r * N + m] * src[m * 64 + c];
            dst[q] = first ? s : (2.f * s - dst[q]);   // dst[q] owner-only
        }
    };
    auto loadW = [&](int k) {
        const float* Wk = W + (size_t)k * 64 * 256 + o0;
        for (int q = t; q < 64 * 64; q += 256) Ws[q] = Wk[(q >> 6) * 256 + (q & 63)];
    };

    accum(bA);                 __syncthreads();   // uses Ws(k=0)
    chebmm(bA, bB, true);      loadW(1);  __syncthreads();
    accum(bB);                 __syncthreads();
    chebmm(bB, bA, false);     loadW(2);  __syncthreads();   // bA = xs2
    accum(bA);                 __syncthreads();
    chebmm(bA, bB, false);     loadW(3);  __syncthreads();   // bB = xs3
    accum(bB);                 __syncthreads();
    chebmm(bB, bA, false);     loadW(4);  __syncthreads();   // bA = xs4
    accum(bA);                 __syncthreads();
    chebmm(bA, bB, false);     loadW(5);  __syncthreads();   // bB = xs5
    accum(bB);                 __syncthreads();

    float* ob = out + (size_t)b * N * 256 + o0;
#pragma unroll
    for (int i = 0; i < NITER; ++i) {
        int q = t + i * 256;
        if (q < NW) {
            int r = q >> 6, o = q & 63;
            float v = fmaxf(a[i], 0.f);
            bA[q] = v;
            ob[r * 256 + o] = v;
        }
    }
    __syncthreads();
    float* zb = Z + (size_t)b * N * 256 + o0;
    for (int q = t; q < N * 64; q += 256) {
        int r = q >> 6, o = q & 63;
        float s = 0.f;
        for (int m = 0; m < N; ++m) s += Ls[r * N + m] * bA[m * 64 + o];
        zb[r * 256 + o] = s;
    }
}

// ---------------------------------------------------------------------------
// k_treg<N>: reg += sum((out^T Z)^2), out/Z are (B,N,256).
// Grid (B, 8 f-tiles x 2 g-halves). LDS ~41KB.
// ---------------------------------------------------------------------------
template<int N>
__global__ __launch_bounds__(256) void k_treg(const float* __restrict__ out,
                                              const float* __restrict__ Z,
                                              float* __restrict__ reg) {
    __shared__ float zs[N * 128];
    __shared__ float os[N * 32];
    __shared__ float red[256];
    int b = blockIdx.x;
    int f0 = (blockIdx.y >> 1) * 32;
    int g0 = (blockIdx.y & 1) * 128;
    int t = threadIdx.x;
    for (int q = t; q < N * 128; q += 256) {
        int r = q >> 7, gl = q & 127;
        zs[q] = Z[(size_t)b * N * 256 + r * 256 + g0 + gl];
    }
    for (int q = t; q < N * 32; q += 256) {
        int r = q >> 5, f = q & 31;
        os[q] = out[(size_t)b * N * 256 + r * 256 + f0 + f];
    }
    __syncthreads();
    int fl = t >> 3;           // 0..31
    int gb = (t & 7) * 16;     // 0..112
    float accv[16];
#pragma unroll
    for (int q = 0; q < 16; ++q) accv[q] = 0.f;
    for (int n = 0; n < N; ++n) {
        float a = os[n * 32 + fl];
        const float* zr = zs + n * 128 + gb;
#pragma unroll
        for (int q = 0; q < 16; ++q) accv[q] += a * zr[q];
    }
    float loc = 0.f;
#pragma unroll
    for (int q = 0; q < 16; ++q) loc += accv[q] * accv[q];
    red[t] = loc; __syncthreads();
    for (int st = 128; st > 0; st >>= 1) { if (t < st) red[t] += red[t + st]; __syncthreads(); }
    if (t == 0) atomicAdd(reg, red[0]);
}

// ---------------------------------------------------------------------------
// k_tail: feature max-pool + 2-layer MLP -> logits
// ---------------------------------------------------------------------------
__global__ __launch_bounds__(256) void k_tail(const float* __restrict__ outR,
                                              const float* __restrict__ outP,
                                              const float* __restrict__ fc1_w,
                                              const float* __restrict__ fc1_b,
                                              const float* __restrict__ fc3_w,
                                              const float* __restrict__ fc3_b,
                                              float* __restrict__ logits) {
    __shared__ float feat[512];
    __shared__ float h[256];
    int b = blockIdx.x, t = threadIdx.x;
    float m = -__builtin_inff();
    for (int r = 0; r < NR; ++r) m = fmaxf(m, outR[((size_t)b * NR + r) * 256 + t]);
    feat[t] = m;
    m = -__builtin_inff();
    for (int p = 0; p < NFPS; ++p) m = fmaxf(m, outP[((size_t)b * NFPS + p) * 256 + t]);
    feat[256 + t] = m;
    __syncthreads();
    float a = fc1_b[t];
    for (int i = 0; i < 512; ++i) a += feat[i] * fc1_w[(size_t)i * 256 + t];
    h[t] = fmaxf(a, 0.f);
    __syncthreads();
    if (t < 40) {
        float a2 = fc3_b[t];
        for (int i = 0; i < 256; ++i) a2 += h[i] * fc3_w[(size_t)i * 40 + t];
        logits[(size_t)b * 40 + t] = a2;
    }
}

// ---------------------------------------------------------------------------
extern "C" void kernel_launch(void* const* d_in, const int* in_sizes, int n_in,
                              void* d_out, int out_size, void* d_ws, size_t ws_size,
                              hipStream_t stream) {
    const float* x      = (const float*)d_in[0];
    // d_in[1] (x2) unused by the reference
    const float* L_reeb = (const float*)d_in[2];
    const float* W1     = (const float*)d_in[3];
    const float* b1     = (const float*)d_in[4];
    const float* W_reeb = (const float*)d_in[5];
    const float* b_reeb = (const float*)d_in[6];
    const float* W_fps  = (const float*)d_in[7];
    const float* b_fps  = (const float*)d_in[8];
    const float* fc1_w  = (const float*)d_in[9];
    const float* fc1_b  = (const float*)d_in[10];
    const float* fc3_w  = (const float*)d_in[11];
    const float* fc3_b  = (const float*)d_in[12];
    const int*   sccs   = (const int*)d_in[13];
    const int*   sccs_f = (const int*)d_in[14];

    float* outv = (float*)d_out;          // 32*40 logits
    float* regs = outv + 1280;            // 7 regs

    char* w = (char*)d_ws;
    size_t off = 0;
    auto alloc = [&](size_t bytes) { void* p = w + off; off = (off + bytes + 255) & ~(size_t)255; return p; };
    int*   knn   = (int*)  alloc((size_t)BN * NP * KNN * 4);
    float* xs1   = (float*)alloc((size_t)BN * NP * 7 * 4);
    float* outF  = (float*)alloc((size_t)BN * NP * 64 * 4);
    float* Z1    = (float*)alloc((size_t)BN * NP * 64 * 4);
    float* Vreeb = (float*)alloc((size_t)BN * NR * 64 * 4);
    float* outRb = (float*)alloc((size_t)BN * NR * 256 * 4);
    float* Z2    = (float*)alloc((size_t)BN * NR * 256 * 4);
    float* Vfps  = (float*)alloc((size_t)BN * NFPS * 64 * 4);
    float* Lfps  = (float*)alloc((size_t)BN * NFPS * NFPS * 4);
    float* outP  = (float*)alloc((size_t)BN * NFPS * 256 * 4);
    float* Z3    = (float*)alloc((size_t)BN * NFPS * 256 * 4);

    k_init<<<1, 256, 0, stream>>>(fc1_w, fc1_b, fc3_w, fc3_b, regs);
    k_knn<<<dim3(BN, NP / 64), 256, 0, stream>>>(x, knn, xs1);
    k_out<<<dim3(BN, NP / 256), 256, 0, stream>>>(x, xs1, knn, W1, b1, outF);
    k_z1<<<dim3(BN, NP / 4), 256, 0, stream>>>(outF, knn, Z1);
    k_t1<<<dim3(BN, 2), 256, 0, stream>>>(outF, Z1, regs);
    k_vreeb<<<dim3(BN, NR / 4), 256, 0, stream>>>(outF, sccs, Vreeb);
    k_cheb6<NR><<<dim3(BN, 4), 256, 0, stream>>>(L_reeb, Vreeb, W_reeb, b_reeb, outRb, Z2);
    k_treg<NR><<<dim3(BN, 16), 256, 0, stream>>>(outRb, Z2, regs + 1);
    k_vfps<<<dim3(BN, NFPS), 256, 0, stream>>>(outF, sccs_f, Vfps);
    k_lfps<<<BN, 256, 0, stream>>>(Vfps, Lfps);
    k_cheb6<NFPS><<<dim3(BN, 4), 256, 0, stream>>>(Lfps, Vfps, W_fps, b_fps, outP, Z3);
    k_treg<NFPS><<<dim3(BN, 16), 256, 0, stream>>>(outP, Z3, regs + 2);
    k_tail<<<BN, 256, 0, stream>>>(outRb, outP, fc1_w, fc1_b, fc3_w, fc3_b, outv);
}

// Round 8
// 561.538 us; speedup vs baseline: 5.6793x; 1.1096x over previous
//
#include <hip/hip_runtime.h>
#include <math.h>

#define BN 32
#define NP 1024
#define KNN 30
#define NR 64
#define NFPS 55

// s = dinv*dinv with dinv = 1/sqrt(30) in f32, matching the reference's
// normalized laplacian (every kNN row-sum is exactly 30).
__device__ __forceinline__ float lap_s() {
    const float dv = 1.0f / sqrtf(30.0f);
    return dv * dv;
}

// Distance with ALL operations IEEE-pinned (contract off): guarantees the
// phase-A value and the phase-C recompute are bit-identical.
__device__ __forceinline__ float dist7(const float4& xiA, const float4& xiB,
                                       float sqi, const float4& ca, const float4& cb) {
#pragma clang fp contract(off)
    float dot = xiA.x * ca.x;
    dot = fmaf(xiA.y, ca.y, dot);
    dot = fmaf(xiA.z, ca.z, dot);
    dot = fmaf(xiA.w, ca.w, dot);
    dot = fmaf(xiB.x, cb.x, dot);
    dot = fmaf(xiB.y, cb.y, dot);
    dot = fmaf(xiB.z, cb.z, dot);
    float r = sqi + cb.w;
    r = r - 2.f * dot;
    return fmaxf(r, 0.f);
}

// ---------------------------------------------------------------------------
// k_init: zero the atomic reg accumulators and compute regs[3..6] directly.
// ---------------------------------------------------------------------------
__global__ __launch_bounds__(256) void k_init(const float* __restrict__ fc1_w,
                                              const float* __restrict__ fc1_b,
                                              const float* __restrict__ fc3_w,
                                              const float* __restrict__ fc3_b,
                                              float* __restrict__ regs) {
    __shared__ float r1[256], r2[256];
    int t = threadIdx.x;
    float s1 = 0.f;
    for (int i = t; i < 512; i += 256) { float v = fc1_w[(size_t)i * 256]; s1 += v * v; }
    float v2 = fc3_w[(size_t)t * 40];   // t < 256 covers all rows of fc3_w
    float s2 = v2 * v2;
    r1[t] = s1; r2[t] = s2;
    __syncthreads();
    for (int st = 128; st > 0; st >>= 1) {
        if (t < st) { r1[t] += r1[t + st]; r2[t] += r2[t + st]; }
        __syncthreads();
    }
    if (t == 0) {
        regs[0] = 0.f; regs[1] = 0.f; regs[2] = 0.f;
        regs[3] = r1[0];
        regs[4] = fc1_b[0] * fc1_b[0];
        regs[5] = r2[0];
        regs[6] = fc3_b[0] * fc3_b[0];
    }
}

// ---------------------------------------------------------------------------
// k_knn: 4 waves/row-group split over j, med3 value-only top-30 per wave,
// per-row 4-way VALUE merge (tie -> lowest wave = jax (dist,idx) order),
// per-wave threshold rescan emits its taken_w indices (set semantics).
// xs1 fused via per-wave partials.
// ---------------------------------------------------------------------------
__global__ __launch_bounds__(256) void k_knn(const float* __restrict__ x,
                                             int* __restrict__ knn,
                                             float* __restrict__ xs1) {
    __shared__ float xls[NP * 8];          // 32768 B: 7 feats + sq in slot 7
    __shared__ float vals[4 * KNN * 64];   // 30720 B (ns-partial overlay later)
    __shared__ float Tm[4 * 64];           // per-(wave,row) threshold
    __shared__ int   Pk[4 * 64];           // base | (need<<8) | (tk<<16)
    int b = blockIdx.x;
    int t = threadIdx.x;
    int ln = t & 63, wv = t >> 6;
    const float* xb = x + (size_t)b * NP * 7;

    for (int q = t; q < NP * 8; q += 256) {
        int r = q >> 3, d = q & 7;
        xls[q] = (d < 7) ? xb[r * 7 + d] : 0.f;
    }
    __syncthreads();
    for (int r = t; r < NP; r += 256) {
        float s = 0.f;
#pragma unroll
        for (int d = 0; d < 7; ++d) { float v = xls[r * 8 + d]; s += v * v; }
        xls[r * 8 + 7] = s;
    }
    __syncthreads();

    int grow = blockIdx.y * 64 + ln;
    float4 xiA = *(const float4*)&xls[grow * 8];
    float4 xiB = *(const float4*)&xls[grow * 8 + 4];
    float sqi = xiB.w;

    // ---- phase A: wave-local branchless value top-30 over 256 j ----
    float bd[KNN];
#pragma unroll
    for (int q = 0; q < KNN; ++q) bd[q] = __builtin_inff();
    int jbase = wv * 256;
    float4 ra = *(const float4*)&xls[jbase * 8];
    float4 rb = *(const float4*)&xls[jbase * 8 + 4];
    for (int jj = 0; jj < 256; ++jj) {
        float4 ca = ra, cb = rb;
        if (jj + 1 < 256) {
            ra = *(const float4*)&xls[(jbase + jj + 1) * 8];
            rb = *(const float4*)&xls[(jbase + jj + 1) * 8 + 4];
        }
        float dist = dist7(xiA, xiB, sqi, ca, cb);
#pragma unroll
        for (int q = KNN - 1; q >= 1; --q)
            bd[q] = __builtin_amdgcn_fmed3f(bd[q - 1], dist, bd[q]);
        bd[0] = fminf(bd[0], dist);
    }
#pragma unroll
    for (int q = 0; q < KNN; ++q) vals[wv * (KNN * 64) + q * 64 + ln] = bd[q];
    __syncthreads();

    // ---- merge: one thread per row, 4-way value merge, tie -> lowest wave ----
    if (t < 64) {
        const float inf = __builtin_inff();
        float h0 = vals[0 * 1920 + t];
        float h1 = vals[1 * 1920 + t];
        float h2 = vals[2 * 1920 + t];
        float h3 = vals[3 * 1920 + t];
        int p0 = 0, p1 = 0, p2 = 0, p3 = 0;
        for (int s = 0; s < KNN; ++s) {
            float best = h0; int bw = 0;
            if (h1 < best) { best = h1; bw = 1; }
            if (h2 < best) { best = h2; bw = 2; }
            if (h3 < best) { best = h3; bw = 3; }
            if (bw == 0)      { ++p0; h0 = (p0 < KNN) ? vals[0 * 1920 + p0 * 64 + t] : inf; }
            else if (bw == 1) { ++p1; h1 = (p1 < KNN) ? vals[1 * 1920 + p1 * 64 + t] : inf; }
            else if (bw == 2) { ++p2; h2 = (p2 < KNN) ? vals[2 * 1920 + p2 * 64 + t] : inf; }
            else              { ++p3; h3 = (p3 < KNN) ? vals[3 * 1920 + p3 * 64 + t] : inf; }
        }
        int bacc = 0;
        int tks[4] = {p0, p1, p2, p3};
#pragma unroll
        for (int w = 0; w < 4; ++w) {
            int tk = tks[w];
            float T; int need;
            if (tk == 0) { T = -__builtin_inff(); need = 0; }
            else {
                T = vals[w * 1920 + (tk - 1) * 64 + t];
                need = 1;
                for (int q = tk - 2; q >= 0; --q) {
                    if (vals[w * 1920 + q * 64 + t] == T) ++need; else break;
                }
            }
            Tm[w * 64 + t] = T;
            Pk[w * 64 + t] = bacc | (need << 8) | (tk << 16);
            bacc += tk;
        }
    }
    __syncthreads();

    // ---- phase C: per-wave threshold rescan, emit + ns partials ----
    float Tw = Tm[wv * 64 + ln];
    int pk = Pk[wv * 64 + ln];
    int base = pk & 255, need = (pk >> 8) & 255, tk = pk >> 16;
    int* kout = knn + ((size_t)b * NP + grow) * KNN;
    float n0 = 0.f, n1 = 0.f, n2 = 0.f, n3 = 0.f, n4 = 0.f, n5 = 0.f, n6 = 0.f;
    int cs = 0, ct = 0;
    ra = *(const float4*)&xls[jbase * 8];
    rb = *(const float4*)&xls[jbase * 8 + 4];
    for (int jj = 0; jj < 256; ++jj) {
        float4 ca = ra, cb = rb;
        if (jj + 1 < 256) {
            ra = *(const float4*)&xls[(jbase + jj + 1) * 8];
            rb = *(const float4*)&xls[(jbase + jj + 1) * 8 + 4];
        }
        float dist = dist7(xiA, xiB, sqi, ca, cb);
        bool lt = dist < Tw;
        bool eq = (dist == Tw) && (ct < need);
        if ((lt || eq) && (cs + ct < tk)) {
            kout[base + cs + ct] = jbase + jj;
            cs += lt ? 1 : 0;
            ct += eq ? 1 : 0;
            n0 += ca.x; n1 += ca.y; n2 += ca.z; n3 += ca.w;
            n4 += cb.x; n5 += cb.y; n6 += cb.z;
        }
    }
    // safety net: fill any unwritten slots with self-index (bounded memory).
    for (int q = cs + ct; q < tk; ++q) kout[base + q] = grow;
    // ns partials overlay the (now-dead) vals region
    float* nsb = vals;
    nsb[wv * 448 + 0 * 64 + ln] = n0;
    nsb[wv * 448 + 1 * 64 + ln] = n1;
    nsb[wv * 448 + 2 * 64 + ln] = n2;
    nsb[wv * 448 + 3 * 64 + ln] = n3;
    nsb[wv * 448 + 4 * 64 + ln] = n4;
    nsb[wv * 448 + 5 * 64 + ln] = n5;
    nsb[wv * 448 + 6 * 64 + ln] = n6;
    __syncthreads();
    for (int u = t; u < 448; u += 256) {       // strided: covers all 448
        int d = u >> 6, rl = u & 63;
        float tot = nsb[d * 64 + rl] + nsb[448 + d * 64 + rl]
                  + nsb[896 + d * 64 + rl] + nsb[1344 + d * 64 + rl];
        int gr = blockIdx.y * 64 + rl;
        xs1[((size_t)b * NP + gr) * 7 + d] = xls[gr * 8 + d] - lap_s() * tot;
    }
}

// ---------------------------------------------------------------------------
// k_out: xs2 = 2 L xs1 - x, then out = relu([x|xs1|xs2] @ W1 + b1), (B,N,64).
// ---------------------------------------------------------------------------
__global__ __launch_bounds__(256) void k_out(const float* __restrict__ x,
                                             const float* __restrict__ xs1,
                                             const int* __restrict__ knn,
                                             const float* __restrict__ W1,
                                             const float* __restrict__ b1,
                                             float* __restrict__ out) {
    __shared__ float x1s[NP * 7];    // xs1 for ALL rows (neighbor gathers)
    __shared__ float x0s[256 * 7];   // x for this block's rows only
    __shared__ float fr[256 * 21];
    __shared__ float W1s[21 * 64];
    __shared__ float b1s[64];
    int b = blockIdx.x;
    int rbase = blockIdx.y * 256;
    int t = threadIdx.x;
    for (int q = t; q < NP * 7; q += 256) x1s[q] = xs1[(size_t)b * NP * 7 + q];
    for (int q = t; q < 256 * 7; q += 256) x0s[q] = x[(size_t)b * NP * 7 + (size_t)rbase * 7 + q];
    for (int q = t; q < 21 * 64; q += 256) W1s[q] = W1[q];
    if (t < 64) b1s[t] = b1[t];
    __syncthreads();
    {   // phase 1: per-row 21-feature vector
        int i = rbase + t;
        float f[21];
#pragma unroll
        for (int d = 0; d < 7; ++d) { f[d] = x0s[t * 7 + d]; f[7 + d] = x1s[i * 7 + d]; }
        float ns[7] = {0.f, 0.f, 0.f, 0.f, 0.f, 0.f, 0.f};
        const int* kn = knn + ((size_t)b * NP + i) * KNN;
        for (int q = 0; q < KNN; ++q) {
            int j = kn[q];
#pragma unroll
            for (int d = 0; d < 7; ++d) ns[d] += x1s[j * 7 + d];
        }
        const float s = lap_s();
#pragma unroll
        for (int d = 0; d < 7; ++d) f[14 + d] = 2.f * (f[7 + d] - s * ns[d]) - f[d];
#pragma unroll
        for (int d = 0; d < 21; ++d) fr[t * 21 + d] = f[d];
    }
    __syncthreads();
    // phase 2: (256 rows x 21) @ (21 x 64), coalesced store
    int o = t & 63, g = t >> 6;
    for (int m = 0; m < 64; ++m) {
        int r = g * 64 + m;
        float acc = b1s[o];
#pragma unroll
        for (int d = 0; d < 21; ++d) acc += fr[r * 21 + d] * W1s[d * 64 + o];
        out[((size_t)b * NP + rbase + r) * 64 + o] = fmaxf(acc, 0.f);
    }
}

// ---------------------------------------------------------------------------
// k_z1: Z1 = L @ out via kNN gathers (B,N,64).
// ---------------------------------------------------------------------------
__global__ __launch_bounds__(256) void k_z1(const float* __restrict__ out,
                                            const int* __restrict__ knn,
                                            float* __restrict__ Z1) {
    int b = blockIdx.x;
    int i = blockIdx.y * 4 + (threadIdx.x >> 6);
    int f = threadIdx.x & 63;
    const int* kn = knn + ((size_t)b * NP + i) * KNN;
    const float* ob = out + (size_t)b * NP * 64;
    float sum = 0.f;
    for (int q = 0; q < KNN; ++q) sum += ob[(size_t)kn[q] * 64 + f];
    Z1[((size_t)b * NP + i) * 64 + f] = ob[(size_t)i * 64 + f] - lap_s() * sum;
}

// ---------------------------------------------------------------------------
// k_t1: reg1 += sum((out^T Z1)^2) per batch. f-half per block, LDS chunks.
// ---------------------------------------------------------------------------
__global__ __launch_bounds__(256) void k_t1(const float* __restrict__ out,
                                            const float* __restrict__ Z1,
                                            float* __restrict__ regs) {
    __shared__ float os[64 * 64];
    __shared__ float zs[64 * 64];
    __shared__ float red[256];
    int b = blockIdx.x;
    int f0 = blockIdx.y * 32;
    int t = threadIdx.x;
    int fl = t >> 3;          // 0..31
    int gb = (t & 7) * 8;     // 0..56
    float acc[8];
#pragma unroll
    for (int q = 0; q < 8; ++q) acc[q] = 0.f;
    for (int c = 0; c < 16; ++c) {
        const float* ob = out + ((size_t)b * NP + c * 64) * 64;
        const float* zb = Z1 + ((size_t)b * NP + c * 64) * 64;
        for (int q = t; q < 64 * 64; q += 256) { os[q] = ob[q]; zs[q] = zb[q]; }
        __syncthreads();
        for (int n = 0; n < 64; ++n) {
            float a = os[n * 64 + f0 + fl];
#pragma unroll
            for (int q = 0; q < 8; ++q) acc[q] += a * zs[n * 64 + gb + q];
        }
        __syncthreads();
    }
    float loc = 0.f;
#pragma unroll
    for (int q = 0; q < 8; ++q) loc += acc[q] * acc[q];
    red[t] = loc; __syncthreads();
    for (int st = 128; st > 0; st >>= 1) { if (t < st) red[t] += red[t + st]; __syncthreads(); }
    if (t == 0) atomicAdd(&regs[0], red[0]);
}

// ---------------------------------------------------------------------------
// k_vreeb: V_reeb[b,r,f] = max_{s<16} out[b, sccs[b,r,s], f]
// ---------------------------------------------------------------------------
__global__ __launch_bounds__(256) void k_vreeb(const float* __restrict__ out,
                                               const int* __restrict__ sccs,
                                               float* __restrict__ V) {
    int b = blockIdx.x;
    int r = blockIdx.y * 4 + (threadIdx.x >> 6);
    int f = threadIdx.x & 63;
    const int* sc = sccs + ((size_t)b * NR + r) * 16;
    const float* ob = out + (size_t)b * NP * 64;
    float m = -__builtin_inff();
    for (int q = 0; q < 16; ++q) m = fmaxf(m, ob[(size_t)sc[q] * 64 + f]);
    V[((size_t)b * NR + r) * 64 + f] = m;
}

// ---------------------------------------------------------------------------
// k_vfps: V_fps[b,p,f] = max_{s<1024} out[b, sccs_fps[b,p,s], f]
// ---------------------------------------------------------------------------
__global__ __launch_bounds__(256) void k_vfps(const float* __restrict__ out,
                                              const int* __restrict__ sccs_fps,
                                              float* __restrict__ V) {
    __shared__ int idxs[1024];
    __shared__ float red[256];
    int b = blockIdx.x, p = blockIdx.y;
    int t = threadIdx.x;
    const int* sp = sccs_fps + ((size_t)b * NFPS + p) * 1024;
    for (int q = t; q < 1024; q += 256) idxs[q] = sp[q];
    __syncthreads();
    int f = t & 63, sc = t >> 6;
    const float* ob = out + (size_t)b * NP * 64;
    float m = -__builtin_inff();
    for (int s = sc; s < 1024; s += 4) m = fmaxf(m, ob[(size_t)idxs[s] * 64 + f]);
    red[t] = m; __syncthreads();
    if (sc == 0) {
        m = fmaxf(fmaxf(red[f], red[64 + f]), fmaxf(red[128 + f], red[192 + f]));
        V[((size_t)b * NFPS + p) * 64 + f] = m;
    }
}

// ---------------------------------------------------------------------------
// k_lfps: L_fps = I - D^{-1/2} dist D^{-1/2} on the pairwise-distance matrix
// of V_fps (55x55 per batch).
// ---------------------------------------------------------------------------
__global__ __launch_bounds__(256) void k_lfps(const float* __restrict__ V,
                                              float* __restrict__ Lf) {
    __shared__ float Vs[NFPS * 64];
    __shared__ float sq[NFPS];
    __shared__ float dist[NFPS * NFPS];
    __shared__ float dinv[NFPS];
    int b = blockIdx.x, t = threadIdx.x;
    for (int q = t; q < NFPS * 64; q += 256) Vs[q] = V[(size_t)b * NFPS * 64 + q];
    __syncthreads();
    if (t < NFPS) {
        float s = 0.f;
        for (int f = 0; f < 64; ++f) { float v = Vs[t * 64 + f]; s += v * v; }
        sq[t] = s;
    }
    __syncthreads();
    for (int q = t; q < NFPS * NFPS; q += 256) {
        int i = q / NFPS, j = q % NFPS;
        float dot = 0.f;
        for (int f = 0; f < 64; ++f) dot += Vs[i * 64 + f] * Vs[j * 64 + f];
        dist[q] = fmaxf(sq[i] + sq[j] - 2.f * dot, 0.f);
    }
    __syncthreads();
    if (t < NFPS) {
        float s = 0.f;
        for (int j = 0; j < NFPS; ++j) s += dist[t * NFPS + j];
        dinv[t] = (s > 0.f) ? 1.0f / sqrtf(fmaxf(s, 1e-12f)) : 0.f;
    }
    __syncthreads();
    for (int q = t; q < NFPS * NFPS; q += 256) {
        int i = q / NFPS, j = q % NFPS;
        Lf[(size_t)b * NFPS * NFPS + q] = ((i == j) ? 1.f : 0.f) - dist[q] * dinv[i] * dinv[j];
    }
}

// ---------------------------------------------------------------------------
// cheb_impl<N>: K=6 Chebyshev conv + relu + Z = L @ out, for one batch and
// one 32-wide output-column slice. Shared LDS pointers passed in (the fused
// wrapper owns one 56KB static allocation sized for N=64).
// ---------------------------------------------------------------------------
template<int N>
__device__ __forceinline__ void cheb_impl(const float* __restrict__ L,
                                          const float* __restrict__ V,
                                          const float* __restrict__ W,
                                          const float* __restrict__ bias,
                                          float* __restrict__ out,
                                          float* __restrict__ Z,
                                          float* Ls, float* bA, float* bB, float* Ws,
                                          int b, int sl) {
    constexpr int OW = 32;
    constexpr int NW = N * OW;
    constexpr int NITER = (NW + 255) / 256;    // 8 (N=64) / 7 (N=55)
    int o0 = sl * OW;
    int t = threadIdx.x;

    for (int q = t; q < N * N; q += 256) Ls[q] = L[(size_t)b * N * N + q];
    for (int q = t; q < N * 64; q += 256) bA[q] = V[(size_t)b * N * 64 + q];
    {
        const float* Wk = W + o0;
        for (int q = t; q < 64 * OW; q += 256) Ws[q] = Wk[(q / OW) * 256 + (q % OW)];
    }
    float a[NITER];
#pragma unroll
    for (int i = 0; i < NITER; ++i) {
        int q = t + i * 256;
        a[i] = (q < NW) ? bias[o0 + (q % OW)] : 0.f;
    }
    __syncthreads();

    auto accum = [&](const float* xb) {
#pragma unroll
        for (int i = 0; i < NITER; ++i) {
            int q = t + i * 256;
            if (q < NW) {
                int r = q / OW, o = q % OW;
                float s = a[i];
#pragma unroll 8
                for (int m = 0; m < 64; ++m) s += xb[r * 64 + m] * Ws[m * OW + o];
                a[i] = s;
            }
        }
    };
    auto chebmm = [&](const float* src, float* dst, bool first) {
        for (int q = t; q < N * 64; q += 256) {
            int r = q >> 6, c = q & 63;
            float s = 0.f;
            for (int m = 0; m < N; ++m) s += Ls[r * N + m] * src[m * 64 + c];
            dst[q] = first ? s : (2.f * s - dst[q]);   // dst[q] owner-only
        }
    };
    auto loadW = [&](int k) {
        const float* Wk = W + (size_t)k * 64 * 256 + o0;
        for (int q = t; q < 64 * OW; q += 256) Ws[q] = Wk[(q / OW) * 256 + (q % OW)];
    };

    accum(bA);                 __syncthreads();   // uses Ws(k=0)
    chebmm(bA, bB, true);      loadW(1);  __syncthreads();
    accum(bB);                 __syncthreads();
    chebmm(bB, bA, false);     loadW(2);  __syncthreads();   // bA = xs2
    accum(bA);                 __syncthreads();
    chebmm(bA, bB, false);     loadW(3);  __syncthreads();   // bB = xs3
    accum(bB);                 __syncthreads();
    chebmm(bB, bA, false);     loadW(4);  __syncthreads();   // bA = xs4
    accum(bA);                 __syncthreads();
    chebmm(bA, bB, false);     loadW(5);  __syncthreads();   // bB = xs5
    accum(bB);                 __syncthreads();

    // relu -> store + stash slice in bB (N x OW) for the Z pass
    float* ob = out + (size_t)b * N * 256 + o0;
#pragma unroll
    for (int i = 0; i < NITER; ++i) {
        int q = t + i * 256;
        if (q < NW) {
            int r = q / OW, o = q % OW;
            float v = fmaxf(a[i], 0.f);
            bB[q] = v;
            ob[r * 256 + o] = v;
        }
    }
    __syncthreads();
    float* zb = Z + (size_t)b * N * 256 + o0;
    for (int q = t; q < NW; q += 256) {
        int r = q / OW, o = q % OW;
        float s = 0.f;
        for (int m = 0; m < N; ++m) s += Ls[r * N + m] * bB[m * OW + o];
        zb[r * 256 + o] = s;
    }
}

// Fused reeb+fps cheb conv. Grid (B, 16): y<8 -> reeb slice y, else fps y-8.
// LDS 57344 B -> 2 blocks/CU; 512 blocks -> all 256 CUs busy with overlap.
__global__ __launch_bounds__(256) void k_cheb_fused(
        const float* __restrict__ Lr, const float* __restrict__ Vr,
        const float* __restrict__ Wr, const float* __restrict__ br,
        float* __restrict__ outR, float* __restrict__ Zr,
        const float* __restrict__ Lf, const float* __restrict__ Vf,
        const float* __restrict__ Wf, const float* __restrict__ bf,
        float* __restrict__ outP, float* __restrict__ Zf) {
    __shared__ float Ls[64 * 64];
    __shared__ float bA[64 * 64];
    __shared__ float bB[64 * 64];
    __shared__ float Ws[64 * 32];
    int b = blockIdx.x, y = blockIdx.y;
    if (y < 8) cheb_impl<NR>(Lr, Vr, Wr, br, outR, Zr, Ls, bA, bB, Ws, b, y);
    else       cheb_impl<NFPS>(Lf, Vf, Wf, bf, outP, Zf, Ls, bA, bB, Ws, b, y - 8);
}

// ---------------------------------------------------------------------------
// treg_impl<N>: reg += sum((out^T Z)^2) for one (f-tile, g-half) pair.
// ---------------------------------------------------------------------------
template<int N>
__device__ __forceinline__ void treg_impl(const float* __restrict__ out,
                                          const float* __restrict__ Z,
                                          float* __restrict__ reg,
                                          float* zs, float* os, float* red, int y) {
    int b = blockIdx.x;
    int f0 = (y >> 1) * 32;
    int g0 = (y & 1) * 128;
    int t = threadIdx.x;
    for (int q = t; q < N * 128; q += 256) {
        int r = q >> 7, gl = q & 127;
        zs[q] = Z[(size_t)b * N * 256 + r * 256 + g0 + gl];
    }
    for (int q = t; q < N * 32; q += 256) {
        int r = q >> 5, f = q & 31;
        os[q] = out[(size_t)b * N * 256 + r * 256 + f0 + f];
    }
    __syncthreads();
    int fl = t >> 3;           // 0..31
    int gb = (t & 7) * 16;     // 0..112
    float accv[16];
#pragma unroll
    for (int q = 0; q < 16; ++q) accv[q] = 0.f;
    for (int n = 0; n < N; ++n) {
        float a = os[n * 32 + fl];
        const float* zr = zs + n * 128 + gb;
#pragma unroll
        for (int q = 0; q < 16; ++q) accv[q] += a * zr[q];
    }
    float loc = 0.f;
#pragma unroll
    for (int q = 0; q < 16; ++q) loc += accv[q] * accv[q];
    red[t] = loc; __syncthreads();
    for (int st = 128; st > 0; st >>= 1) { if (t < st) red[t] += red[t + st]; __syncthreads(); }
    if (t == 0) atomicAdd(reg, red[0]);
}

// Fused treg. Grid (B, 32): y<16 -> reeb (regs[1]), else fps (regs[2]).
__global__ __launch_bounds__(256) void k_treg_fused(
        const float* __restrict__ outR, const float* __restrict__ Zr,
        const float* __restrict__ outP, const float* __restrict__ Zf,
        float* __restrict__ regs) {
    __shared__ float zs[64 * 128];
    __shared__ float os[64 * 32];
    __shared__ float red[256];
    int y = blockIdx.y;
    if (y < 16) treg_impl<NR>(outR, Zr, regs + 1, zs, os, red, y);
    else        treg_impl<NFPS>(outP, Zf, regs + 2, zs, os, red, y - 16);
}

// ---------------------------------------------------------------------------
// k_tail: feature max-pool + 2-layer MLP -> logits
// ---------------------------------------------------------------------------
__global__ __launch_bounds__(256) void k_tail(const float* __restrict__ outR,
                                              const float* __restrict__ outP,
                                              const float* __restrict__ fc1_w,
                                              const float* __restrict__ fc1_b,
                                              const float* __restrict__ fc3_w,
                                              const float* __restrict__ fc3_b,
                                              float* __restrict__ logits) {
    __shared__ float feat[512];
    __shared__ float h[256];
    int b = blockIdx.x, t = threadIdx.x;
    float m = -__builtin_inff();
    for (int r = 0; r < NR; ++r) m = fmaxf(m, outR[((size_t)b * NR + r) * 256 + t]);
    feat[t] = m;
    m = -__builtin_inff();
    for (int p = 0; p < NFPS; ++p) m = fmaxf(m, outP[((size_t)b * NFPS + p) * 256 + t]);
    feat[256 + t] = m;
    __syncthreads();
    float a = fc1_b[t];
    for (int i = 0; i < 512; ++i) a += feat[i] * fc1_w[(size_t)i * 256 + t];
    h[t] = fmaxf(a, 0.f);
    __syncthreads();
    if (t < 40) {
        float a2 = fc3_b[t];
        for (int i = 0; i < 256; ++i) a2 += h[i] * fc3_w[(size_t)i * 40 + t];
        logits[(size_t)b * 40 + t] = a2;
    }
}

// ---------------------------------------------------------------------------
extern "C" void kernel_launch(void* const* d_in, const int* in_sizes, int n_in,
                              void* d_out, int out_size, void* d_ws, size_t ws_size,
                              hipStream_t stream) {
    const float* x      = (const float*)d_in[0];
    // d_in[1] (x2) unused by the reference
    const float* L_reeb = (const float*)d_in[2];
    const float* W1     = (const float*)d_in[3];
    const float* b1     = (const float*)d_in[4];
    const float* W_reeb = (const float*)d_in[5];
    const float* b_reeb = (const float*)d_in[6];
    const float* W_fps  = (const float*)d_in[7];
    const float* b_fps  = (const float*)d_in[8];
    const float* fc1_w  = (const float*)d_in[9];
    const float* fc1_b  = (const float*)d_in[10];
    const float* fc3_w  = (const float*)d_in[11];
    const float* fc3_b  = (const float*)d_in[12];
    const int*   sccs   = (const int*)d_in[13];
    const int*   sccs_f = (const int*)d_in[14];

    float* outv = (float*)d_out;          // 32*40 logits
    float* regs = outv + 1280;            // 7 regs

    char* w = (char*)d_ws;
    size_t off = 0;
    auto alloc = [&](size_t bytes) { void* p = w + off; off = (off + bytes + 255) & ~(size_t)255; return p; };
    int*   knn   = (int*)  alloc((size_t)BN * NP * KNN * 4);
    float* xs1   = (float*)alloc((size_t)BN * NP * 7 * 4);
    float* outF  = (float*)alloc((size_t)BN * NP * 64 * 4);
    float* Z1    = (float*)alloc((size_t)BN * NP * 64 * 4);
    float* Vreeb = (float*)alloc((size_t)BN * NR * 64 * 4);
    float* outRb = (float*)alloc((size_t)BN * NR * 256 * 4);
    float* Z2    = (float*)alloc((size_t)BN * NR * 256 * 4);
    float* Vfps  = (float*)alloc((size_t)BN * NFPS * 64 * 4);
    float* Lfps  = (float*)alloc((size_t)BN * NFPS * NFPS * 4);
    float* outP  = (float*)alloc((size_t)BN * NFPS * 256 * 4);
    float* Z3    = (float*)alloc((size_t)BN * NFPS * 256 * 4);

    k_init<<<1, 256, 0, stream>>>(fc1_w, fc1_b, fc3_w, fc3_b, regs);
    k_knn<<<dim3(BN, NP / 64), 256, 0, stream>>>(x, knn, xs1);
    k_out<<<dim3(BN, NP / 256), 256, 0, stream>>>(x, xs1, knn, W1, b1, outF);
    k_z1<<<dim3(BN, NP / 4), 256, 0, stream>>>(outF, knn, Z1);
    k_t1<<<dim3(BN, 2), 256, 0, stream>>>(outF, Z1, regs);
    k_vreeb<<<dim3(BN, NR / 4), 256, 0, stream>>>(outF, sccs, Vreeb);
    k_vfps<<<dim3(BN, NFPS), 256, 0, stream>>>(outF, sccs_f, Vfps);
    k_lfps<<<BN, 256, 0, stream>>>(Vfps, Lfps);
    k_cheb_fused<<<dim3(BN, 16), 256, 0, stream>>>(L_reeb, Vreeb, W_reeb, b_reeb, outRb, Z2,
                                                   Lfps, Vfps, W_fps, b_fps, outP, Z3);
    k_treg_fused<<<dim3(BN, 32), 256, 0, stream>>>(outRb, Z2, outP, Z3, regs);
    k_tail<<<BN, 256, 0, stream>>>(outRb, outP, fc1_w, fc1_b, fc3_w, fc3_b, outv);
}

// Round 9
// 468.945 us; speedup vs baseline: 6.8007x; 1.1974x over previous
//
#include <hip/hip_runtime.h>
#include <math.h>

#define BN 32
#define NP 1024
#define KNN 30
#define NR 64
#define NFPS 55

// s = dinv*dinv with dinv = 1/sqrt(30) in f32, matching the reference's
// normalized laplacian (every kNN row-sum is exactly 30).
__device__ __forceinline__ float lap_s() {
    const float dv = 1.0f / sqrtf(30.0f);
    return dv * dv;
}

// Distance with ALL operations IEEE-pinned (contract off): guarantees the
// phase-A value and the phase-C recompute are bit-identical.
__device__ __forceinline__ float dist7(const float4& xiA, const float4& xiB,
                                       float sqi, const float4& ca, const float4& cb) {
#pragma clang fp contract(off)
    float dot = xiA.x * ca.x;
    dot = fmaf(xiA.y, ca.y, dot);
    dot = fmaf(xiA.z, ca.z, dot);
    dot = fmaf(xiA.w, ca.w, dot);
    dot = fmaf(xiB.x, cb.x, dot);
    dot = fmaf(xiB.y, cb.y, dot);
    dot = fmaf(xiB.z, cb.z, dot);
    float r = sqi + cb.w;
    r = r - 2.f * dot;
    return fmaxf(r, 0.f);
}

// ---------------------------------------------------------------------------
// k_init: zero the atomic reg accumulators and compute regs[3..6] directly.
// ---------------------------------------------------------------------------
__global__ __launch_bounds__(256) void k_init(const float* __restrict__ fc1_w,
                                              const float* __restrict__ fc1_b,
                                              const float* __restrict__ fc3_w,
                                              const float* __restrict__ fc3_b,
                                              float* __restrict__ regs) {
    __shared__ float r1[256], r2[256];
    int t = threadIdx.x;
    float s1 = 0.f;
    for (int i = t; i < 512; i += 256) { float v = fc1_w[(size_t)i * 256]; s1 += v * v; }
    float v2 = fc3_w[(size_t)t * 40];   // t < 256 covers all rows of fc3_w
    float s2 = v2 * v2;
    r1[t] = s1; r2[t] = s2;
    __syncthreads();
    for (int st = 128; st > 0; st >>= 1) {
        if (t < st) { r1[t] += r1[t + st]; r2[t] += r2[t + st]; }
        __syncthreads();
    }
    if (t == 0) {
        regs[0] = 0.f; regs[1] = 0.f; regs[2] = 0.f;
        regs[3] = r1[0];
        regs[4] = fc1_b[0] * fc1_b[0];
        regs[5] = r2[0];
        regs[6] = fc3_b[0] * fc3_b[0];
    }
}

// ---------------------------------------------------------------------------
// k_knn: 4 waves/row-group split over j, med3 value-only top-30 per wave,
// per-row 4-way VALUE merge (tie -> lowest wave = jax (dist,idx) order),
// per-wave threshold rescan emits its taken_w indices (set semantics).
// xs1 fused via per-wave partials.
// ---------------------------------------------------------------------------
__global__ __launch_bounds__(256) void k_knn(const float* __restrict__ x,
                                             int* __restrict__ knn,
                                             float* __restrict__ xs1) {
    __shared__ float xls[NP * 8];          // 32768 B: 7 feats + sq in slot 7
    __shared__ float vals[4 * KNN * 64];   // 30720 B (ns-partial overlay later)
    __shared__ float Tm[4 * 64];           // per-(wave,row) threshold
    __shared__ int   Pk[4 * 64];           // base | (need<<8) | (tk<<16)
    int b = blockIdx.x;
    int t = threadIdx.x;
    int ln = t & 63, wv = t >> 6;
    const float* xb = x + (size_t)b * NP * 7;

    for (int q = t; q < NP * 8; q += 256) {
        int r = q >> 3, d = q & 7;
        xls[q] = (d < 7) ? xb[r * 7 + d] : 0.f;
    }
    __syncthreads();
    for (int r = t; r < NP; r += 256) {
        float s = 0.f;
#pragma unroll
        for (int d = 0; d < 7; ++d) { float v = xls[r * 8 + d]; s += v * v; }
        xls[r * 8 + 7] = s;
    }
    __syncthreads();

    int grow = blockIdx.y * 64 + ln;
    float4 xiA = *(const float4*)&xls[grow * 8];
    float4 xiB = *(const float4*)&xls[grow * 8 + 4];
    float sqi = xiB.w;

    // ---- phase A: wave-local branchless value top-30 over 256 j ----
    float bd[KNN];
#pragma unroll
    for (int q = 0; q < KNN; ++q) bd[q] = __builtin_inff();
    int jbase = wv * 256;
    float4 ra = *(const float4*)&xls[jbase * 8];
    float4 rb = *(const float4*)&xls[jbase * 8 + 4];
    for (int jj = 0; jj < 256; ++jj) {
        float4 ca = ra, cb = rb;
        if (jj + 1 < 256) {
            ra = *(const float4*)&xls[(jbase + jj + 1) * 8];
            rb = *(const float4*)&xls[(jbase + jj + 1) * 8 + 4];
        }
        float dist = dist7(xiA, xiB, sqi, ca, cb);
#pragma unroll
        for (int q = KNN - 1; q >= 1; --q)
            bd[q] = __builtin_amdgcn_fmed3f(bd[q - 1], dist, bd[q]);
        bd[0] = fminf(bd[0], dist);
    }
#pragma unroll
    for (int q = 0; q < KNN; ++q) vals[wv * (KNN * 64) + q * 64 + ln] = bd[q];
    __syncthreads();

    // ---- merge: one thread per row, 4-way value merge, tie -> lowest wave ----
    if (t < 64) {
        const float inf = __builtin_inff();
        float h0 = vals[0 * 1920 + t];
        float h1 = vals[1 * 1920 + t];
        float h2 = vals[2 * 1920 + t];
        float h3 = vals[3 * 1920 + t];
        int p0 = 0, p1 = 0, p2 = 0, p3 = 0;
        for (int s = 0; s < KNN; ++s) {
            float best = h0; int bw = 0;
            if (h1 < best) { best = h1; bw = 1; }
            if (h2 < best) { best = h2; bw = 2; }
            if (h3 < best) { best = h3; bw = 3; }
            if (bw == 0)      { ++p0; h0 = (p0 < KNN) ? vals[0 * 1920 + p0 * 64 + t] : inf; }
            else if (bw == 1) { ++p1; h1 = (p1 < KNN) ? vals[1 * 1920 + p1 * 64 + t] : inf; }
            else if (bw == 2) { ++p2; h2 = (p2 < KNN) ? vals[2 * 1920 + p2 * 64 + t] : inf; }
            else              { ++p3; h3 = (p3 < KNN) ? vals[3 * 1920 + p3 * 64 + t] : inf; }
        }
        int bacc = 0;
        int tks[4] = {p0, p1, p2, p3};
#pragma unroll
        for (int w = 0; w < 4; ++w) {
            int tk = tks[w];
            float T; int need;
            if (tk == 0) { T = -__builtin_inff(); need = 0; }
            else {
                T = vals[w * 1920 + (tk - 1) * 64 + t];
                need = 1;
                for (int q = tk - 2; q >= 0; --q) {
                    if (vals[w * 1920 + q * 64 + t] == T) ++need; else break;
                }
            }
            Tm[w * 64 + t] = T;
            Pk[w * 64 + t] = bacc | (need << 8) | (tk << 16);
            bacc += tk;
        }
    }
    __syncthreads();

    // ---- phase C: per-wave threshold rescan, emit + ns partials ----
    float Tw = Tm[wv * 64 + ln];
    int pk = Pk[wv * 64 + ln];
    int base = pk & 255, need = (pk >> 8) & 255, tk = pk >> 16;
    int* kout = knn + ((size_t)b * NP + grow) * KNN;
    float n0 = 0.f, n1 = 0.f, n2 = 0.f, n3 = 0.f, n4 = 0.f, n5 = 0.f, n6 = 0.f;
    int cs = 0, ct = 0;
    ra = *(const float4*)&xls[jbase * 8];
    rb = *(const float4*)&xls[jbase * 8 + 4];
    for (int jj = 0; jj < 256; ++jj) {
        float4 ca = ra, cb = rb;
        if (jj + 1 < 256) {
            ra = *(const float4*)&xls[(jbase + jj + 1) * 8];
            rb = *(const float4*)&xls[(jbase + jj + 1) * 8 + 4];
        }
        float dist = dist7(xiA, xiB, sqi, ca, cb);
        bool lt = dist < Tw;
        bool eq = (dist == Tw) && (ct < need);
        if ((lt || eq) && (cs + ct < tk)) {
            kout[base + cs + ct] = jbase + jj;
            cs += lt ? 1 : 0;
            ct += eq ? 1 : 0;
            n0 += ca.x; n1 += ca.y; n2 += ca.z; n3 += ca.w;
            n4 += cb.x; n5 += cb.y; n6 += cb.z;
        }
    }
    // safety net: fill any unwritten slots with self-index (bounded memory).
    for (int q = cs + ct; q < tk; ++q) kout[base + q] = grow;
    // ns partials overlay the (now-dead) vals region
    float* nsb = vals;
    nsb[wv * 448 + 0 * 64 + ln] = n0;
    nsb[wv * 448 + 1 * 64 + ln] = n1;
    nsb[wv * 448 + 2 * 64 + ln] = n2;
    nsb[wv * 448 + 3 * 64 + ln] = n3;
    nsb[wv * 448 + 4 * 64 + ln] = n4;
    nsb[wv * 448 + 5 * 64 + ln] = n5;
    nsb[wv * 448 + 6 * 64 + ln] = n6;
    __syncthreads();
    for (int u = t; u < 448; u += 256) {       // strided: covers all 448
        int d = u >> 6, rl = u & 63;
        float tot = nsb[d * 64 + rl] + nsb[448 + d * 64 + rl]
                  + nsb[896 + d * 64 + rl] + nsb[1344 + d * 64 + rl];
        int gr = blockIdx.y * 64 + rl;
        xs1[((size_t)b * NP + gr) * 7 + d] = xls[gr * 8 + d] - lap_s() * tot;
    }
}

// ---------------------------------------------------------------------------
// k_out: xs2 = 2 L xs1 - x, then out = relu([x|xs1|xs2] @ W1 + b1), (B,N,64).
// ---------------------------------------------------------------------------
__global__ __launch_bounds__(256) void k_out(const float* __restrict__ x,
                                             const float* __restrict__ xs1,
                                             const int* __restrict__ knn,
                                             const float* __restrict__ W1,
                                             const float* __restrict__ b1,
                                             float* __restrict__ out) {
    __shared__ float x1s[NP * 7];    // xs1 for ALL rows (neighbor gathers)
    __shared__ float x0s[256 * 7];   // x for this block's rows only
    __shared__ float fr[256 * 21];
    __shared__ float W1s[21 * 64];
    __shared__ float b1s[64];
    int b = blockIdx.x;
    int rbase = blockIdx.y * 256;
    int t = threadIdx.x;
    for (int q = t; q < NP * 7; q += 256) x1s[q] = xs1[(size_t)b * NP * 7 + q];
    for (int q = t; q < 256 * 7; q += 256) x0s[q] = x[(size_t)b * NP * 7 + (size_t)rbase * 7 + q];
    for (int q = t; q < 21 * 64; q += 256) W1s[q] = W1[q];
    if (t < 64) b1s[t] = b1[t];
    __syncthreads();
    {   // phase 1: per-row 21-feature vector
        int i = rbase + t;
        float f[21];
#pragma unroll
        for (int d = 0; d < 7; ++d) { f[d] = x0s[t * 7 + d]; f[7 + d] = x1s[i * 7 + d]; }
        float ns[7] = {0.f, 0.f, 0.f, 0.f, 0.f, 0.f, 0.f};
        const int* kn = knn + ((size_t)b * NP + i) * KNN;
        for (int q = 0; q < KNN; ++q) {
            int j = kn[q];
#pragma unroll
            for (int d = 0; d < 7; ++d) ns[d] += x1s[j * 7 + d];
        }
        const float s = lap_s();
#pragma unroll
        for (int d = 0; d < 7; ++d) f[14 + d] = 2.f * (f[7 + d] - s * ns[d]) - f[d];
#pragma unroll
        for (int d = 0; d < 21; ++d) fr[t * 21 + d] = f[d];
    }
    __syncthreads();
    // phase 2: (256 rows x 21) @ (21 x 64), coalesced store
    int o = t & 63, g = t >> 6;
    for (int m = 0; m < 64; ++m) {
        int r = g * 64 + m;
        float acc = b1s[o];
#pragma unroll
        for (int d = 0; d < 21; ++d) acc += fr[r * 21 + d] * W1s[d * 64 + o];
        out[((size_t)b * NP + rbase + r) * 64 + o] = fmaxf(acc, 0.f);
    }
}

// ---------------------------------------------------------------------------
// k_z1: Z1 = L @ out via kNN gathers (B,N,64).
// ---------------------------------------------------------------------------
__global__ __launch_bounds__(256) void k_z1(const float* __restrict__ out,
                                            const int* __restrict__ knn,
                                            float* __restrict__ Z1) {
    int b = blockIdx.x;
    int i = blockIdx.y * 4 + (threadIdx.x >> 6);
    int f = threadIdx.x & 63;
    const int* kn = knn + ((size_t)b * NP + i) * KNN;
    const float* ob = out + (size_t)b * NP * 64;
    float sum = 0.f;
    for (int q = 0; q < KNN; ++q) sum += ob[(size_t)kn[q] * 64 + f];
    Z1[((size_t)b * NP + i) * 64 + f] = ob[(size_t)i * 64 + f] - lap_s() * sum;
}

// ---------------------------------------------------------------------------
// k_t1: reg1 += sum((out^T Z1)^2) per batch. f-half per block, LDS chunks.
// ---------------------------------------------------------------------------
__global__ __launch_bounds__(256) void k_t1(const float* __restrict__ out,
                                            const float* __restrict__ Z1,
                                            float* __restrict__ regs) {
    __shared__ float os[64 * 64];
    __shared__ float zs[64 * 64];
    __shared__ float red[256];
    int b = blockIdx.x;
    int f0 = blockIdx.y * 32;
    int t = threadIdx.x;
    int fl = t >> 3;          // 0..31
    int gb = (t & 7) * 8;     // 0..56
    float acc[8];
#pragma unroll
    for (int q = 0; q < 8; ++q) acc[q] = 0.f;
    for (int c = 0; c < 16; ++c) {
        const float* ob = out + ((size_t)b * NP + c * 64) * 64;
        const float* zb = Z1 + ((size_t)b * NP + c * 64) * 64;
        for (int q = t; q < 64 * 64; q += 256) { os[q] = ob[q]; zs[q] = zb[q]; }
        __syncthreads();
        for (int n = 0; n < 64; ++n) {
            float a = os[n * 64 + f0 + fl];
#pragma unroll
            for (int q = 0; q < 8; ++q) acc[q] += a * zs[n * 64 + gb + q];
        }
        __syncthreads();
    }
    float loc = 0.f;
#pragma unroll
    for (int q = 0; q < 8; ++q) loc += acc[q] * acc[q];
    red[t] = loc; __syncthreads();
    for (int st = 128; st > 0; st >>= 1) { if (t < st) red[t] += red[t + st]; __syncthreads(); }
    if (t == 0) atomicAdd(&regs[0], red[0]);
}

// ---------------------------------------------------------------------------
// k_vreeb: V_reeb[b,r,f] = max_{s<16} out[b, sccs[b,r,s], f]
// ---------------------------------------------------------------------------
__global__ __launch_bounds__(256) void k_vreeb(const float* __restrict__ out,
                                               const int* __restrict__ sccs,
                                               float* __restrict__ V) {
    int b = blockIdx.x;
    int r = blockIdx.y * 4 + (threadIdx.x >> 6);
    int f = threadIdx.x & 63;
    const int* sc = sccs + ((size_t)b * NR + r) * 16;
    const float* ob = out + (size_t)b * NP * 64;
    float m = -__builtin_inff();
    for (int q = 0; q < 16; ++q) m = fmaxf(m, ob[(size_t)sc[q] * 64 + f]);
    V[((size_t)b * NR + r) * 64 + f] = m;
}

// ---------------------------------------------------------------------------
// k_vfps: V_fps[b,p,f] = max_{s<1024} out[b, sccs_fps[b,p,s], f]
// ---------------------------------------------------------------------------
__global__ __launch_bounds__(256) void k_vfps(const float* __restrict__ out,
                                              const int* __restrict__ sccs_fps,
                                              float* __restrict__ V) {
    __shared__ int idxs[1024];
    __shared__ float red[256];
    int b = blockIdx.x, p = blockIdx.y;
    int t = threadIdx.x;
    const int* sp = sccs_fps + ((size_t)b * NFPS + p) * 1024;
    for (int q = t; q < 1024; q += 256) idxs[q] = sp[q];
    __syncthreads();
    int f = t & 63, sc = t >> 6;
    const float* ob = out + (size_t)b * NP * 64;
    float m = -__builtin_inff();
    for (int s = sc; s < 1024; s += 4) m = fmaxf(m, ob[(size_t)idxs[s] * 64 + f]);
    red[t] = m; __syncthreads();
    if (sc == 0) {
        m = fmaxf(fmaxf(red[f], red[64 + f]), fmaxf(red[128 + f], red[192 + f]));
        V[((size_t)b * NFPS + p) * 64 + f] = m;
    }
}

// ---------------------------------------------------------------------------
// k_lfps: L_fps = I - D^{-1/2} dist D^{-1/2} on the pairwise-distance matrix
// of V_fps (55x55 per batch).
// ---------------------------------------------------------------------------
__global__ __launch_bounds__(256) void k_lfps(const float* __restrict__ V,
                                              float* __restrict__ Lf) {
    __shared__ float Vs[NFPS * 64];
    __shared__ float sq[NFPS];
    __shared__ float dist[NFPS * NFPS];
    __shared__ float dinv[NFPS];
    int b = blockIdx.x, t = threadIdx.x;
    for (int q = t; q < NFPS * 64; q += 256) Vs[q] = V[(size_t)b * NFPS * 64 + q];
    __syncthreads();
    if (t < NFPS) {
        float s = 0.f;
        for (int f = 0; f < 64; ++f) { float v = Vs[t * 64 + f]; s += v * v; }
        sq[t] = s;
    }
    __syncthreads();
    for (int q = t; q < NFPS * NFPS; q += 256) {
        int i = q / NFPS, j = q % NFPS;
        float dot = 0.f;
        for (int f = 0; f < 64; ++f) dot += Vs[i * 64 + f] * Vs[j * 64 + f];
        dist[q] = fmaxf(sq[i] + sq[j] - 2.f * dot, 0.f);
    }
    __syncthreads();
    if (t < NFPS) {
        float s = 0.f;
        for (int j = 0; j < NFPS; ++j) s += dist[t * NFPS + j];
        dinv[t] = (s > 0.f) ? 1.0f / sqrtf(fmaxf(s, 1e-12f)) : 0.f;
    }
    __syncthreads();
    for (int q = t; q < NFPS * NFPS; q += 256) {
        int i = q / NFPS, j = q % NFPS;
        Lf[(size_t)b * NFPS * NFPS + q] = ((i == j) ? 1.f : 0.f) - dist[q] * dinv[i] * dinv[j];
    }
}

// ---------------------------------------------------------------------------
// cheb_impl<N>: K=6 Chebyshev conv + relu + Z = L @ out, one batch, one
// 64-wide output-column slice. Register-tiled 4x4 per thread, float4 LDS
// reads both operands (2 B/FMA vs 4 B/FMA scalar -- the R8 kernel was
// LDS-bandwidth-bound at 4 B/FMA). All buffers 64x64; pad rows/cols zeroed
// so N=55 needs no read guards (m-loop to NPAD, Ls pad cols are 0).
// Summation order per output unchanged (m ascending).
// ---------------------------------------------------------------------------
template<int N>
__device__ __forceinline__ void cheb_impl(const float* __restrict__ L,
                                          const float* __restrict__ V,
                                          const float* __restrict__ W,
                                          const float* __restrict__ bias,
                                          float* __restrict__ out,
                                          float* __restrict__ Z,
                                          float* Ls, float* bA, float* bB, float* Ws,
                                          int b, int sl) {
    constexpr int NPAD = (N + 3) & ~3;   // 64 or 56
    int t = threadIdx.x;
    int c0 = (t & 15) * 4;               // 0..60
    int r0 = (t >> 4) * 4;               // 0..60

    // zero-init (pad rows/cols must be exactly 0; LDS may hold poison)
    for (int q = t; q < 64 * 64; q += 256) { Ls[q] = 0.f; bA[q] = 0.f; bB[q] = 0.f; }
    __syncthreads();
    for (int q = t; q < N * N; q += 256) {
        int r = q / N, m = q % N;
        Ls[r * 64 + m] = L[(size_t)b * N * N + q];
    }
    for (int q = t; q < N * 64; q += 256) bA[q] = V[(size_t)b * N * 64 + q];
    {
        const float* Wk = W + sl * 64;
        for (int q = t; q < 64 * 64; q += 256) Ws[q] = Wk[(q >> 6) * 256 + (q & 63)];
    }
    float4 a4[4];
    {
        float4 bv = *(const float4*)&bias[sl * 64 + c0];
#pragma unroll
        for (int i = 0; i < 4; ++i) a4[i] = bv;
    }
    __syncthreads();

    // accum: a4[i] += X[r0+i][:] @ Ws[:, c0..c0+3]  (m ascending, 4-step)
    auto accum = [&](const float* xb) {
        for (int m = 0; m < 64; m += 4) {
            float4 xv[4], wv[4];
#pragma unroll
            for (int i = 0; i < 4; ++i) xv[i] = *(const float4*)&xb[(r0 + i) * 64 + m];
#pragma unroll
            for (int mm = 0; mm < 4; ++mm) wv[mm] = *(const float4*)&Ws[(m + mm) * 64 + c0];
#pragma unroll
            for (int i = 0; i < 4; ++i) {
                float xi0 = xv[i].x, xi1 = xv[i].y, xi2 = xv[i].z, xi3 = xv[i].w;
                a4[i].x += xi0 * wv[0].x; a4[i].y += xi0 * wv[0].y; a4[i].z += xi0 * wv[0].z; a4[i].w += xi0 * wv[0].w;
                a4[i].x += xi1 * wv[1].x; a4[i].y += xi1 * wv[1].y; a4[i].z += xi1 * wv[1].z; a4[i].w += xi1 * wv[1].w;
                a4[i].x += xi2 * wv[2].x; a4[i].y += xi2 * wv[2].y; a4[i].z += xi2 * wv[2].z; a4[i].w += xi2 * wv[2].w;
                a4[i].x += xi3 * wv[3].x; a4[i].y += xi3 * wv[3].y; a4[i].z += xi3 * wv[3].z; a4[i].w += xi3 * wv[3].w;
            }
        }
    };
    // chebmm: dst[r][c] = (first ? 1 : 2)*L@src - (first ? 0 : dst)
    auto chebmm = [&](const float* src, float* dst, bool first) {
        float4 acc[4];
#pragma unroll
        for (int i = 0; i < 4; ++i) acc[i] = make_float4(0.f, 0.f, 0.f, 0.f);
        for (int m = 0; m < NPAD; m += 4) {
            float4 sv[4], lv[4];
#pragma unroll
            for (int mm = 0; mm < 4; ++mm) sv[mm] = *(const float4*)&src[(m + mm) * 64 + c0];
#pragma unroll
            for (int i = 0; i < 4; ++i) lv[i] = *(const float4*)&Ls[(r0 + i) * 64 + m];
#pragma unroll
            for (int i = 0; i < 4; ++i) {
                float l0 = lv[i].x, l1 = lv[i].y, l2 = lv[i].z, l3 = lv[i].w;
                acc[i].x += l0 * sv[0].x; acc[i].y += l0 * sv[0].y; acc[i].z += l0 * sv[0].z; acc[i].w += l0 * sv[0].w;
                acc[i].x += l1 * sv[1].x; acc[i].y += l1 * sv[1].y; acc[i].z += l1 * sv[1].z; acc[i].w += l1 * sv[1].w;
                acc[i].x += l2 * sv[2].x; acc[i].y += l2 * sv[2].y; acc[i].z += l2 * sv[2].z; acc[i].w += l2 * sv[2].w;
                acc[i].x += l3 * sv[3].x; acc[i].y += l3 * sv[3].y; acc[i].z += l3 * sv[3].z; acc[i].w += l3 * sv[3].w;
            }
        }
#pragma unroll
        for (int i = 0; i < 4; ++i) {
            if (r0 + i < N) {
                float4* d = (float4*)&dst[(r0 + i) * 64 + c0];
                if (first) *d = acc[i];
                else {
                    float4 od = *d;
                    *d = make_float4(2.f * acc[i].x - od.x, 2.f * acc[i].y - od.y,
                                     2.f * acc[i].z - od.z, 2.f * acc[i].w - od.w);
                }
            }
        }
    };
    auto loadW = [&](int k) {
        const float* Wk = W + (size_t)k * 64 * 256 + sl * 64;
        for (int q = t; q < 64 * 64; q += 256) Ws[q] = Wk[(q >> 6) * 256 + (q & 63)];
    };

    accum(bA);                 __syncthreads();   // uses Ws(k=0)
    chebmm(bA, bB, true);      loadW(1);  __syncthreads();
    accum(bB);                 __syncthreads();
    chebmm(bB, bA, false);     loadW(2);  __syncthreads();   // bA = xs2
    accum(bA);                 __syncthreads();
    chebmm(bA, bB, false);     loadW(3);  __syncthreads();   // bB = xs3
    accum(bB);                 __syncthreads();
    chebmm(bB, bA, false);     loadW(4);  __syncthreads();   // bA = xs4
    accum(bA);                 __syncthreads();
    chebmm(bA, bB, false);     loadW(5);  __syncthreads();   // bB = xs5
    accum(bB);                 __syncthreads();

    // relu -> global store + stash in bA (pad rows of bA stay zero)
    float* ob = out + (size_t)b * N * 256 + sl * 64;
#pragma unroll
    for (int i = 0; i < 4; ++i) {
        if (r0 + i < N) {
            float4 v = make_float4(fmaxf(a4[i].x, 0.f), fmaxf(a4[i].y, 0.f),
                                   fmaxf(a4[i].z, 0.f), fmaxf(a4[i].w, 0.f));
            *(float4*)&bA[(r0 + i) * 64 + c0] = v;
            *(float4*)&ob[(size_t)(r0 + i) * 256 + c0] = v;
        }
    }
    __syncthreads();
    // Z = L @ relu(out), same tiling
    {
        float4 acc[4];
#pragma unroll
        for (int i = 0; i < 4; ++i) acc[i] = make_float4(0.f, 0.f, 0.f, 0.f);
        for (int m = 0; m < NPAD; m += 4) {
            float4 sv[4], lv[4];
#pragma unroll
            for (int mm = 0; mm < 4; ++mm) sv[mm] = *(const float4*)&bA[(m + mm) * 64 + c0];
#pragma unroll
            for (int i = 0; i < 4; ++i) lv[i] = *(const float4*)&Ls[(r0 + i) * 64 + m];
#pragma unroll
            for (int i = 0; i < 4; ++i) {
                float l0 = lv[i].x, l1 = lv[i].y, l2 = lv[i].z, l3 = lv[i].w;
                acc[i].x += l0 * sv[0].x; acc[i].y += l0 * sv[0].y; acc[i].z += l0 * sv[0].z; acc[i].w += l0 * sv[0].w;
                acc[i].x += l1 * sv[1].x; acc[i].y += l1 * sv[1].y; acc[i].z += l1 * sv[1].z; acc[i].w += l1 * sv[1].w;
                acc[i].x += l2 * sv[2].x; acc[i].y += l2 * sv[2].y; acc[i].z += l2 * sv[2].z; acc[i].w += l2 * sv[2].w;
                acc[i].x += l3 * sv[3].x; acc[i].y += l3 * sv[3].y; acc[i].z += l3 * sv[3].z; acc[i].w += l3 * sv[3].w;
            }
        }
        float* zb = Z + (size_t)b * N * 256 + sl * 64;
#pragma unroll
        for (int i = 0; i < 4; ++i)
            if (r0 + i < N) *(float4*)&zb[(size_t)(r0 + i) * 256 + c0] = acc[i];
    }
}

// Fused reeb+fps cheb conv. Grid (B, 8): y<4 -> reeb slice y, else fps y-4.
// LDS 64 KB exactly -> 2 blocks/CU.
__global__ __launch_bounds__(256) void k_cheb_fused(
        const float* __restrict__ Lr, const float* __restrict__ Vr,
        const float* __restrict__ Wr, const float* __restrict__ br,
        float* __restrict__ outR, float* __restrict__ Zr,
        const float* __restrict__ Lf, const float* __restrict__ Vf,
        const float* __restrict__ Wf, const float* __restrict__ bf,
        float* __restrict__ outP, float* __restrict__ Zf) {
    __shared__ float Ls[64 * 64];
    __shared__ float bA[64 * 64];
    __shared__ float bB[64 * 64];
    __shared__ float Ws[64 * 64];
    int b = blockIdx.x, y = blockIdx.y;
    if (y < 4) cheb_impl<NR>(Lr, Vr, Wr, br, outR, Zr, Ls, bA, bB, Ws, b, y);
    else       cheb_impl<NFPS>(Lf, Vf, Wf, bf, outP, Zf, Ls, bA, bB, Ws, b, y - 4);
}

// ---------------------------------------------------------------------------
// treg_impl<N>: reg += sum((out^T Z)^2) for one (f-tile, g-half) pair.
// ---------------------------------------------------------------------------
template<int N>
__device__ __forceinline__ void treg_impl(const float* __restrict__ out,
                                          const float* __restrict__ Z,
                                          float* __restrict__ reg,
                                          float* zs, float* os, float* red, int y) {
    int b = blockIdx.x;
    int f0 = (y >> 1) * 32;
    int g0 = (y & 1) * 128;
    int t = threadIdx.x;
    for (int q = t; q < N * 128; q += 256) {
        int r = q >> 7, gl = q & 127;
        zs[q] = Z[(size_t)b * N * 256 + r * 256 + g0 + gl];
    }
    for (int q = t; q < N * 32; q += 256) {
        int r = q >> 5, f = q & 31;
        os[q] = out[(size_t)b * N * 256 + r * 256 + f0 + f];
    }
    __syncthreads();
    int fl = t >> 3;           // 0..31
    int gb = (t & 7) * 16;     // 0..112
    float accv[16];
#pragma unroll
    for (int q = 0; q < 16; ++q) accv[q] = 0.f;
    for (int n = 0; n < N; ++n) {
        float a = os[n * 32 + fl];
        const float* zr = zs + n * 128 + gb;
#pragma unroll
        for (int q = 0; q < 16; ++q) accv[q] += a * zr[q];
    }
    float loc = 0.f;
#pragma unroll
    for (int q = 0; q < 16; ++q) loc += accv[q] * accv[q];
    red[t] = loc; __syncthreads();
    for (int st = 128; st > 0; st >>= 1) { if (t < st) red[t] += red[t + st]; __syncthreads(); }
    if (t == 0) atomicAdd(reg, red[0]);
}

// Fused treg. Grid (B, 32): y<16 -> reeb (regs[1]), else fps (regs[2]).
__global__ __launch_bounds__(256) void k_treg_fused(
        const float* __restrict__ outR, const float* __restrict__ Zr,
        const float* __restrict__ outP, const float* __restrict__ Zf,
        float* __restrict__ regs) {
    __shared__ float zs[64 * 128];
    __shared__ float os[64 * 32];
    __shared__ float red[256];
    int y = blockIdx.y;
    if (y < 16) treg_impl<NR>(outR, Zr, regs + 1, zs, os, red, y);
    else        treg_impl<NFPS>(outP, Zf, regs + 2, zs, os, red, y - 16);
}

// ---------------------------------------------------------------------------
// k_tail: feature max-pool + 2-layer MLP -> logits
// ---------------------------------------------------------------------------
__global__ __launch_bounds__(256) void k_tail(const float* __restrict__ outR,
                                              const float* __restrict__ outP,
                                              const float* __restrict__ fc1_w,
                                              const float* __restrict__ fc1_b,
                                              const float* __restrict__ fc3_w,
                                              const float* __restrict__ fc3_b,
                                              float* __restrict__ logits) {
    __shared__ float feat[512];
    __shared__ float h[256];
    int b = blockIdx.x, t = threadIdx.x;
    float m = -__builtin_inff();
    for (int r = 0; r < NR; ++r) m = fmaxf(m, outR[((size_t)b * NR + r) * 256 + t]);
    feat[t] = m;
    m = -__builtin_inff();
    for (int p = 0; p < NFPS; ++p) m = fmaxf(m, outP[((size_t)b * NFPS + p) * 256 + t]);
    feat[256 + t] = m;
    __syncthreads();
    float a = fc1_b[t];
    for (int i = 0; i < 512; ++i) a += feat[i] * fc1_w[(size_t)i * 256 + t];
    h[t] = fmaxf(a, 0.f);
    __syncthreads();
    if (t < 40) {
        float a2 = fc3_b[t];
        for (int i = 0; i < 256; ++i) a2 += h[i] * fc3_w[(size_t)i * 40 + t];
        logits[(size_t)b * 40 + t] = a2;
    }
}

// ---------------------------------------------------------------------------
extern "C" void kernel_launch(void* const* d_in, const int* in_sizes, int n_in,
                              void* d_out, int out_size, void* d_ws, size_t ws_size,
                              hipStream_t stream) {
    const float* x      = (const float*)d_in[0];
    // d_in[1] (x2) unused by the reference
    const float* L_reeb = (const float*)d_in[2];
    const float* W1     = (const float*)d_in[3];
    const float* b1     = (const float*)d_in[4];
    const float* W_reeb = (const float*)d_in[5];
    const float* b_reeb = (const float*)d_in[6];
    const float* W_fps  = (const float*)d_in[7];
    const float* b_fps  = (const float*)d_in[8];
    const float* fc1_w  = (const float*)d_in[9];
    const float* fc1_b  = (const float*)d_in[10];
    const float* fc3_w  = (const float*)d_in[11];
    const float* fc3_b  = (const float*)d_in[12];
    const int*   sccs   = (const int*)d_in[13];
    const int*   sccs_f = (const int*)d_in[14];

    float* outv = (float*)d_out;          // 32*40 logits
    float* regs = outv + 1280;            // 7 regs

    char* w = (char*)d_ws;
    size_t off = 0;
    auto alloc = [&](size_t bytes) { void* p = w + off; off = (off + bytes + 255) & ~(size_t)255; return p; };
    int*   knn   = (int*)  alloc((size_t)BN * NP * KNN * 4);
    float* xs1   = (float*)alloc((size_t)BN * NP * 7 * 4);
    float* outF  = (float*)alloc((size_t)BN * NP * 64 * 4);
    float* Z1    = (float*)alloc((size_t)BN * NP * 64 * 4);
    float* Vreeb = (float*)alloc((size_t)BN * NR * 64 * 4);
    float* outRb = (float*)alloc((size_t)BN * NR * 256 * 4);
    float* Z2    = (float*)alloc((size_t)BN * NR * 256 * 4);
    float* Vfps  = (float*)alloc((size_t)BN * NFPS * 64 * 4);
    float* Lfps  = (float*)alloc((size_t)BN * NFPS * NFPS * 4);
    float* outP  = (float*)alloc((size_t)BN * NFPS * 256 * 4);
    float* Z3    = (float*)alloc((size_t)BN * NFPS * 256 * 4);

    k_init<<<1, 256, 0, stream>>>(fc1_w, fc1_b, fc3_w, fc3_b, regs);
    k_knn<<<dim3(BN, NP / 64), 256, 0, stream>>>(x, knn, xs1);
    k_out<<<dim3(BN, NP / 256), 256, 0, stream>>>(x, xs1, knn, W1, b1, outF);
    k_z1<<<dim3(BN, NP / 4), 256, 0, stream>>>(outF, knn, Z1);
    k_t1<<<dim3(BN, 2), 256, 0, stream>>>(outF, Z1, regs);
    k_vreeb<<<dim3(BN, NR / 4), 256, 0, stream>>>(outF, sccs, Vreeb);
    k_vfps<<<dim3(BN, NFPS), 256, 0, stream>>>(outF, sccs_f, Vfps);
    k_lfps<<<BN, 256, 0, stream>>>(Vfps, Lfps);
    k_cheb_fused<<<dim3(BN, 8), 256, 0, stream>>>(L_reeb, Vreeb, W_reeb, b_reeb, outRb, Z2,
                                                  Lfps, Vfps, W_fps, b_fps, outP, Z3);
    k_treg_fused<<<dim3(BN, 32), 256, 0, stream>>>(outRb, Z2, outP, Z3, regs);
    k_tail<<<BN, 256, 0, stream>>>(outRb, outP, fc1_w, fc1_b, fc3_w, fc3_b, outv);
}

// Round 10
// 458.664 us; speedup vs baseline: 6.9531x; 1.0224x over previous
//
#include <hip/hip_runtime.h>
#include <math.h>

#define BN 32
#define NP 1024
#define KNN 30
#define NR 64
#define NFPS 55

// s = dinv*dinv with dinv = 1/sqrt(30) in f32, matching the reference's
// normalized laplacian (every kNN row-sum is exactly 30).
__device__ __forceinline__ float lap_s() {
    const float dv = 1.0f / sqrtf(30.0f);
    return dv * dv;
}

// Distance with ALL operations IEEE-pinned (contract off): guarantees the
// phase-A value and the phase-C recompute are bit-identical.
__device__ __forceinline__ float dist7(const float4& xiA, const float4& xiB,
                                       float sqi, const float4& ca, const float4& cb) {
#pragma clang fp contract(off)
    float dot = xiA.x * ca.x;
    dot = fmaf(xiA.y, ca.y, dot);
    dot = fmaf(xiA.z, ca.z, dot);
    dot = fmaf(xiA.w, ca.w, dot);
    dot = fmaf(xiB.x, cb.x, dot);
    dot = fmaf(xiB.y, cb.y, dot);
    dot = fmaf(xiB.z, cb.z, dot);
    float r = sqi + cb.w;
    r = r - 2.f * dot;
    return fmaxf(r, 0.f);
}

// ---------------------------------------------------------------------------
// k_knn: 4 waves/row-group split over j, med3 value-only top-30 per wave
// (4-wide j-chunks: 8 ds_read_b128 issued per chunk, then 4 dist+chain --
// one lgkm wait per 4 j; value multiset is order-independent), per-row 4-way
// VALUE merge (tie -> lowest wave = jax (dist,idx) order), per-wave
// threshold rescan emits its taken_w indices in ascending j (set semantics).
// xs1 fused via per-wave partials. Block (0,0) also does the reg-init work
// (block-uniform branch; stream order guarantees completion before k_t1).
// ---------------------------------------------------------------------------
__global__ __launch_bounds__(256) void k_knn(const float* __restrict__ x,
                                             int* __restrict__ knn,
                                             float* __restrict__ xs1,
                                             const float* __restrict__ fc1_w,
                                             const float* __restrict__ fc1_b,
                                             const float* __restrict__ fc3_w,
                                             const float* __restrict__ fc3_b,
                                             float* __restrict__ regs) {
    __shared__ float xls[NP * 8];          // 32768 B: 7 feats + sq in slot 7
    __shared__ float vals[4 * KNN * 64];   // 30720 B (overlaid: init red / ns)
    __shared__ float Tm[4 * 64];           // per-(wave,row) threshold
    __shared__ int   Pk[4 * 64];           // base | (need<<8) | (tk<<16)
    int b = blockIdx.x;
    int t = threadIdx.x;
    int ln = t & 63, wv = t >> 6;

    // ---- folded k_init (one block; uniform branch so barriers are legal) ----
    if (b == 0 && blockIdx.y == 0) {
        float* r1 = vals;        // overlay (vals not yet used)
        float* r2 = vals + 256;
        float s1 = 0.f;
        for (int i = t; i < 512; i += 256) { float v = fc1_w[(size_t)i * 256]; s1 += v * v; }
        float v2 = fc3_w[(size_t)t * 40];
        r1[t] = s1; r2[t] = v2 * v2;
        __syncthreads();
        for (int st = 128; st > 0; st >>= 1) {
            if (t < st) { r1[t] += r1[t + st]; r2[t] += r2[t + st]; }
            __syncthreads();
        }
        if (t == 0) {
            regs[0] = 0.f; regs[1] = 0.f; regs[2] = 0.f;
            regs[3] = r1[0];
            regs[4] = fc1_b[0] * fc1_b[0];
            regs[5] = r2[0];
            regs[6] = fc3_b[0] * fc3_b[0];
        }
        __syncthreads();
    }

    const float* xb = x + (size_t)b * NP * 7;
    for (int q = t; q < NP * 8; q += 256) {
        int r = q >> 3, d = q & 7;
        xls[q] = (d < 7) ? xb[r * 7 + d] : 0.f;
    }
    __syncthreads();
    for (int r = t; r < NP; r += 256) {
        float s = 0.f;
#pragma unroll
        for (int d = 0; d < 7; ++d) { float v = xls[r * 8 + d]; s += v * v; }
        xls[r * 8 + 7] = s;
    }
    __syncthreads();

    int grow = blockIdx.y * 64 + ln;
    float4 xiA = *(const float4*)&xls[grow * 8];
    float4 xiB = *(const float4*)&xls[grow * 8 + 4];
    float sqi = xiB.w;

    // ---- phase A: wave-local branchless value top-30, 4-wide j chunks ----
    float bd[KNN];
#pragma unroll
    for (int q = 0; q < KNN; ++q) bd[q] = __builtin_inff();
    int jbase = wv * 256;
    for (int jc = 0; jc < 256; jc += 4) {
        const float* p = &xls[(jbase + jc) * 8];
        float4 a0 = *(const float4*)(p +  0), b0 = *(const float4*)(p +  4);
        float4 a1 = *(const float4*)(p +  8), b1 = *(const float4*)(p + 12);
        float4 a2 = *(const float4*)(p + 16), b2 = *(const float4*)(p + 20);
        float4 a3 = *(const float4*)(p + 24), b3 = *(const float4*)(p + 28);
        float d0 = dist7(xiA, xiB, sqi, a0, b0);
        float d1 = dist7(xiA, xiB, sqi, a1, b1);
        float d2 = dist7(xiA, xiB, sqi, a2, b2);
        float d3 = dist7(xiA, xiB, sqi, a3, b3);
#pragma unroll
        for (int q = KNN - 1; q >= 1; --q) bd[q] = __builtin_amdgcn_fmed3f(bd[q - 1], d0, bd[q]);
        bd[0] = fminf(bd[0], d0);
#pragma unroll
        for (int q = KNN - 1; q >= 1; --q) bd[q] = __builtin_amdgcn_fmed3f(bd[q - 1], d1, bd[q]);
        bd[0] = fminf(bd[0], d1);
#pragma unroll
        for (int q = KNN - 1; q >= 1; --q) bd[q] = __builtin_amdgcn_fmed3f(bd[q - 1], d2, bd[q]);
        bd[0] = fminf(bd[0], d2);
#pragma unroll
        for (int q = KNN - 1; q >= 1; --q) bd[q] = __builtin_amdgcn_fmed3f(bd[q - 1], d3, bd[q]);
        bd[0] = fminf(bd[0], d3);
    }
#pragma unroll
    for (int q = 0; q < KNN; ++q) vals[wv * (KNN * 64) + q * 64 + ln] = bd[q];
    __syncthreads();

    // ---- merge: one thread per row, 4-way value merge, tie -> lowest wave ----
    if (t < 64) {
        const float inf = __builtin_inff();
        float h0 = vals[0 * 1920 + t];
        float h1 = vals[1 * 1920 + t];
        float h2 = vals[2 * 1920 + t];
        float h3 = vals[3 * 1920 + t];
        int p0 = 0, p1 = 0, p2 = 0, p3 = 0;
        for (int s = 0; s < KNN; ++s) {
            float best = h0; int bw = 0;
            if (h1 < best) { best = h1; bw = 1; }
            if (h2 < best) { best = h2; bw = 2; }
            if (h3 < best) { best = h3; bw = 3; }
            if (bw == 0)      { ++p0; h0 = (p0 < KNN) ? vals[0 * 1920 + p0 * 64 + t] : inf; }
            else if (bw == 1) { ++p1; h1 = (p1 < KNN) ? vals[1 * 1920 + p1 * 64 + t] : inf; }
            else if (bw == 2) { ++p2; h2 = (p2 < KNN) ? vals[2 * 1920 + p2 * 64 + t] : inf; }
            else              { ++p3; h3 = (p3 < KNN) ? vals[3 * 1920 + p3 * 64 + t] : inf; }
        }
        int bacc = 0;
        int tks[4] = {p0, p1, p2, p3};
#pragma unroll
        for (int w = 0; w < 4; ++w) {
            int tk = tks[w];
            float T; int need;
            if (tk == 0) { T = -__builtin_inff(); need = 0; }
            else {
                T = vals[w * 1920 + (tk - 1) * 64 + t];
                need = 1;
                for (int q = tk - 2; q >= 0; --q) {
                    if (vals[w * 1920 + q * 64 + t] == T) ++need; else break;
                }
            }
            Tm[w * 64 + t] = T;
            Pk[w * 64 + t] = bacc | (need << 8) | (tk << 16);
            bacc += tk;
        }
    }
    __syncthreads();

    // ---- phase C: per-wave threshold rescan (4-wide chunks), emit + ns ----
    float Tw = Tm[wv * 64 + ln];
    int pk = Pk[wv * 64 + ln];
    int base = pk & 255, need = (pk >> 8) & 255, tk = pk >> 16;
    int* kout = knn + ((size_t)b * NP + grow) * KNN;
    float n0 = 0.f, n1 = 0.f, n2 = 0.f, n3 = 0.f, n4 = 0.f, n5 = 0.f, n6 = 0.f;
    int cs = 0, ct = 0;
    for (int jc = 0; jc < 256; jc += 4) {
        const float* p = &xls[(jbase + jc) * 8];
        float4 a0 = *(const float4*)(p +  0), b0 = *(const float4*)(p +  4);
        float4 a1 = *(const float4*)(p +  8), b1 = *(const float4*)(p + 12);
        float4 a2 = *(const float4*)(p + 16), b2 = *(const float4*)(p + 20);
        float4 a3 = *(const float4*)(p + 24), b3 = *(const float4*)(p + 28);
        float d0 = dist7(xiA, xiB, sqi, a0, b0);
        float d1 = dist7(xiA, xiB, sqi, a1, b1);
        float d2 = dist7(xiA, xiB, sqi, a2, b2);
        float d3 = dist7(xiA, xiB, sqi, a3, b3);
#pragma unroll
        for (int u = 0; u < 4; ++u) {
            float dist = (u == 0) ? d0 : (u == 1) ? d1 : (u == 2) ? d2 : d3;
            const float4& ca = (u == 0) ? a0 : (u == 1) ? a1 : (u == 2) ? a2 : a3;
            const float4& cb = (u == 0) ? b0 : (u == 1) ? b1 : (u == 2) ? b2 : b3;
            bool lt = dist < Tw;
            bool eq = (dist == Tw) && (ct < need);
            if ((lt || eq) && (cs + ct < tk)) {
                kout[base + cs + ct] = jbase + jc + u;
                cs += lt ? 1 : 0;
                ct += eq ? 1 : 0;
                n0 += ca.x; n1 += ca.y; n2 += ca.z; n3 += ca.w;
                n4 += cb.x; n5 += cb.y; n6 += cb.z;
            }
        }
    }
    for (int q = cs + ct; q < tk; ++q) kout[base + q] = grow;  // safety net
    // ns partials overlay the (now-dead) vals region
    float* nsb = vals;
    nsb[wv * 448 + 0 * 64 + ln] = n0;
    nsb[wv * 448 + 1 * 64 + ln] = n1;
    nsb[wv * 448 + 2 * 64 + ln] = n2;
    nsb[wv * 448 + 3 * 64 + ln] = n3;
    nsb[wv * 448 + 4 * 64 + ln] = n4;
    nsb[wv * 448 + 5 * 64 + ln] = n5;
    nsb[wv * 448 + 6 * 64 + ln] = n6;
    __syncthreads();
    for (int u = t; u < 448; u += 256) {
        int d = u >> 6, rl = u & 63;
        float tot = nsb[d * 64 + rl] + nsb[448 + d * 64 + rl]
                  + nsb[896 + d * 64 + rl] + nsb[1344 + d * 64 + rl];
        int gr = blockIdx.y * 64 + rl;
        xs1[((size_t)b * NP + gr) * 7 + d] = xls[gr * 8 + d] - lap_s() * tot;
    }
}

// ---------------------------------------------------------------------------
// k_out: xs2 = 2 L xs1 - x, then out = relu([x|xs1|xs2] @ W1 + b1), (B,N,64).
// 128 rows/block -> grid (32,8) = 256 blocks (was 128: half the chip idle).
// ---------------------------------------------------------------------------
__global__ __launch_bounds__(256) void k_out(const float* __restrict__ x,
                                             const float* __restrict__ xs1,
                                             const int* __restrict__ knn,
                                             const float* __restrict__ W1,
                                             const float* __restrict__ b1,
                                             float* __restrict__ out) {
    __shared__ float x1s[NP * 7];    // xs1 for ALL rows (neighbor gathers)
    __shared__ float x0s[128 * 7];   // x for this block's rows only
    __shared__ float fr[128 * 21];
    __shared__ float W1s[21 * 64];
    __shared__ float b1s[64];
    int b = blockIdx.x;
    int rbase = blockIdx.y * 128;
    int t = threadIdx.x;
    for (int q = t; q < NP * 7; q += 256) x1s[q] = xs1[(size_t)b * NP * 7 + q];
    for (int q = t; q < 128 * 7; q += 256) x0s[q] = x[(size_t)b * NP * 7 + (size_t)rbase * 7 + q];
    for (int q = t; q < 21 * 64; q += 256) W1s[q] = W1[q];
    if (t < 64) b1s[t] = b1[t];
    __syncthreads();
    if (t < 128) {   // phase 1: per-row 21-feature vector (128 rows)
        int i = rbase + t;
        float f[21];
#pragma unroll
        for (int d = 0; d < 7; ++d) { f[d] = x0s[t * 7 + d]; f[7 + d] = x1s[i * 7 + d]; }
        float ns[7] = {0.f, 0.f, 0.f, 0.f, 0.f, 0.f, 0.f};
        const int* kn = knn + ((size_t)b * NP + i) * KNN;
        for (int q = 0; q < KNN; ++q) {
            int j = kn[q];
#pragma unroll
            for (int d = 0; d < 7; ++d) ns[d] += x1s[j * 7 + d];
        }
        const float s = lap_s();
#pragma unroll
        for (int d = 0; d < 7; ++d) f[14 + d] = 2.f * (f[7 + d] - s * ns[d]) - f[d];
#pragma unroll
        for (int d = 0; d < 21; ++d) fr[t * 21 + d] = f[d];
    }
    __syncthreads();
    // phase 2: (128 rows x 21) @ (21 x 64), coalesced store
    int o = t & 63, g = t >> 6;
    for (int m = 0; m < 32; ++m) {
        int r = g * 32 + m;
        float acc = b1s[o];
#pragma unroll
        for (int d = 0; d < 21; ++d) acc += fr[r * 21 + d] * W1s[d * 64 + o];
        out[((size_t)b * NP + rbase + r) * 64 + o] = fmaxf(acc, 0.f);
    }
}

// ---------------------------------------------------------------------------
// k_z1: Z1 = L @ out via kNN gathers (B,N,64).
// ---------------------------------------------------------------------------
__global__ __launch_bounds__(256) void k_z1(const float* __restrict__ out,
                                            const int* __restrict__ knn,
                                            float* __restrict__ Z1) {
    int b = blockIdx.x;
    int i = blockIdx.y * 4 + (threadIdx.x >> 6);
    int f = threadIdx.x & 63;
    const int* kn = knn + ((size_t)b * NP + i) * KNN;
    const float* ob = out + (size_t)b * NP * 64;
    float sum = 0.f;
    for (int q = 0; q < KNN; ++q) sum += ob[(size_t)kn[q] * 64 + f];
    Z1[((size_t)b * NP + i) * 64 + f] = ob[(size_t)i * 64 + f] - lap_s() * sum;
}

// ---------------------------------------------------------------------------
// k_t1: reg1 += sum((out^T Z1)^2) per batch. f-half per block, LDS chunks.
// ---------------------------------------------------------------------------
__global__ __launch_bounds__(256) void k_t1(const float* __restrict__ out,
                                            const float* __restrict__ Z1,
                                            float* __restrict__ regs) {
    __shared__ float os[64 * 64];
    __shared__ float zs[64 * 64];
    __shared__ float red[256];
    int b = blockIdx.x;
    int f0 = blockIdx.y * 32;
    int t = threadIdx.x;
    int fl = t >> 3;          // 0..31
    int gb = (t & 7) * 8;     // 0..56
    float acc[8];
#pragma unroll
    for (int q = 0; q < 8; ++q) acc[q] = 0.f;
    for (int c = 0; c < 16; ++c) {
        const float* ob = out + ((size_t)b * NP + c * 64) * 64;
        const float* zb = Z1 + ((size_t)b * NP + c * 64) * 64;
        for (int q = t; q < 64 * 64; q += 256) { os[q] = ob[q]; zs[q] = zb[q]; }
        __syncthreads();
        for (int n = 0; n < 64; ++n) {
            float a = os[n * 64 + f0 + fl];
#pragma unroll
            for (int q = 0; q < 8; ++q) acc[q] += a * zs[n * 64 + gb + q];
        }
        __syncthreads();
    }
    float loc = 0.f;
#pragma unroll
    for (int q = 0; q < 8; ++q) loc += acc[q] * acc[q];
    red[t] = loc; __syncthreads();
    for (int st = 128; st > 0; st >>= 1) { if (t < st) red[t] += red[t + st]; __syncthreads(); }
    if (t == 0) atomicAdd(&regs[0], red[0]);
}

// ---------------------------------------------------------------------------
// k_vpool: fused segment-max pools. Grid (B, 16+55):
//   y<16  -> V_reeb rows y*4..y*4+3 (16-segment max)
//   y>=16 -> V_fps row p=y-16 (1024-segment max)
// ---------------------------------------------------------------------------
__global__ __launch_bounds__(256) void k_vpool(const float* __restrict__ out,
                                               const int* __restrict__ sccs,
                                               const int* __restrict__ sccs_fps,
                                               float* __restrict__ Vr,
                                               float* __restrict__ Vf) {
    __shared__ int idxs[1024];
    __shared__ float red[256];
    int b = blockIdx.x, y = blockIdx.y;
    int t = threadIdx.x;
    const float* ob = out + (size_t)b * NP * 64;
    if (y < 16) {
        int r = y * 4 + (t >> 6);
        int f = t & 63;
        const int* sc = sccs + ((size_t)b * NR + r) * 16;
        float m = -__builtin_inff();
        for (int q = 0; q < 16; ++q) m = fmaxf(m, ob[(size_t)sc[q] * 64 + f]);
        Vr[((size_t)b * NR + r) * 64 + f] = m;
    } else {
        int p = y - 16;
        const int* sp = sccs_fps + ((size_t)b * NFPS + p) * 1024;
        for (int q = t; q < 1024; q += 256) idxs[q] = sp[q];
        __syncthreads();
        int f = t & 63, sc = t >> 6;
        float m = -__builtin_inff();
        for (int s = sc; s < 1024; s += 4) m = fmaxf(m, ob[(size_t)idxs[s] * 64 + f]);
        red[t] = m; __syncthreads();
        if (sc == 0) {
            m = fmaxf(fmaxf(red[f], red[64 + f]), fmaxf(red[128 + f], red[192 + f]));
            Vf[((size_t)b * NFPS + p) * 64 + f] = m;
        }
    }
}

// ---------------------------------------------------------------------------
// k_lfps: L_fps = I - D^{-1/2} dist D^{-1/2} on the pairwise-distance matrix
// of V_fps (55x55 per batch).
// ---------------------------------------------------------------------------
__global__ __launch_bounds__(256) void k_lfps(const float* __restrict__ V,
                                              float* __restrict__ Lf) {
    __shared__ float Vs[NFPS * 64];
    __shared__ float sq[NFPS];
    __shared__ float dist[NFPS * NFPS];
    __shared__ float dinv[NFPS];
    int b = blockIdx.x, t = threadIdx.x;
    for (int q = t; q < NFPS * 64; q += 256) Vs[q] = V[(size_t)b * NFPS * 64 + q];
    __syncthreads();
    if (t < NFPS) {
        float s = 0.f;
        for (int f = 0; f < 64; ++f) { float v = Vs[t * 64 + f]; s += v * v; }
        sq[t] = s;
    }
    __syncthreads();
    for (int q = t; q < NFPS * NFPS; q += 256) {
        int i = q / NFPS, j = q % NFPS;
        float dot = 0.f;
        for (int f = 0; f < 64; ++f) dot += Vs[i * 64 + f] * Vs[j * 64 + f];
        dist[q] = fmaxf(sq[i] + sq[j] - 2.f * dot, 0.f);
    }
    __syncthreads();
    if (t < NFPS) {
        float s = 0.f;
        for (int j = 0; j < NFPS; ++j) s += dist[t * NFPS + j];
        dinv[t] = (s > 0.f) ? 1.0f / sqrtf(fmaxf(s, 1e-12f)) : 0.f;
    }
    __syncthreads();
    for (int q = t; q < NFPS * NFPS; q += 256) {
        int i = q / NFPS, j = q % NFPS;
        Lf[(size_t)b * NFPS * NFPS + q] = ((i == j) ? 1.f : 0.f) - dist[q] * dinv[i] * dinv[j];
    }
}

// ---------------------------------------------------------------------------
// cheb_impl<N>: K=6 Chebyshev conv + relu + Z = L @ out, one batch, one
// 64-wide output-column slice. Register-tiled 4x4 per thread, float4 LDS
// reads both operands. Pad rows/cols zeroed so N=55 needs no read guards.
// ---------------------------------------------------------------------------
template<int N>
__device__ __forceinline__ void cheb_impl(const float* __restrict__ L,
                                          const float* __restrict__ V,
                                          const float* __restrict__ W,
                                          const float* __restrict__ bias,
                                          float* __restrict__ out,
                                          float* __restrict__ Z,
                                          float* Ls, float* bA, float* bB, float* Ws,
                                          int b, int sl) {
    constexpr int NPAD = (N + 3) & ~3;   // 64 or 56
    int t = threadIdx.x;
    int c0 = (t & 15) * 4;               // 0..60
    int r0 = (t >> 4) * 4;               // 0..60

    for (int q = t; q < 64 * 64; q += 256) { Ls[q] = 0.f; bA[q] = 0.f; bB[q] = 0.f; }
    __syncthreads();
    for (int q = t; q < N * N; q += 256) {
        int r = q / N, m = q % N;
        Ls[r * 64 + m] = L[(size_t)b * N * N + q];
    }
    for (int q = t; q < N * 64; q += 256) bA[q] = V[(size_t)b * N * 64 + q];
    {
        const float* Wk = W + sl * 64;
        for (int q = t; q < 64 * 64; q += 256) Ws[q] = Wk[(q >> 6) * 256 + (q & 63)];
    }
    float4 a4[4];
    {
        float4 bv = *(const float4*)&bias[sl * 64 + c0];
#pragma unroll
        for (int i = 0; i < 4; ++i) a4[i] = bv;
    }
    __syncthreads();

    auto accum = [&](const float* xb) {
        for (int m = 0; m < 64; m += 4) {
            float4 xv[4], wv[4];
#pragma unroll
            for (int i = 0; i < 4; ++i) xv[i] = *(const float4*)&xb[(r0 + i) * 64 + m];
#pragma unroll
            for (int mm = 0; mm < 4; ++mm) wv[mm] = *(const float4*)&Ws[(m + mm) * 64 + c0];
#pragma unroll
            for (int i = 0; i < 4; ++i) {
                float xi0 = xv[i].x, xi1 = xv[i].y, xi2 = xv[i].z, xi3 = xv[i].w;
                a4[i].x += xi0 * wv[0].x; a4[i].y += xi0 * wv[0].y; a4[i].z += xi0 * wv[0].z; a4[i].w += xi0 * wv[0].w;
                a4[i].x += xi1 * wv[1].x; a4[i].y += xi1 * wv[1].y; a4[i].z += xi1 * wv[1].z; a4[i].w += xi1 * wv[1].w;
                a4[i].x += xi2 * wv[2].x; a4[i].y += xi2 * wv[2].y; a4[i].z += xi2 * wv[2].z; a4[i].w += xi2 * wv[2].w;
                a4[i].x += xi3 * wv[3].x; a4[i].y += xi3 * wv[3].y; a4[i].z += xi3 * wv[3].z; a4[i].w += xi3 * wv[3].w;
            }
        }
    };
    auto chebmm = [&](const float* src, float* dst, bool first) {
        float4 acc[4];
#pragma unroll
        for (int i = 0; i < 4; ++i) acc[i] = make_float4(0.f, 0.f, 0.f, 0.f);
        for (int m = 0; m < NPAD; m += 4) {
            float4 sv[4], lv[4];
#pragma unroll
            for (int mm = 0; mm < 4; ++mm) sv[mm] = *(const float4*)&src[(m + mm) * 64 + c0];
#pragma unroll
            for (int i = 0; i < 4; ++i) lv[i] = *(const float4*)&Ls[(r0 + i) * 64 + m];
#pragma unroll
            for (int i = 0; i < 4; ++i) {
                float l0 = lv[i].x, l1 = lv[i].y, l2 = lv[i].z, l3 = lv[i].w;
                acc[i].x += l0 * sv[0].x; acc[i].y += l0 * sv[0].y; acc[i].z += l0 * sv[0].z; acc[i].w += l0 * sv[0].w;
                acc[i].x += l1 * sv[1].x; acc[i].y += l1 * sv[1].y; acc[i].z += l1 * sv[1].z; acc[i].w += l1 * sv[1].w;
                acc[i].x += l2 * sv[2].x; acc[i].y += l2 * sv[2].y; acc[i].z += l2 * sv[2].z; acc[i].w += l2 * sv[2].w;
                acc[i].x += l3 * sv[3].x; acc[i].y += l3 * sv[3].y; acc[i].z += l3 * sv[3].z; acc[i].w += l3 * sv[3].w;
            }
        }
#pragma unroll
        for (int i = 0; i < 4; ++i) {
            if (r0 + i < N) {
                float4* d = (float4*)&dst[(r0 + i) * 64 + c0];
                if (first) *d = acc[i];
                else {
                    float4 od = *d;
                    *d = make_float4(2.f * acc[i].x - od.x, 2.f * acc[i].y - od.y,
                                     2.f * acc[i].z - od.z, 2.f * acc[i].w - od.w);
                }
            }
        }
    };
    auto loadW = [&](int k) {
        const float* Wk = W + (size_t)k * 64 * 256 + sl * 64;
        for (int q = t; q < 64 * 64; q += 256) Ws[q] = Wk[(q >> 6) * 256 + (q & 63)];
    };

    accum(bA);                 __syncthreads();
    chebmm(bA, bB, true);      loadW(1);  __syncthreads();
    accum(bB);                 __syncthreads();
    chebmm(bB, bA, false);     loadW(2);  __syncthreads();
    accum(bA);                 __syncthreads();
    chebmm(bA, bB, false);     loadW(3);  __syncthreads();
    accum(bB);                 __syncthreads();
    chebmm(bB, bA, false);     loadW(4);  __syncthreads();
    accum(bA);                 __syncthreads();
    chebmm(bA, bB, false);     loadW(5);  __syncthreads();
    accum(bB);                 __syncthreads();

    float* ob = out + (size_t)b * N * 256 + sl * 64;
#pragma unroll
    for (int i = 0; i < 4; ++i) {
        if (r0 + i < N) {
            float4 v = make_float4(fmaxf(a4[i].x, 0.f), fmaxf(a4[i].y, 0.f),
                                   fmaxf(a4[i].z, 0.f), fmaxf(a4[i].w, 0.f));
            *(float4*)&bA[(r0 + i) * 64 + c0] = v;
            *(float4*)&ob[(size_t)(r0 + i) * 256 + c0] = v;
        }
    }
    __syncthreads();
    {
        float4 acc[4];
#pragma unroll
        for (int i = 0; i < 4; ++i) acc[i] = make_float4(0.f, 0.f, 0.f, 0.f);
        for (int m = 0; m < NPAD; m += 4) {
            float4 sv[4], lv[4];
#pragma unroll
            for (int mm = 0; mm < 4; ++mm) sv[mm] = *(const float4*)&bA[(m + mm) * 64 + c0];
#pragma unroll
            for (int i = 0; i < 4; ++i) lv[i] = *(const float4*)&Ls[(r0 + i) * 64 + m];
#pragma unroll
            for (int i = 0; i < 4; ++i) {
                float l0 = lv[i].x, l1 = lv[i].y, l2 = lv[i].z, l3 = lv[i].w;
                acc[i].x += l0 * sv[0].x; acc[i].y += l0 * sv[0].y; acc[i].z += l0 * sv[0].z; acc[i].w += l0 * sv[0].w;
                acc[i].x += l1 * sv[1].x; acc[i].y += l1 * sv[1].y; acc[i].z += l1 * sv[1].z; acc[i].w += l1 * sv[1].w;
                acc[i].x += l2 * sv[2].x; acc[i].y += l2 * sv[2].y; acc[i].z += l2 * sv[2].z; acc[i].w += l2 * sv[2].w;
                acc[i].x += l3 * sv[3].x; acc[i].y += l3 * sv[3].y; acc[i].z += l3 * sv[3].z; acc[i].w += l3 * sv[3].w;
            }
        }
        float* zb = Z + (size_t)b * N * 256 + sl * 64;
#pragma unroll
        for (int i = 0; i < 4; ++i)
            if (r0 + i < N) *(float4*)&zb[(size_t)(r0 + i) * 256 + c0] = acc[i];
    }
}

// Fused reeb+fps cheb conv. Grid (B, 8): y<4 -> reeb slice y, else fps y-4.
__global__ __launch_bounds__(256) void k_cheb_fused(
        const float* __restrict__ Lr, const float* __restrict__ Vr,
        const float* __restrict__ Wr, const float* __restrict__ br,
        float* __restrict__ outR, float* __restrict__ Zr,
        const float* __restrict__ Lf, const float* __restrict__ Vf,
        const float* __restrict__ Wf, const float* __restrict__ bf,
        float* __restrict__ outP, float* __restrict__ Zf) {
    __shared__ float Ls[64 * 64];
    __shared__ float bA[64 * 64];
    __shared__ float bB[64 * 64];
    __shared__ float Ws[64 * 64];
    int b = blockIdx.x, y = blockIdx.y;
    if (y < 4) cheb_impl<NR>(Lr, Vr, Wr, br, outR, Zr, Ls, bA, bB, Ws, b, y);
    else       cheb_impl<NFPS>(Lf, Vf, Wf, bf, outP, Zf, Ls, bA, bB, Ws, b, y - 4);
}

// ---------------------------------------------------------------------------
// treg_impl<N>: reg += sum((out^T Z)^2) for one (f-tile, g-half) pair.
// ---------------------------------------------------------------------------
template<int N>
__device__ __forceinline__ void treg_impl(const float* __restrict__ out,
                                          const float* __restrict__ Z,
                                          float* __restrict__ reg,
                                          float* zs, float* os, float* red, int y) {
    int b = blockIdx.x;
    int f0 = (y >> 1) * 32;
    int g0 = (y & 1) * 128;
    int t = threadIdx.x;
    for (int q = t; q < N * 128; q += 256) {
        int r = q >> 7, gl = q & 127;
        zs[q] = Z[(size_t)b * N * 256 + r * 256 + g0 + gl];
    }
    for (int q = t; q < N * 32; q += 256) {
        int r = q >> 5, f = q & 31;
        os[q] = out[(size_t)b * N * 256 + r * 256 + f0 + f];
    }
    __syncthreads();
    int fl = t >> 3;           // 0..31
    int gb = (t & 7) * 16;     // 0..112
    float accv[16];
#pragma unroll
    for (int q = 0; q < 16; ++q) accv[q] = 0.f;
    for (int n = 0; n < N; ++n) {
        float a = os[n * 32 + fl];
        const float* zr = zs + n * 128 + gb;
#pragma unroll
        for (int q = 0; q < 16; ++q) accv[q] += a * zr[q];
    }
    float loc = 0.f;
#pragma unroll
    for (int q = 0; q < 16; ++q) loc += accv[q] * accv[q];
    red[t] = loc; __syncthreads();
    for (int st = 128; st > 0; st >>= 1) { if (t < st) red[t] += red[t + st]; __syncthreads(); }
    if (t == 0) atomicAdd(reg, red[0]);
}

// Fused treg. Grid (B, 32): y<16 -> reeb (regs[1]), else fps (regs[2]).
__global__ __launch_bounds__(256) void k_treg_fused(
        const float* __restrict__ outR, const float* __restrict__ Zr,
        const float* __restrict__ outP, const float* __restrict__ Zf,
        float* __restrict__ regs) {
    __shared__ float zs[64 * 128];
    __shared__ float os[64 * 32];
    __shared__ float red[256];
    int y = blockIdx.y;
    if (y < 16) treg_impl<NR>(outR, Zr, regs + 1, zs, os, red, y);
    else        treg_impl<NFPS>(outP, Zf, regs + 2, zs, os, red, y - 16);
}

// ---------------------------------------------------------------------------
// k_tail: feature max-pool + 2-layer MLP -> logits
// ---------------------------------------------------------------------------
__global__ __launch_bounds__(256) void k_tail(const float* __restrict__ outR,
                                              const float* __restrict__ outP,
                                              const float* __restrict__ fc1_w,
                                              const float* __restrict__ fc1_b,
                                              const float* __restrict__ fc3_w,
                                              const float* __restrict__ fc3_b,
                                              float* __restrict__ logits) {
    __shared__ float feat[512];
    __shared__ float h[256];
    int b = blockIdx.x, t = threadIdx.x;
    float m = -__builtin_inff();
    for (int r = 0; r < NR; ++r) m = fmaxf(m, outR[((size_t)b * NR + r) * 256 + t]);
    feat[t] = m;
    m = -__builtin_inff();
    for (int p = 0; p < NFPS; ++p) m = fmaxf(m, outP[((size_t)b * NFPS + p) * 256 + t]);
    feat[256 + t] = m;
    __syncthreads();
    float a = fc1_b[t];
    for (int i = 0; i < 512; ++i) a += feat[i] * fc1_w[(size_t)i * 256 + t];
    h[t] = fmaxf(a, 0.f);
    __syncthreads();
    if (t < 40) {
        float a2 = fc3_b[t];
        for (int i = 0; i < 256; ++i) a2 += h[i] * fc3_w[(size_t)i * 40 + t];
        logits[(size_t)b * 40 + t] = a2;
    }
}

// ---------------------------------------------------------------------------
extern "C" void kernel_launch(void* const* d_in, const int* in_sizes, int n_in,
                              void* d_out, int out_size, void* d_ws, size_t ws_size,
                              hipStream_t stream) {
    const float* x      = (const float*)d_in[0];
    // d_in[1] (x2) unused by the reference
    const float* L_reeb = (const float*)d_in[2];
    const float* W1     = (const float*)d_in[3];
    const float* b1     = (const float*)d_in[4];
    const float* W_reeb = (const float*)d_in[5];
    const float* b_reeb = (const float*)d_in[6];
    const float* W_fps  = (const float*)d_in[7];
    const float* b_fps  = (const float*)d_in[8];
    const float* fc1_w  = (const float*)d_in[9];
    const float* fc1_b  = (const float*)d_in[10];
    const float* fc3_w  = (const float*)d_in[11];
    const float* fc3_b  = (const float*)d_in[12];
    const int*   sccs   = (const int*)d_in[13];
    const int*   sccs_f = (const int*)d_in[14];

    float* outv = (float*)d_out;          // 32*40 logits
    float* regs = outv + 1280;            // 7 regs

    char* w = (char*)d_ws;
    size_t off = 0;
    auto alloc = [&](size_t bytes) { void* p = w + off; off = (off + bytes + 255) & ~(size_t)255; return p; };
    int*   knn   = (int*)  alloc((size_t)BN * NP * KNN * 4);
    float* xs1   = (float*)alloc((size_t)BN * NP * 7 * 4);
    float* outF  = (float*)alloc((size_t)BN * NP * 64 * 4);
    float* Z1    = (float*)alloc((size_t)BN * NP * 64 * 4);
    float* Vreeb = (float*)alloc((size_t)BN * NR * 64 * 4);
    float* outRb = (float*)alloc((size_t)BN * NR * 256 * 4);
    float* Z2    = (float*)alloc((size_t)BN * NR * 256 * 4);
    float* Vfps  = (float*)alloc((size_t)BN * NFPS * 64 * 4);
    float* Lfps  = (float*)alloc((size_t)BN * NFPS * NFPS * 4);
    float* outP  = (float*)alloc((size_t)BN * NFPS * 256 * 4);
    float* Z3    = (float*)alloc((size_t)BN * NFPS * 256 * 4);

    k_knn<<<dim3(BN, NP / 64), 256, 0, stream>>>(x, knn, xs1,
                                                 fc1_w, fc1_b, fc3_w, fc3_b, regs);
    k_out<<<dim3(BN, 8), 256, 0, stream>>>(x, xs1, knn, W1, b1, outF);
    k_z1<<<dim3(BN, NP / 4), 256, 0, stream>>>(outF, knn, Z1);
    k_t1<<<dim3(BN, 2), 256, 0, stream>>>(outF, Z1, regs);
    k_vpool<<<dim3(BN, 16 + NFPS), 256, 0, stream>>>(outF, sccs, sccs_f, Vreeb, Vfps);
    k_lfps<<<BN, 256, 0, stream>>>(Vfps, Lfps);
    k_cheb_fused<<<dim3(BN, 8), 256, 0, stream>>>(L_reeb, Vreeb, W_reeb, b_reeb, outRb, Z2,
                                                  Lfps, Vfps, W_fps, b_fps, outP, Z3);
    k_treg_fused<<<dim3(BN, 32), 256, 0, stream>>>(outRb, Z2, outP, Z3, regs);
    k_tail<<<BN, 256, 0, stream>>>(outRb, outP, fc1_w, fc1_b, fc3_w, fc3_b, outv);
}